// Round 1
// baseline (5102.603 us; speedup 1.0000x reference)
//
#include <hip/hip_runtime.h>
#include <math.h>

// Problem constants (B=16, H=W=56, C=256)
#define BB   16
#define HH   56
#define WW   56
#define NN   (HH*WW)        // 3136
#define CC   256
#define CD   64             // conv branch dim
#define AD   192            // attn dim
#define NH   8
#define HG   4
#define HD   24
#define HID  1024
#define M1   49             // 7x7
#define M2   196            // 14x14
#define BNR  (BB*NN)        // 50176 tokens

__device__ __forceinline__ float gelu_f(float x) {
    return 0.5f * x * (1.0f + erff(x * 0.70710678118654752f));
}

// ---------------- LPU: depthwise 3x3 (groups=C) + bias + residual ----------------
// x layout (B,N,C) channel-last. out same.
__global__ __launch_bounds__(256) void lpu_kernel(const float* __restrict__ x,
        const float* __restrict__ w, const float* __restrict__ bias,
        float* __restrict__ out) {
    int c = threadIdx.x;          // 0..255
    int n = blockIdx.x;           // 0..3135
    int b = blockIdx.y;           // 0..15
    int h = n / WW, wc = n - h * WW;
    const float* xb = x + (size_t)b * NN * CC;
    float acc = bias[c];
#pragma unroll
    for (int ky = 0; ky < 3; ++ky) {
        int hy = h + ky - 1;
        if ((unsigned)hy >= (unsigned)HH) continue;
#pragma unroll
        for (int kx = 0; kx < 3; ++kx) {
            int wx = wc + kx - 1;
            if ((unsigned)wx >= (unsigned)WW) continue;
            acc = fmaf(xb[(size_t)(hy * WW + wx) * CC + c], w[c * 9 + ky * 3 + kx], acc);
        }
    }
    size_t o = (size_t)b * NN * CC + (size_t)n * CC + c;
    out[o] = acc + x[o];
}

// ---------------- LayerNorm over C=256, one wave per token ----------------
__global__ __launch_bounds__(256) void ln256_kernel(const float* __restrict__ x,
        const float* __restrict__ g, const float* __restrict__ bt,
        float* __restrict__ y) {
    int lane = threadIdx.x & 63;
    int tok = blockIdx.x * 4 + (threadIdx.x >> 6);
    const float4 v = *(const float4*)(x + (size_t)tok * CC + lane * 4);
    float s = v.x + v.y + v.z + v.w;
    float sq = v.x * v.x + v.y * v.y + v.z * v.z + v.w * v.w;
#pragma unroll
    for (int off = 32; off >= 1; off >>= 1) {
        s += __shfl_xor(s, off, 64);
        sq += __shfl_xor(sq, off, 64);
    }
    float mean = s * (1.0f / 256.0f);
    float var = sq * (1.0f / 256.0f) - mean * mean;
    float rstd = rsqrtf(var + 1e-5f);
    float4 gv = *(const float4*)(g + lane * 4);
    float4 bv = *(const float4*)(bt + lane * 4);
    float4 o;
    o.x = (v.x - mean) * rstd * gv.x + bv.x;
    o.y = (v.y - mean) * rstd * gv.y + bv.y;
    o.z = (v.z - mean) * rstd * gv.z + bv.z;
    o.w = (v.w - mean) * rstd * gv.w + bv.w;
    *(float4*)(y + (size_t)tok * CC + lane * 4) = o;
}

// ---------------- cp branch: dense conv3x3 (64->64) + LN(64) + GELU ----------------
// reads y cols [0,64), writes concat cols [192,256). wave = one pixel, lane = co.
__global__ __launch_bounds__(256) void cpconv_kernel(const float* __restrict__ y,
        const float* __restrict__ w, const float* __restrict__ cb,
        const float* __restrict__ g, const float* __restrict__ bt,
        float* __restrict__ cat) {
    int lane = threadIdx.x & 63;  // co
    int n = blockIdx.x * 4 + (threadIdx.x >> 6);
    int b = blockIdx.y;
    int h = n / WW, wc = n - h * WW;
    const float* yb = y + (size_t)b * NN * CC;
    float acc = cb[lane];
#pragma unroll
    for (int ky = 0; ky < 3; ++ky) {
        int hy = h + ky - 1;
        if ((unsigned)hy >= (unsigned)HH) continue;
#pragma unroll
        for (int kx = 0; kx < 3; ++kx) {
            int wx = wc + kx - 1;
            if ((unsigned)wx >= (unsigned)WW) continue;
            const float* yr = yb + (size_t)(hy * WW + wx) * CC;
            const float* wr = w + lane * 576 + ky * 3 + kx;
#pragma unroll 8
            for (int ci = 0; ci < 64; ++ci)
                acc = fmaf(yr[ci], wr[ci * 9], acc);
        }
    }
    // LN over the 64 lanes (cd dim)
    float s = acc, sq = acc * acc;
#pragma unroll
    for (int off = 32; off >= 1; off >>= 1) {
        s += __shfl_xor(s, off, 64);
        sq += __shfl_xor(sq, off, 64);
    }
    float mean = s * (1.0f / 64.0f);
    float var = sq * (1.0f / 64.0f) - mean * mean;
    float rstd = rsqrtf(var + 1e-5f);
    float v = (acc - mean) * rstd * g[lane] + bt[lane];
    cat[(size_t)b * NN * CC + (size_t)n * CC + 192 + lane] = gelu_f(v);
}

// ---------------- SR conv (depthwise KSxKS stride KS) + LN(192) + GELU ----------------
// yap = y + 64 (the ap columns), row stride 256. out (B*OW*OW, 192).
template <int KS, int OW>
__global__ __launch_bounds__(192) void sr_kernel(const float* __restrict__ yap,
        const float* __restrict__ w, const float* __restrict__ bias,
        const float* __restrict__ g, const float* __restrict__ bt,
        float* __restrict__ out) {
    int ch = threadIdx.x;  // 0..191
    int m = blockIdx.x, b = blockIdx.y;
    int oh = m / OW, ow = m - oh * OW;
    const float* yb = yap + (size_t)b * NN * CC;
    float acc = bias[ch];
#pragma unroll
    for (int ky = 0; ky < KS; ++ky)
#pragma unroll
        for (int kx = 0; kx < KS; ++kx)
            acc = fmaf(yb[(size_t)((oh * KS + ky) * WW + ow * KS + kx) * CC + ch],
                       w[ch * KS * KS + ky * KS + kx], acc);
    // block LN over 192 channels
    __shared__ float red[2][3];
    float s = acc, sq = acc * acc;
#pragma unroll
    for (int off = 32; off >= 1; off >>= 1) {
        s += __shfl_xor(s, off, 64);
        sq += __shfl_xor(sq, off, 64);
    }
    int wv = threadIdx.x >> 6, lane = threadIdx.x & 63;
    if (lane == 0) { red[0][wv] = s; red[1][wv] = sq; }
    __syncthreads();
    s = red[0][0] + red[0][1] + red[0][2];
    sq = red[1][0] + red[1][1] + red[1][2];
    float mean = s * (1.0f / 192.0f);
    float var = sq * (1.0f / 192.0f) - mean * mean;
    float rstd = rsqrtf(var + 1e-5f);
    float v = (acc - mean) * rstd * g[ch] + bt[ch];
    out[((size_t)b * (OW * OW) + m) * AD + ch] = gelu_f(v);
}

// ---------------- generic tiled GEMM: C[r,o] = A[r,:K].W[o,:K] (+bias) (+res) ----------------
// A row-major with lda; W row-major (O,K); 64x64 tile, BK=16, 256 threads, 4x4 micro.
__global__ __launch_bounds__(256) void gemm_kernel(
        const float* __restrict__ A, int lda,
        const float* __restrict__ W, int K,
        const float* __restrict__ bias,
        const float* __restrict__ res,   // nullable; row stride = ldc
        float* __restrict__ C, int ldc, int R) {
    __shared__ float As[16][64];
    __shared__ float Ws[16][64];
    int tid = threadIdx.x;
    int tx = tid & 15, ty = tid >> 4;
    int ot = blockIdx.x * 64, rt = blockIdx.y * 64;
    int lr = tid & 63, lk = (tid >> 6) << 2;
    int ar = rt + lr;
    if (ar > R - 1) ar = R - 1;   // clamp OOB rows (values unused)
    const float* Ap = A + (size_t)ar * lda + lk;
    const float* Wp = W + (size_t)(ot + lr) * K + lk;
    float acc[4][4] = {};
    for (int kt = 0; kt < K; kt += 16) {
        float4 av = *(const float4*)(Ap + kt);
        float4 wv = *(const float4*)(Wp + kt);
        __syncthreads();
        As[lk + 0][lr] = av.x; As[lk + 1][lr] = av.y;
        As[lk + 2][lr] = av.z; As[lk + 3][lr] = av.w;
        Ws[lk + 0][lr] = wv.x; Ws[lk + 1][lr] = wv.y;
        Ws[lk + 2][lr] = wv.z; Ws[lk + 3][lr] = wv.w;
        __syncthreads();
#pragma unroll
        for (int kk = 0; kk < 16; ++kk) {
            float4 a4 = *(const float4*)&As[kk][ty << 2];
            float4 w4 = *(const float4*)&Ws[kk][tx << 2];
            float aa[4] = {a4.x, a4.y, a4.z, a4.w};
            float ww[4] = {w4.x, w4.y, w4.z, w4.w};
#pragma unroll
            for (int i = 0; i < 4; ++i)
#pragma unroll
                for (int j = 0; j < 4; ++j)
                    acc[i][j] = fmaf(aa[i], ww[j], acc[i][j]);
        }
    }
#pragma unroll
    for (int i = 0; i < 4; ++i) {
        int r = rt + (ty << 2) + i;
        if (r >= R) continue;
#pragma unroll
        for (int j = 0; j < 4; ++j) {
            int o = ot + (tx << 2) + j;
            float v = acc[i][j];
            if (bias) v += bias[o];
            if (res) v += res[(size_t)r * ldc + o];
            C[(size_t)r * ldc + o] = v;
        }
    }
}

// ---------------- attention: per (n-tile, head, batch) block; K/V in LDS ----------------
// q (BN,192); kv layout (B*M,192): cols [g*24..): K, [96+g*24..): V.
// writes concat cols h*24+d.
__global__ __launch_bounds__(256) void attn_kernel(const float* __restrict__ q,
        const float* __restrict__ kv1, const float* __restrict__ kv2,
        float* __restrict__ cat) {
    __shared__ float sk[M2 * HD];
    __shared__ float sv[M2 * HD];
    int h = blockIdx.y, b = blockIdx.z;
    int M = (h < HG) ? M1 : M2;
    const float* kvo = (h < HG) ? kv1 : kv2;
    int g = (h < HG) ? h : h - HG;
    int tot = M * HD;
    for (int idx = threadIdx.x; idx < tot; idx += 256) {
        int m = idx / HD, d = idx - m * HD;
        sk[idx] = kvo[((size_t)b * M + m) * AD + g * HD + d];
        sv[idx] = kvo[((size_t)b * M + m) * AD + 96 + g * HD + d];
    }
    __syncthreads();
    int n = blockIdx.x * 256 + threadIdx.x;
    if (n >= NN) return;
    float qv[HD];
    const float* qr = q + ((size_t)b * NN + n) * AD + h * HD;
#pragma unroll
    for (int d = 0; d < HD; ++d) qv[d] = qr[d];
    const float scale = 0.20412414523193154f;  // 24^-0.5
    float mx = -1e30f;
    for (int m = 0; m < M; ++m) {
        float s = 0.f;
        const float* kr = sk + m * HD;
#pragma unroll
        for (int d = 0; d < HD; ++d) s = fmaf(qv[d], kr[d], s);
        mx = fmaxf(mx, s * scale);
    }
    float sum = 0.f;
    float acc[HD] = {};
    for (int m = 0; m < M; ++m) {
        float s = 0.f;
        const float* kr = sk + m * HD;
#pragma unroll
        for (int d = 0; d < HD; ++d) s = fmaf(qv[d], kr[d], s);
        float p = expf(s * scale - mx);
        sum += p;
        const float* vr = sv + m * HD;
#pragma unroll
        for (int d = 0; d < HD; ++d) acc[d] = fmaf(p, vr[d], acc[d]);
    }
    float inv = 1.0f / sum;
    float* o = cat + ((size_t)b * NN + n) * CC + h * HD;
#pragma unroll
    for (int d = 0; d < HD; ++d) o[d] = acc[d] * inv;
}

// ---------------- depthwise 3x3 on hid=1024 channels + bias + GELU ----------------
__global__ __launch_bounds__(256) void dwconv_kernel(const float* __restrict__ z1,
        const float* __restrict__ w, const float* __restrict__ bias,
        float* __restrict__ z2) {
    int c = blockIdx.x * 256 + threadIdx.x;  // 0..1023
    int n = blockIdx.y;
    int b = blockIdx.z;
    int h = n / WW, wc = n - h * WW;
    const float* zb = z1 + (size_t)b * NN * HID;
    float acc = bias[c];
#pragma unroll
    for (int ky = 0; ky < 3; ++ky) {
        int hy = h + ky - 1;
        if ((unsigned)hy >= (unsigned)HH) continue;
#pragma unroll
        for (int kx = 0; kx < 3; ++kx) {
            int wx = wc + kx - 1;
            if ((unsigned)wx >= (unsigned)WW) continue;
            acc = fmaf(zb[(size_t)(hy * WW + wx) * HID + c], w[c * 9 + ky * 3 + kx], acc);
        }
    }
    z2[(size_t)b * NN * HID + (size_t)n * HID + c] = gelu_f(acc);
}

extern "C" void kernel_launch(void* const* d_in, const int* in_sizes, int n_in,
                              void* d_out, int out_size, void* d_ws, size_t ws_size,
                              hipStream_t stream) {
    const float* x      = (const float*)d_in[0];
    const float* lpu_w  = (const float*)d_in[3];
    const float* lpu_b  = (const float*)d_in[4];
    const float* n1_g   = (const float*)d_in[5];
    const float* n1_b   = (const float*)d_in[6];
    const float* c2_w   = (const float*)d_in[7];
    const float* c2_b   = (const float*)d_in[8];
    const float* cn_g   = (const float*)d_in[9];
    const float* cn_b   = (const float*)d_in[10];
    const float* q_w    = (const float*)d_in[11];
    const float* sr1_w  = (const float*)d_in[12];
    const float* sr1_b  = (const float*)d_in[13];
    const float* an1_g  = (const float*)d_in[14];
    const float* an1_b  = (const float*)d_in[15];
    const float* sr2_w  = (const float*)d_in[16];
    const float* sr2_b  = (const float*)d_in[17];
    const float* an2_g  = (const float*)d_in[18];
    const float* an2_b  = (const float*)d_in[19];
    const float* kv1_w  = (const float*)d_in[20];
    const float* kv2_w  = (const float*)d_in[21];
    const float* proj_w = (const float*)d_in[22];
    const float* proj_b = (const float*)d_in[23];
    const float* n2_g   = (const float*)d_in[24];
    const float* n2_b   = (const float*)d_in[25];
    const float* fc1_w  = (const float*)d_in[26];
    const float* fc1_b  = (const float*)d_in[27];
    const float* dw_w   = (const float*)d_in[28];
    const float* dw_b   = (const float*)d_in[29];
    const float* fc2_w  = (const float*)d_in[30];
    const float* fc2_b  = (const float*)d_in[31];
    float* out = (float*)d_out;

    char* ws = (char*)d_ws;
    size_t off = 0;
    auto alloc = [&](size_t elems) {
        float* p = (float*)(ws + off);
        off += ((elems * 4 + 255) & ~(size_t)255);
        return p;
    };
    float* xbuf = alloc((size_t)BNR * CC);   // x after LPU, then x+attn (in place)
    float* ybuf = alloc((size_t)BNR * CC);   // LN outputs (reused for LN1 and LN2)
    size_t zmark = off;                      // z1/z2 overlay everything below
    float* cat  = alloc((size_t)BNR * CC);   // [o1|o2|cp]
    float* qbuf = alloc((size_t)BNR * AD);
    float* x1g  = alloc((size_t)BB * M1 * AD);
    float* x2g  = alloc((size_t)BB * M2 * AD);
    float* kv1o = alloc((size_t)BB * M1 * AD);
    float* kv2o = alloc((size_t)BB * M2 * AD);

    // MLP batch-chunk size: biggest that fits the overlay region
    int CB2 = 1;
    for (int cb = 16; cb >= 1; cb >>= 1) {
        if (zmark + 2 * (size_t)cb * NN * HID * 4 <= ws_size) { CB2 = cb; break; }
    }

    dim3 b256(256);
    // 1. LPU + residual
    lpu_kernel<<<dim3(NN, BB), b256, 0, stream>>>(x, lpu_w, lpu_b, xbuf);
    // 2. LN1
    ln256_kernel<<<dim3(BNR / 4), b256, 0, stream>>>(xbuf, n1_g, n1_b, ybuf);
    // 3. cp branch -> concat cols [192,256)
    cpconv_kernel<<<dim3(NN / 4, BB), b256, 0, stream>>>(ybuf, c2_w, c2_b, cn_g, cn_b, cat);
    // 4. q = ap @ q_w.T
    gemm_kernel<<<dim3(AD / 64, BNR / 64), b256, 0, stream>>>(
        ybuf + CD, CC, q_w, AD, nullptr, nullptr, qbuf, AD, BNR);
    // 5. SR convs + LN + GELU
    sr_kernel<8, 7><<<dim3(M1, BB), dim3(192), 0, stream>>>(ybuf + CD, sr1_w, sr1_b, an1_g, an1_b, x1g);
    sr_kernel<4, 14><<<dim3(M2, BB), dim3(192), 0, stream>>>(ybuf + CD, sr2_w, sr2_b, an2_g, an2_b, x2g);
    // 6. kv GEMMs
    gemm_kernel<<<dim3(AD / 64, (BB * M1 + 63) / 64), b256, 0, stream>>>(
        x1g, AD, kv1_w, AD, nullptr, nullptr, kv1o, AD, BB * M1);
    gemm_kernel<<<dim3(AD / 64, (BB * M2 + 63) / 64), b256, 0, stream>>>(
        x2g, AD, kv2_w, AD, nullptr, nullptr, kv2o, AD, BB * M2);
    // 7. attention -> concat cols [0,192)
    attn_kernel<<<dim3((NN + 255) / 256, NH, BB), b256, 0, stream>>>(qbuf, kv1o, kv2o, cat);
    // 8. proj + bias + residual (in-place into xbuf)
    gemm_kernel<<<dim3(CC / 64, BNR / 64), b256, 0, stream>>>(
        cat, CC, proj_w, CC, proj_b, xbuf, xbuf, CC, BNR);
    // 9. LN2
    ln256_kernel<<<dim3(BNR / 4), b256, 0, stream>>>(xbuf, n2_g, n2_b, ybuf);
    // 10. MLP in batch chunks (z buffers overlay cat/q/kv region)
    float* z1 = (float*)(ws + zmark);
    float* z2 = z1 + (size_t)CB2 * NN * HID;
    for (int c0 = 0; c0 < BB; c0 += CB2) {
        size_t tokoff = (size_t)c0 * NN;
        int Rr = CB2 * NN;
        gemm_kernel<<<dim3(HID / 64, Rr / 64), b256, 0, stream>>>(
            ybuf + tokoff * CC, CC, fc1_w, CC, fc1_b, nullptr, z1, HID, Rr);
        dwconv_kernel<<<dim3(HID / 256, NN, CB2), b256, 0, stream>>>(z1, dw_w, dw_b, z2);
        gemm_kernel<<<dim3(CC / 64, Rr / 64), b256, 0, stream>>>(
            z2, HID, fc2_w, HID, fc2_b, xbuf + tokoff * CC, out + tokoff * CC, CC, Rr);
    }
}

// Round 2
// 1872.858 us; speedup vs baseline: 2.7245x; 2.7245x over previous
//
#include <hip/hip_runtime.h>
#include <math.h>

// Problem constants (B=16, H=W=56, C=256)
#define BB   16
#define HH   56
#define WW   56
#define NN   (HH*WW)        // 3136
#define CC   256
#define CD   64             // conv branch dim
#define AD   192            // attn dim
#define NH   8
#define HG   4
#define HD   24
#define HID  1024
#define M1   49             // 7x7
#define M2   196            // 14x14
#define BNR  (BB*NN)        // 50176 tokens

__device__ __forceinline__ float gelu_f(float x) {
    return 0.5f * x * (1.0f + erff(x * 0.70710678118654752f));
}

// ---------------- LPU: depthwise 3x3 (groups=C) + bias + residual ----------------
__global__ __launch_bounds__(256) void lpu_kernel(const float* __restrict__ x,
        const float* __restrict__ w, const float* __restrict__ bias,
        float* __restrict__ out) {
    int c = threadIdx.x;          // 0..255
    int n = blockIdx.x;           // 0..3135
    int b = blockIdx.y;           // 0..15
    int h = n / WW, wc = n - h * WW;
    const float* xb = x + (size_t)b * NN * CC;
    float acc = bias[c];
#pragma unroll
    for (int ky = 0; ky < 3; ++ky) {
        int hy = h + ky - 1;
        if ((unsigned)hy >= (unsigned)HH) continue;
#pragma unroll
        for (int kx = 0; kx < 3; ++kx) {
            int wx = wc + kx - 1;
            if ((unsigned)wx >= (unsigned)WW) continue;
            acc = fmaf(xb[(size_t)(hy * WW + wx) * CC + c], w[c * 9 + ky * 3 + kx], acc);
        }
    }
    size_t o = (size_t)b * NN * CC + (size_t)n * CC + c;
    out[o] = acc + x[o];
}

// ---------------- LayerNorm over C=256, one wave per token ----------------
__global__ __launch_bounds__(256) void ln256_kernel(const float* __restrict__ x,
        const float* __restrict__ g, const float* __restrict__ bt,
        float* __restrict__ y) {
    int lane = threadIdx.x & 63;
    int tok = blockIdx.x * 4 + (threadIdx.x >> 6);
    const float4 v = *(const float4*)(x + (size_t)tok * CC + lane * 4);
    float s = v.x + v.y + v.z + v.w;
    float sq = v.x * v.x + v.y * v.y + v.z * v.z + v.w * v.w;
#pragma unroll
    for (int off = 32; off >= 1; off >>= 1) {
        s += __shfl_xor(s, off, 64);
        sq += __shfl_xor(sq, off, 64);
    }
    float mean = s * (1.0f / 256.0f);
    float var = sq * (1.0f / 256.0f) - mean * mean;
    float rstd = rsqrtf(var + 1e-5f);
    float4 gv = *(const float4*)(g + lane * 4);
    float4 bv = *(const float4*)(bt + lane * 4);
    float4 o;
    o.x = (v.x - mean) * rstd * gv.x + bv.x;
    o.y = (v.y - mean) * rstd * gv.y + bv.y;
    o.z = (v.z - mean) * rstd * gv.z + bv.z;
    o.w = (v.w - mean) * rstd * gv.w + bv.w;
    *(float4*)(y + (size_t)tok * CC + lane * 4) = o;
}

// ---------------- cp weight transform: wt[co][tap*64+ci] = w[co][ci*9+tap] ----------------
__global__ __launch_bounds__(256) void cpwt_kernel(const float* __restrict__ w,
        float* __restrict__ wt) {
    int idx = blockIdx.x * 256 + threadIdx.x;
    if (idx >= 64 * 576) return;
    int co = idx / 576, k = idx - co * 576;
    int tap = k >> 6, ci = k & 63;
    wt[idx] = w[co * 576 + ci * 9 + tap];
}

// ---------------- cp branch as implicit GEMM: (BNR,576) x (64,576)^T ----------------
// A gathered on-the-fly from ybuf cols [0,64); k = tap*64 + ci so A-stage is float4.
__global__ __launch_bounds__(256) void cpgemm_kernel(
        const float* __restrict__ y,   // (BNR,256), conv input in cols [0,64)
        const float* __restrict__ wt,  // (64,576) transformed weights
        const float* __restrict__ cb,
        float* __restrict__ cbuf) {    // (BNR,64) conv output + bias
    __shared__ float As[16][64];
    __shared__ float Ws[16][64];
    int tid = threadIdx.x;
    int tx = tid & 15, ty = tid >> 4;
    int rt = blockIdx.x * 64;
    int lr = tid & 63, lk = (tid >> 6) << 2;
    int ar = rt + lr;                  // BNR % 64 == 0, always valid
    int b = ar / NN, n = ar - b * NN;
    int h = n / WW, wc = n - h * WW;
    const float* Wp = wt + (size_t)lr * 576 + lk;
    float acc[4][4] = {};
    for (int kt = 0; kt < 576; kt += 16) {
        int k = kt + lk;
        int tap = k >> 6, ci = k & 63;
        int t3 = tap / 3;
        int hy = h + t3 - 1, wx = wc + (tap - t3 * 3) - 1;
        float4 av = make_float4(0.f, 0.f, 0.f, 0.f);
        if ((unsigned)hy < (unsigned)HH && (unsigned)wx < (unsigned)WW)
            av = *(const float4*)(y + ((size_t)b * NN + hy * WW + wx) * CC + ci);
        float4 wv = *(const float4*)(Wp + kt);
        __syncthreads();
        As[lk + 0][lr] = av.x; As[lk + 1][lr] = av.y;
        As[lk + 2][lr] = av.z; As[lk + 3][lr] = av.w;
        Ws[lk + 0][lr] = wv.x; Ws[lk + 1][lr] = wv.y;
        Ws[lk + 2][lr] = wv.z; Ws[lk + 3][lr] = wv.w;
        __syncthreads();
#pragma unroll
        for (int kk = 0; kk < 16; ++kk) {
            float4 a4 = *(const float4*)&As[kk][ty << 2];
            float4 w4 = *(const float4*)&Ws[kk][tx << 2];
            float aa[4] = {a4.x, a4.y, a4.z, a4.w};
            float ww[4] = {w4.x, w4.y, w4.z, w4.w};
#pragma unroll
            for (int i = 0; i < 4; ++i)
#pragma unroll
                for (int j = 0; j < 4; ++j)
                    acc[i][j] = fmaf(aa[i], ww[j], acc[i][j]);
        }
    }
#pragma unroll
    for (int i = 0; i < 4; ++i) {
        int r = rt + (ty << 2) + i;
#pragma unroll
        for (int j = 0; j < 4; ++j) {
            int o = (tx << 2) + j;
            cbuf[(size_t)r * 64 + o] = acc[i][j] + cb[o];
        }
    }
}

// ---------------- LN(64) + GELU epilogue for cp branch -> cat cols [192,256) ----------------
__global__ __launch_bounds__(256) void ln64gelu_kernel(const float* __restrict__ cbuf,
        const float* __restrict__ g, const float* __restrict__ bt,
        float* __restrict__ cat) {
    int lane = threadIdx.x & 63;
    int tok = blockIdx.x * 4 + (threadIdx.x >> 6);
    float v = cbuf[(size_t)tok * 64 + lane];
    float s = v, sq = v * v;
#pragma unroll
    for (int off = 32; off >= 1; off >>= 1) {
        s += __shfl_xor(s, off, 64);
        sq += __shfl_xor(sq, off, 64);
    }
    float mean = s * (1.0f / 64.0f);
    float var = sq * (1.0f / 64.0f) - mean * mean;
    float rstd = rsqrtf(var + 1e-5f);
    float o = (v - mean) * rstd * g[lane] + bt[lane];
    cat[(size_t)tok * CC + 192 + lane] = gelu_f(o);
}

// ---------------- SR conv (depthwise KSxKS stride KS) + LN(192) + GELU ----------------
template <int KS, int OW>
__global__ __launch_bounds__(192) void sr_kernel(const float* __restrict__ yap,
        const float* __restrict__ w, const float* __restrict__ bias,
        const float* __restrict__ g, const float* __restrict__ bt,
        float* __restrict__ out) {
    int ch = threadIdx.x;  // 0..191
    int m = blockIdx.x, b = blockIdx.y;
    int oh = m / OW, ow = m - oh * OW;
    const float* yb = yap + (size_t)b * NN * CC;
    float acc = bias[ch];
#pragma unroll
    for (int ky = 0; ky < KS; ++ky)
#pragma unroll
        for (int kx = 0; kx < KS; ++kx)
            acc = fmaf(yb[(size_t)((oh * KS + ky) * WW + ow * KS + kx) * CC + ch],
                       w[ch * KS * KS + ky * KS + kx], acc);
    __shared__ float red[2][3];
    float s = acc, sq = acc * acc;
#pragma unroll
    for (int off = 32; off >= 1; off >>= 1) {
        s += __shfl_xor(s, off, 64);
        sq += __shfl_xor(sq, off, 64);
    }
    int wv = threadIdx.x >> 6, lane = threadIdx.x & 63;
    if (lane == 0) { red[0][wv] = s; red[1][wv] = sq; }
    __syncthreads();
    s = red[0][0] + red[0][1] + red[0][2];
    sq = red[1][0] + red[1][1] + red[1][2];
    float mean = s * (1.0f / 192.0f);
    float var = sq * (1.0f / 192.0f) - mean * mean;
    float rstd = rsqrtf(var + 1e-5f);
    float v = (acc - mean) * rstd * g[ch] + bt[ch];
    out[((size_t)b * (OW * OW) + m) * AD + ch] = gelu_f(v);
}

// ---------------- generic tiled GEMM: C[r,o] = A[r,:K].W[o,:K] (+bias) (+res) ----------------
__global__ __launch_bounds__(256) void gemm_kernel(
        const float* __restrict__ A, int lda,
        const float* __restrict__ W, int K,
        const float* __restrict__ bias,
        const float* __restrict__ res,   // nullable; row stride = ldc
        float* __restrict__ C, int ldc, int R) {
    __shared__ float As[16][64];
    __shared__ float Ws[16][64];
    int tid = threadIdx.x;
    int tx = tid & 15, ty = tid >> 4;
    int ot = blockIdx.x * 64, rt = blockIdx.y * 64;
    int lr = tid & 63, lk = (tid >> 6) << 2;
    int ar = rt + lr;
    if (ar > R - 1) ar = R - 1;   // clamp OOB rows (values unused)
    const float* Ap = A + (size_t)ar * lda + lk;
    const float* Wp = W + (size_t)(ot + lr) * K + lk;
    float acc[4][4] = {};
    for (int kt = 0; kt < K; kt += 16) {
        float4 av = *(const float4*)(Ap + kt);
        float4 wv = *(const float4*)(Wp + kt);
        __syncthreads();
        As[lk + 0][lr] = av.x; As[lk + 1][lr] = av.y;
        As[lk + 2][lr] = av.z; As[lk + 3][lr] = av.w;
        Ws[lk + 0][lr] = wv.x; Ws[lk + 1][lr] = wv.y;
        Ws[lk + 2][lr] = wv.z; Ws[lk + 3][lr] = wv.w;
        __syncthreads();
#pragma unroll
        for (int kk = 0; kk < 16; ++kk) {
            float4 a4 = *(const float4*)&As[kk][ty << 2];
            float4 w4 = *(const float4*)&Ws[kk][tx << 2];
            float aa[4] = {a4.x, a4.y, a4.z, a4.w};
            float ww[4] = {w4.x, w4.y, w4.z, w4.w};
#pragma unroll
            for (int i = 0; i < 4; ++i)
#pragma unroll
                for (int j = 0; j < 4; ++j)
                    acc[i][j] = fmaf(aa[i], ww[j], acc[i][j]);
        }
    }
#pragma unroll
    for (int i = 0; i < 4; ++i) {
        int r = rt + (ty << 2) + i;
        if (r >= R) continue;
#pragma unroll
        for (int j = 0; j < 4; ++j) {
            int o = ot + (tx << 2) + j;
            float v = acc[i][j];
            if (bias) v += bias[o];
            if (res) v += res[(size_t)r * ldc + o];
            C[(size_t)r * ldc + o] = v;
        }
    }
}

// ---------------- attention: per (n-tile, head, batch) block; K/V in LDS ----------------
__global__ __launch_bounds__(256) void attn_kernel(const float* __restrict__ q,
        const float* __restrict__ kv1, const float* __restrict__ kv2,
        float* __restrict__ cat) {
    __shared__ float sk[M2 * HD];
    __shared__ float sv[M2 * HD];
    int h = blockIdx.y, b = blockIdx.z;
    int M = (h < HG) ? M1 : M2;
    const float* kvo = (h < HG) ? kv1 : kv2;
    int g = (h < HG) ? h : h - HG;
    int tot = M * HD;
    for (int idx = threadIdx.x; idx < tot; idx += 256) {
        int m = idx / HD, d = idx - m * HD;
        sk[idx] = kvo[((size_t)b * M + m) * AD + g * HD + d];
        sv[idx] = kvo[((size_t)b * M + m) * AD + 96 + g * HD + d];
    }
    __syncthreads();
    int n = blockIdx.x * 256 + threadIdx.x;
    if (n >= NN) return;
    float qv[HD];
    const float* qr = q + ((size_t)b * NN + n) * AD + h * HD;
#pragma unroll
    for (int d = 0; d < HD; ++d) qv[d] = qr[d];
    const float scale = 0.20412414523193154f;  // 24^-0.5
    float mx = -1e30f;
    for (int m = 0; m < M; ++m) {
        float s = 0.f;
        const float* kr = sk + m * HD;
#pragma unroll
        for (int d = 0; d < HD; ++d) s = fmaf(qv[d], kr[d], s);
        mx = fmaxf(mx, s * scale);
    }
    float sum = 0.f;
    float acc[HD] = {};
    for (int m = 0; m < M; ++m) {
        float s = 0.f;
        const float* kr = sk + m * HD;
#pragma unroll
        for (int d = 0; d < HD; ++d) s = fmaf(qv[d], kr[d], s);
        float p = expf(s * scale - mx);
        sum += p;
        const float* vr = sv + m * HD;
#pragma unroll
        for (int d = 0; d < HD; ++d) acc[d] = fmaf(p, vr[d], acc[d]);
    }
    float inv = 1.0f / sum;
    float* o = cat + ((size_t)b * NN + n) * CC + h * HD;
#pragma unroll
    for (int d = 0; d < HD; ++d) o[d] = acc[d] * inv;
}

// ---------------- depthwise 3x3 on hid=1024 channels + bias + GELU ----------------
__global__ __launch_bounds__(256) void dwconv_kernel(const float* __restrict__ z1,
        const float* __restrict__ w, const float* __restrict__ bias,
        float* __restrict__ z2) {
    int c = blockIdx.x * 256 + threadIdx.x;  // 0..1023
    int n = blockIdx.y;
    int b = blockIdx.z;
    int h = n / WW, wc = n - h * WW;
    const float* zb = z1 + (size_t)b * NN * HID;
    float acc = bias[c];
#pragma unroll
    for (int ky = 0; ky < 3; ++ky) {
        int hy = h + ky - 1;
        if ((unsigned)hy >= (unsigned)HH) continue;
#pragma unroll
        for (int kx = 0; kx < 3; ++kx) {
            int wx = wc + kx - 1;
            if ((unsigned)wx >= (unsigned)WW) continue;
            acc = fmaf(zb[(size_t)(hy * WW + wx) * HID + c], w[c * 9 + ky * 3 + kx], acc);
        }
    }
    z2[(size_t)b * NN * HID + (size_t)n * HID + c] = gelu_f(acc);
}

extern "C" void kernel_launch(void* const* d_in, const int* in_sizes, int n_in,
                              void* d_out, int out_size, void* d_ws, size_t ws_size,
                              hipStream_t stream) {
    const float* x      = (const float*)d_in[0];
    const float* lpu_w  = (const float*)d_in[3];
    const float* lpu_b  = (const float*)d_in[4];
    const float* n1_g   = (const float*)d_in[5];
    const float* n1_b   = (const float*)d_in[6];
    const float* c2_w   = (const float*)d_in[7];
    const float* c2_b   = (const float*)d_in[8];
    const float* cn_g   = (const float*)d_in[9];
    const float* cn_b   = (const float*)d_in[10];
    const float* q_w    = (const float*)d_in[11];
    const float* sr1_w  = (const float*)d_in[12];
    const float* sr1_b  = (const float*)d_in[13];
    const float* an1_g  = (const float*)d_in[14];
    const float* an1_b  = (const float*)d_in[15];
    const float* sr2_w  = (const float*)d_in[16];
    const float* sr2_b  = (const float*)d_in[17];
    const float* an2_g  = (const float*)d_in[18];
    const float* an2_b  = (const float*)d_in[19];
    const float* kv1_w  = (const float*)d_in[20];
    const float* kv2_w  = (const float*)d_in[21];
    const float* proj_w = (const float*)d_in[22];
    const float* proj_b = (const float*)d_in[23];
    const float* n2_g   = (const float*)d_in[24];
    const float* n2_b   = (const float*)d_in[25];
    const float* fc1_w  = (const float*)d_in[26];
    const float* fc1_b  = (const float*)d_in[27];
    const float* dw_w   = (const float*)d_in[28];
    const float* dw_b   = (const float*)d_in[29];
    const float* fc2_w  = (const float*)d_in[30];
    const float* fc2_b  = (const float*)d_in[31];
    float* out = (float*)d_out;

    char* ws = (char*)d_ws;
    size_t off = 0;
    auto alloc = [&](size_t elems) {
        float* p = (float*)(ws + off);
        off += ((elems * 4 + 255) & ~(size_t)255);
        return p;
    };
    float* xbuf = alloc((size_t)BNR * CC);   // x after LPU, then x+attn (in place)
    float* ybuf = alloc((size_t)BNR * CC);   // LN outputs (reused for LN1 and LN2)
    size_t zmark = off;                      // z1/z2 overlay everything below
    float* cat  = alloc((size_t)BNR * CC);   // [o1|o2|cp]
    float* qbuf = alloc((size_t)BNR * AD);
    float* x1g  = alloc((size_t)BB * M1 * AD);
    float* x2g  = alloc((size_t)BB * M2 * AD);
    float* kv1o = alloc((size_t)BB * M1 * AD);
    float* kv2o = alloc((size_t)BB * M2 * AD);
    float* wt   = alloc((size_t)64 * 576);   // transformed cp weights
    float* cbuf = alloc((size_t)BNR * CD);   // cp conv output pre-LN

    // MLP batch-chunk size: biggest that fits the overlay region
    int CB2 = 1;
    for (int cb = 16; cb >= 1; cb >>= 1) {
        if (zmark + 2 * (size_t)cb * NN * HID * 4 <= ws_size) { CB2 = cb; break; }
    }

    dim3 b256(256);
    // 0. cp weight transform (independent of data path)
    cpwt_kernel<<<dim3(144), b256, 0, stream>>>(c2_w, wt);
    // 1. LPU + residual
    lpu_kernel<<<dim3(NN, BB), b256, 0, stream>>>(x, lpu_w, lpu_b, xbuf);
    // 2. LN1
    ln256_kernel<<<dim3(BNR / 4), b256, 0, stream>>>(xbuf, n1_g, n1_b, ybuf);
    // 3. cp branch: implicit GEMM conv, then LN64+GELU -> cat cols [192,256)
    cpgemm_kernel<<<dim3(BNR / 64), b256, 0, stream>>>(ybuf, wt, c2_b, cbuf);
    ln64gelu_kernel<<<dim3(BNR / 4), b256, 0, stream>>>(cbuf, cn_g, cn_b, cat);
    // 4. q = ap @ q_w.T
    gemm_kernel<<<dim3(AD / 64, BNR / 64), b256, 0, stream>>>(
        ybuf + CD, CC, q_w, AD, nullptr, nullptr, qbuf, AD, BNR);
    // 5. SR convs + LN + GELU
    sr_kernel<8, 7><<<dim3(M1, BB), dim3(192), 0, stream>>>(ybuf + CD, sr1_w, sr1_b, an1_g, an1_b, x1g);
    sr_kernel<4, 14><<<dim3(M2, BB), dim3(192), 0, stream>>>(ybuf + CD, sr2_w, sr2_b, an2_g, an2_b, x2g);
    // 6. kv GEMMs
    gemm_kernel<<<dim3(AD / 64, (BB * M1 + 63) / 64), b256, 0, stream>>>(
        x1g, AD, kv1_w, AD, nullptr, nullptr, kv1o, AD, BB * M1);
    gemm_kernel<<<dim3(AD / 64, (BB * M2 + 63) / 64), b256, 0, stream>>>(
        x2g, AD, kv2_w, AD, nullptr, nullptr, kv2o, AD, BB * M2);
    // 7. attention -> cat cols [0,192)
    attn_kernel<<<dim3((NN + 255) / 256, NH, BB), b256, 0, stream>>>(qbuf, kv1o, kv2o, cat);
    // 8. proj + bias + residual (in-place into xbuf)
    gemm_kernel<<<dim3(CC / 64, BNR / 64), b256, 0, stream>>>(
        cat, CC, proj_w, CC, proj_b, xbuf, xbuf, CC, BNR);
    // 9. LN2
    ln256_kernel<<<dim3(BNR / 4), b256, 0, stream>>>(xbuf, n2_g, n2_b, ybuf);
    // 10. MLP in batch chunks (z buffers overlay cat/q/kv region)
    float* z1 = (float*)(ws + zmark);
    float* z2 = z1 + (size_t)CB2 * NN * HID;
    for (int c0 = 0; c0 < BB; c0 += CB2) {
        size_t tokoff = (size_t)c0 * NN;
        int Rr = CB2 * NN;
        gemm_kernel<<<dim3(HID / 64, Rr / 64), b256, 0, stream>>>(
            ybuf + tokoff * CC, CC, fc1_w, CC, fc1_b, nullptr, z1, HID, Rr);
        dwconv_kernel<<<dim3(HID / 256, NN, CB2), b256, 0, stream>>>(z1, dw_w, dw_b, z2);
        gemm_kernel<<<dim3(CC / 64, Rr / 64), b256, 0, stream>>>(
            z2, HID, fc2_w, HID, fc2_b, xbuf + tokoff * CC, out + tokoff * CC, CC, Rr);
    }
}

// Round 4
// 1065.722 us; speedup vs baseline: 4.7879x; 1.7574x over previous
//
#include <hip/hip_runtime.h>
#include <math.h>

// Problem constants (B=16, H=W=56, C=256)
#define BB   16
#define HH   56
#define WW   56
#define NN   (HH*WW)        // 3136
#define CC   256
#define CD   64
#define AD   192
#define NH   8
#define HG   4
#define HD   24
#define HID  1024
#define M1   49
#define M2   196
#define BNR  (BB*NN)        // 50176

typedef __attribute__((ext_vector_type(8))) short s8v;   // 8 bf16
typedef __attribute__((ext_vector_type(4))) short s4v;
typedef __attribute__((ext_vector_type(4))) float f4v;

__device__ __forceinline__ float gelu_f(float x) {
    return 0.5f * x * (1.0f + erff(x * 0.70710678118654752f));
}
__device__ __forceinline__ ushort f2bf(float f) {
    union { float f; uint32_t u; } c; c.f = f;
    uint32_t u = c.u;
    return (ushort)((u + 0x7fffu + ((u >> 16) & 1u)) >> 16);
}
__device__ __forceinline__ float bf2f(ushort u) {
    union { uint32_t u; float f; } c; c.u = ((uint32_t)u) << 16;
    return c.f;
}

// ---------------- generic f32 -> bf16 convert ----------------
__global__ __launch_bounds__(256) void cvt_kernel(const float* __restrict__ src,
        ushort* __restrict__ dst, int n) {
    for (int i = blockIdx.x * 256 + threadIdx.x; i < n; i += gridDim.x * 256)
        dst[i] = f2bf(src[i]);
}

// ---------------- cp weight transform: wt[co][tap*64+ci] = w[co][ci*9+tap] ----------------
__global__ __launch_bounds__(256) void cpwt_kernel(const float* __restrict__ w,
        ushort* __restrict__ wt) {
    int idx = blockIdx.x * 256 + threadIdx.x;
    if (idx >= 64 * 576) return;
    int co = idx / 576, k = idx - co * 576;
    int tap = k >> 6, ci = k & 63;
    wt[idx] = f2bf(w[co * 576 + ci * 9 + tap]);
}

// ---------------- LPU: depthwise 3x3 + bias + residual (fp32) ----------------
__global__ __launch_bounds__(256) void lpu_kernel(const float* __restrict__ x,
        const float* __restrict__ w, const float* __restrict__ bias,
        float* __restrict__ out) {
    int c = threadIdx.x;
    int n = blockIdx.x;
    int b = blockIdx.y;
    int h = n / WW, wc = n - h * WW;
    const float* xb = x + (size_t)b * NN * CC;
    float acc = bias[c];
#pragma unroll
    for (int ky = 0; ky < 3; ++ky) {
        int hy = h + ky - 1;
        if ((unsigned)hy >= (unsigned)HH) continue;
#pragma unroll
        for (int kx = 0; kx < 3; ++kx) {
            int wx = wc + kx - 1;
            if ((unsigned)wx >= (unsigned)WW) continue;
            acc = fmaf(xb[(size_t)(hy * WW + wx) * CC + c], w[c * 9 + ky * 3 + kx], acc);
        }
    }
    size_t o = (size_t)b * NN * CC + (size_t)n * CC + c;
    out[o] = acc + x[o];
}

// ---------------- LayerNorm over C=256, fp32 in, bf16 out ----------------
__global__ __launch_bounds__(256) void ln256_kernel(const float* __restrict__ x,
        const float* __restrict__ g, const float* __restrict__ bt,
        ushort* __restrict__ y) {
    int lane = threadIdx.x & 63;
    int tok = blockIdx.x * 4 + (threadIdx.x >> 6);
    const float4 v = *(const float4*)(x + (size_t)tok * CC + lane * 4);
    float s = v.x + v.y + v.z + v.w;
    float sq = v.x * v.x + v.y * v.y + v.z * v.z + v.w * v.w;
#pragma unroll
    for (int off = 32; off >= 1; off >>= 1) {
        s += __shfl_xor(s, off, 64);
        sq += __shfl_xor(sq, off, 64);
    }
    float mean = s * (1.0f / 256.0f);
    float var = sq * (1.0f / 256.0f) - mean * mean;
    float rstd = rsqrtf(var + 1e-5f);
    float4 gv = *(const float4*)(g + lane * 4);
    float4 bv = *(const float4*)(bt + lane * 4);
    s4v o;
    o.x = (short)f2bf((v.x - mean) * rstd * gv.x + bv.x);
    o.y = (short)f2bf((v.y - mean) * rstd * gv.y + bv.y);
    o.z = (short)f2bf((v.z - mean) * rstd * gv.z + bv.z);
    o.w = (short)f2bf((v.w - mean) * rstd * gv.w + bv.w);
    *(s4v*)(y + (size_t)tok * CC + lane * 4) = o;
}

// ---------------- cp branch: implicit-GEMM conv via MFMA ----------------
// A (BNR x 576) gathered from ybuf bf16 cols [0,64); W = wt (64 x 576) bf16.
// Tile 128x64, BK=32, 4 waves (each 32 rows x 64 cols). Out cbuf fp32 + bias.
__global__ __launch_bounds__(256) void cpgemm_kernel(
        const ushort* __restrict__ y, const ushort* __restrict__ wt,
        const float* __restrict__ cb, float* __restrict__ cbuf) {
    __shared__ __align__(16) ushort As[128 * 32];
    __shared__ __align__(16) ushort Ws[64 * 32];
    int tid = threadIdx.x;
    int wid = tid >> 6, lane = tid & 63;
    int rt = blockIdx.x * 128;
    // staging geometry: A has 512 16B-units (2/thread), W has 256 (1/thread)
    int u0 = tid, u1 = tid + 256;
    int r0 = u0 >> 2, c0 = u0 & 3;
    int r1 = u1 >> 2, c1 = u1 & 3;
    int tok0 = rt + r0, tok1 = rt + r1;
    int b0 = tok0 / NN, n0 = tok0 - b0 * NN, h0 = n0 / WW, w0 = n0 - h0 * WW;
    int b1 = tok1 / NN, n1 = tok1 - b1 * NN, h1 = n1 / WW, w1 = n1 - h1 * WW;
    int wr0 = tid >> 2, wc0 = tid & 3;         // W unit
    const ushort* Wp = wt + (size_t)wr0 * 576 + wc0 * 8;
    f4v acc[2][4];
#pragma unroll
    for (int m = 0; m < 2; ++m)
#pragma unroll
        for (int n = 0; n < 4; ++n) acc[m][n] = (f4v)0.f;
    int lr = lane & 15, lk = (lane >> 4) * 8;
    for (int kt = 0; kt < 576; kt += 32) {
        int tap = kt >> 6, ci0 = kt & 63;
        int t3 = tap / 3, dy = t3 - 1, dx = (tap - t3 * 3) - 1;
        s8v a0 = (s8v)0, a1 = (s8v)0;
        int hy0 = h0 + dy, wx0 = w0 + dx;
        if ((unsigned)hy0 < (unsigned)HH && (unsigned)wx0 < (unsigned)WW)
            a0 = *(const s8v*)(y + ((size_t)b0 * NN + hy0 * WW + wx0) * CC + ci0 + c0 * 8);
        int hy1 = h1 + dy, wx1 = w1 + dx;
        if ((unsigned)hy1 < (unsigned)HH && (unsigned)wx1 < (unsigned)WW)
            a1 = *(const s8v*)(y + ((size_t)b1 * NN + hy1 * WW + wx1) * CC + ci0 + c1 * 8);
        s8v wv = *(const s8v*)(Wp + kt);
        __syncthreads();
        *(s8v*)&As[r0 * 32 + c0 * 8] = a0;
        *(s8v*)&As[r1 * 32 + c1 * 8] = a1;
        *(s8v*)&Ws[wr0 * 32 + wc0 * 8] = wv;
        __syncthreads();
        s8v af[2], bf[4];
#pragma unroll
        for (int m = 0; m < 2; ++m)
            af[m] = *(const s8v*)&As[(wid * 32 + m * 16 + lr) * 32 + lk];
#pragma unroll
        for (int n = 0; n < 4; ++n)
            bf[n] = *(const s8v*)&Ws[(n * 16 + lr) * 32 + lk];
#pragma unroll
        for (int m = 0; m < 2; ++m)
#pragma unroll
            for (int n = 0; n < 4; ++n)
                acc[m][n] = __builtin_amdgcn_mfma_f32_16x16x32_bf16(af[m], bf[n], acc[m][n], 0, 0, 0);
    }
#pragma unroll
    for (int m = 0; m < 2; ++m)
#pragma unroll
        for (int n = 0; n < 4; ++n) {
            int gr = rt + wid * 32 + m * 16 + (lane >> 4) * 4;
            int gc = n * 16 + (lane & 15);
#pragma unroll
            for (int r = 0; r < 4; ++r)
                cbuf[(size_t)(gr + r) * 64 + gc] = acc[m][n][r] + cb[gc];
        }
}

// ---------------- LN(64)+GELU epilogue: cbuf fp32 -> cat bf16 cols [192,256) ----------------
__global__ __launch_bounds__(256) void ln64gelu_kernel(const float* __restrict__ cbuf,
        const float* __restrict__ g, const float* __restrict__ bt,
        ushort* __restrict__ cat) {
    int lane = threadIdx.x & 63;
    int tok = blockIdx.x * 4 + (threadIdx.x >> 6);
    float v = cbuf[(size_t)tok * 64 + lane];
    float s = v, sq = v * v;
#pragma unroll
    for (int off = 32; off >= 1; off >>= 1) {
        s += __shfl_xor(s, off, 64);
        sq += __shfl_xor(sq, off, 64);
    }
    float mean = s * (1.0f / 64.0f);
    float var = sq * (1.0f / 64.0f) - mean * mean;
    float rstd = rsqrtf(var + 1e-5f);
    float o = (v - mean) * rstd * g[lane] + bt[lane];
    cat[(size_t)tok * CC + 192 + lane] = f2bf(gelu_f(o));
}

// ---------------- SR conv (depthwise KSxKS stride KS) + LN(192) + GELU, bf16 io ----------------
template <int KS, int OW>
__global__ __launch_bounds__(192) void sr_kernel(const ushort* __restrict__ yap,
        const float* __restrict__ w, const float* __restrict__ bias,
        const float* __restrict__ g, const float* __restrict__ bt,
        ushort* __restrict__ out) {
    int ch = threadIdx.x;
    int m = blockIdx.x, b = blockIdx.y;
    int oh = m / OW, ow = m - oh * OW;
    const ushort* yb = yap + (size_t)b * NN * CC;
    float acc = bias[ch];
#pragma unroll
    for (int ky = 0; ky < KS; ++ky)
#pragma unroll
        for (int kx = 0; kx < KS; ++kx)
            acc = fmaf(bf2f(yb[(size_t)((oh * KS + ky) * WW + ow * KS + kx) * CC + ch]),
                       w[ch * KS * KS + ky * KS + kx], acc);
    __shared__ float red[2][3];
    float s = acc, sq = acc * acc;
#pragma unroll
    for (int off = 32; off >= 1; off >>= 1) {
        s += __shfl_xor(s, off, 64);
        sq += __shfl_xor(sq, off, 64);
    }
    int wv = threadIdx.x >> 6, lane = threadIdx.x & 63;
    if (lane == 0) { red[0][wv] = s; red[1][wv] = sq; }
    __syncthreads();
    s = red[0][0] + red[0][1] + red[0][2];
    sq = red[1][0] + red[1][1] + red[1][2];
    float mean = s * (1.0f / 192.0f);
    float var = sq * (1.0f / 192.0f) - mean * mean;
    float rstd = rsqrtf(var + 1e-5f);
    float v = (acc - mean) * rstd * g[ch] + bt[ch];
    out[((size_t)b * (OW * OW) + m) * AD + ch] = f2bf(gelu_f(v));
}

// ---------------- generic MFMA GEMM: C[r,o] = sum_k A[r,k]*W[o,k] ----------------
// bf16 A (R x lda), bf16 W (O x K). Tile 128x128, BK=32, 4 waves (2x2), 4x4 frags.
// MODE bits: 1=bias(fp32), 2=residual(fp32, stride ldr), 4=output bf16 (else fp32)
template <int MODE>
__global__ __launch_bounds__(256) void gemm_mfma(
        const ushort* __restrict__ A, int lda,
        const ushort* __restrict__ W, int K, int O,
        const float* __restrict__ bias,
        const float* __restrict__ res, int ldr,
        void* __restrict__ Cout, int ldc, int R) {
    __shared__ __align__(16) ushort As[128 * 32];
    __shared__ __align__(16) ushort Ws[128 * 32];
    int tid = threadIdx.x;
    int wid = tid >> 6, lane = tid & 63;
    int wr = wid >> 1, wc = wid & 1;
    int rt = blockIdx.y * 128, ot = blockIdx.x * 128;
    int u0 = tid, u1 = tid + 256;
    int r0 = u0 >> 2, c0 = u0 & 3;
    int r1 = u1 >> 2, c1 = u1 & 3;
    const ushort* Ap0 = A + (size_t)min(rt + r0, R - 1) * lda + c0 * 8;
    const ushort* Ap1 = A + (size_t)min(rt + r1, R - 1) * lda + c1 * 8;
    const ushort* Wp0 = W + (size_t)min(ot + r0, O - 1) * K + c0 * 8;
    const ushort* Wp1 = W + (size_t)min(ot + r1, O - 1) * K + c1 * 8;
    f4v acc[4][4];
#pragma unroll
    for (int m = 0; m < 4; ++m)
#pragma unroll
        for (int n = 0; n < 4; ++n) acc[m][n] = (f4v)0.f;
    int lr = lane & 15, lk = (lane >> 4) * 8;
    for (int kt = 0; kt < K; kt += 32) {
        s8v a0 = *(const s8v*)(Ap0 + kt);
        s8v a1 = *(const s8v*)(Ap1 + kt);
        s8v w0 = *(const s8v*)(Wp0 + kt);
        s8v w1 = *(const s8v*)(Wp1 + kt);
        __syncthreads();
        *(s8v*)&As[r0 * 32 + c0 * 8] = a0;
        *(s8v*)&As[r1 * 32 + c1 * 8] = a1;
        *(s8v*)&Ws[r0 * 32 + c0 * 8] = w0;
        *(s8v*)&Ws[r1 * 32 + c1 * 8] = w1;
        __syncthreads();
        s8v af[4], bf[4];
#pragma unroll
        for (int m = 0; m < 4; ++m)
            af[m] = *(const s8v*)&As[(wr * 64 + m * 16 + lr) * 32 + lk];
#pragma unroll
        for (int n = 0; n < 4; ++n)
            bf[n] = *(const s8v*)&Ws[(wc * 64 + n * 16 + lr) * 32 + lk];
#pragma unroll
        for (int m = 0; m < 4; ++m)
#pragma unroll
            for (int n = 0; n < 4; ++n)
                acc[m][n] = __builtin_amdgcn_mfma_f32_16x16x32_bf16(af[m], bf[n], acc[m][n], 0, 0, 0);
    }
#pragma unroll
    for (int m = 0; m < 4; ++m)
#pragma unroll
        for (int n = 0; n < 4; ++n) {
            int gr = rt + wr * 64 + m * 16 + (lane >> 4) * 4;
            int gc = ot + wc * 64 + n * 16 + (lane & 15);
            if (gc >= O) continue;
#pragma unroll
            for (int r = 0; r < 4; ++r) {
                int row = gr + r;
                if (row >= R) continue;
                float v = acc[m][n][r];
                if (MODE & 1) v += bias[gc];
                if (MODE & 2) v += res[(size_t)row * ldr + gc];
                if (MODE & 4) ((ushort*)Cout)[(size_t)row * ldc + gc] = f2bf(v);
                else          ((float*)Cout)[(size_t)row * ldc + gc] = v;
            }
        }
}

// ---------------- attention: q bf16, kv fp32 in LDS, out cat bf16 ----------------
__global__ __launch_bounds__(256) void attn_kernel(const ushort* __restrict__ q,
        const float* __restrict__ kv1, const float* __restrict__ kv2,
        ushort* __restrict__ cat) {
    __shared__ float sk[M2 * HD];
    __shared__ float sv[M2 * HD];
    int h = blockIdx.y, b = blockIdx.z;
    int M = (h < HG) ? M1 : M2;
    const float* kvo = (h < HG) ? kv1 : kv2;
    int g = (h < HG) ? h : h - HG;
    int tot = M * HD;
    for (int idx = threadIdx.x; idx < tot; idx += 256) {
        int m = idx / HD, d = idx - m * HD;
        sk[idx] = kvo[((size_t)b * M + m) * AD + g * HD + d];
        sv[idx] = kvo[((size_t)b * M + m) * AD + 96 + g * HD + d];
    }
    __syncthreads();
    int n = blockIdx.x * 256 + threadIdx.x;
    if (n >= NN) return;
    float qv[HD];
    const ushort* qr = q + ((size_t)b * NN + n) * AD + h * HD;
#pragma unroll
    for (int d = 0; d < HD; ++d) qv[d] = bf2f(qr[d]);
    const float scale = 0.20412414523193154f;  // 24^-0.5
    float mx = -1e30f;
    for (int m = 0; m < M; ++m) {
        float s = 0.f;
        const float* kr = sk + m * HD;
#pragma unroll
        for (int d = 0; d < HD; ++d) s = fmaf(qv[d], kr[d], s);
        mx = fmaxf(mx, s * scale);
    }
    float sum = 0.f;
    float acc[HD] = {};
    for (int m = 0; m < M; ++m) {
        float s = 0.f;
        const float* kr = sk + m * HD;
#pragma unroll
        for (int d = 0; d < HD; ++d) s = fmaf(qv[d], kr[d], s);
        float p = expf(s * scale - mx);
        sum += p;
        const float* vr = sv + m * HD;
#pragma unroll
        for (int d = 0; d < HD; ++d) acc[d] = fmaf(p, vr[d], acc[d]);
    }
    float inv = 1.0f / sum;
    ushort* o = cat + ((size_t)b * NN + n) * CC + h * HD;
#pragma unroll
    for (int d = 0; d < HD; ++d) o[d] = f2bf(acc[d] * inv);
}

// ---------------- depthwise 3x3 on hid=1024, bf16 in, GELU, bf16 out ----------------
__global__ __launch_bounds__(256) void dwconv_kernel(const ushort* __restrict__ z1,
        const float* __restrict__ w, const float* __restrict__ bias,
        ushort* __restrict__ z2) {
    int c = blockIdx.x * 256 + threadIdx.x;
    int n = blockIdx.y;
    int b = blockIdx.z;
    int h = n / WW, wc = n - h * WW;
    const ushort* zb = z1 + (size_t)b * NN * HID;
    float acc = bias[c];
#pragma unroll
    for (int ky = 0; ky < 3; ++ky) {
        int hy = h + ky - 1;
        if ((unsigned)hy >= (unsigned)HH) continue;
#pragma unroll
        for (int kx = 0; kx < 3; ++kx) {
            int wx = wc + kx - 1;
            if ((unsigned)wx >= (unsigned)WW) continue;
            acc = fmaf(bf2f(zb[(size_t)(hy * WW + wx) * HID + c]), w[c * 9 + ky * 3 + kx], acc);
        }
    }
    z2[(size_t)b * NN * HID + (size_t)n * HID + c] = f2bf(gelu_f(acc));
}

extern "C" void kernel_launch(void* const* d_in, const int* in_sizes, int n_in,
                              void* d_out, int out_size, void* d_ws, size_t ws_size,
                              hipStream_t stream) {
    const float* x      = (const float*)d_in[0];
    const float* lpu_w  = (const float*)d_in[3];
    const float* lpu_b  = (const float*)d_in[4];
    const float* n1_g   = (const float*)d_in[5];
    const float* n1_b   = (const float*)d_in[6];
    const float* c2_w   = (const float*)d_in[7];
    const float* c2_b   = (const float*)d_in[8];
    const float* cn_g   = (const float*)d_in[9];
    const float* cn_b   = (const float*)d_in[10];
    const float* q_w    = (const float*)d_in[11];
    const float* sr1_w  = (const float*)d_in[12];
    const float* sr1_b  = (const float*)d_in[13];
    const float* an1_g  = (const float*)d_in[14];
    const float* an1_b  = (const float*)d_in[15];
    const float* sr2_w  = (const float*)d_in[16];
    const float* sr2_b  = (const float*)d_in[17];
    const float* an2_g  = (const float*)d_in[18];
    const float* an2_b  = (const float*)d_in[19];
    const float* kv1_w  = (const float*)d_in[20];
    const float* kv2_w  = (const float*)d_in[21];
    const float* proj_w = (const float*)d_in[22];
    const float* proj_b = (const float*)d_in[23];
    const float* n2_g   = (const float*)d_in[24];
    const float* n2_b   = (const float*)d_in[25];
    const float* fc1_w  = (const float*)d_in[26];
    const float* fc1_b  = (const float*)d_in[27];
    const float* dw_w   = (const float*)d_in[28];
    const float* dw_b   = (const float*)d_in[29];
    const float* fc2_w  = (const float*)d_in[30];
    const float* fc2_b  = (const float*)d_in[31];
    float* out = (float*)d_out;

    char* ws = (char*)d_ws;
    size_t off = 0;
    auto allocB = [&](size_t bytes) {
        char* p = ws + off;
        off += ((bytes + 255) & ~(size_t)255);
        return p;
    };
    float*  xbuf = (float*)allocB((size_t)BNR * CC * 4);   // fp32 residual spine
    ushort* ybuf = (ushort*)allocB((size_t)BNR * CC * 2);  // LN out (bf16)
    // persistent bf16 weights (must survive into MLP phase)
    ushort* wq   = (ushort*)allocB((size_t)AD * AD * 2);
    ushort* wkv1 = (ushort*)allocB((size_t)AD * AD * 2);
    ushort* wkv2 = (ushort*)allocB((size_t)AD * AD * 2);
    ushort* wpr  = (ushort*)allocB((size_t)CC * CC * 2);
    ushort* wf1  = (ushort*)allocB((size_t)HID * CC * 2);
    ushort* wf2  = (ushort*)allocB((size_t)CC * HID * 2);
    ushort* wcp  = (ushort*)allocB((size_t)64 * 576 * 2);
    size_t zmark = off;                                    // overlay region start
    ushort* cat  = (ushort*)allocB((size_t)BNR * CC * 2);  // [o1|o2|cp] bf16
    ushort* qbuf = (ushort*)allocB((size_t)BNR * AD * 2);
    ushort* x1g  = (ushort*)allocB((size_t)BB * M1 * AD * 2);
    ushort* x2g  = (ushort*)allocB((size_t)BB * M2 * AD * 2);
    float*  kv1o = (float*)allocB((size_t)BB * M1 * AD * 4);
    float*  kv2o = (float*)allocB((size_t)BB * M2 * AD * 4);
    float*  cbuf = (float*)allocB((size_t)BNR * CD * 4);

    // MLP batch-chunk size (z1/z2 bf16 overlay from zmark)
    int CB2 = 1;
    for (int cb = 16; cb >= 1; cb >>= 1) {
        if (zmark + 2 * (size_t)cb * NN * HID * 2 <= ws_size) { CB2 = cb; break; }
    }

    dim3 b256(256);
    // 0. weight converts (independent)
    cvt_kernel<<<dim3(64), b256, 0, stream>>>(q_w, wq, AD * AD);
    cvt_kernel<<<dim3(64), b256, 0, stream>>>(kv1_w, wkv1, AD * AD);
    cvt_kernel<<<dim3(64), b256, 0, stream>>>(kv2_w, wkv2, AD * AD);
    cvt_kernel<<<dim3(64), b256, 0, stream>>>(proj_w, wpr, CC * CC);
    cvt_kernel<<<dim3(256), b256, 0, stream>>>(fc1_w, wf1, HID * CC);
    cvt_kernel<<<dim3(256), b256, 0, stream>>>(fc2_w, wf2, CC * HID);
    cpwt_kernel<<<dim3(144), b256, 0, stream>>>(c2_w, wcp);
    // 1. LPU + residual
    lpu_kernel<<<dim3(NN, BB), b256, 0, stream>>>(x, lpu_w, lpu_b, xbuf);
    // 2. LN1 -> ybuf bf16
    ln256_kernel<<<dim3(BNR / 4), b256, 0, stream>>>(xbuf, n1_g, n1_b, ybuf);
    // 3. cp branch: MFMA implicit conv, then LN64+GELU -> cat cols [192,256)
    cpgemm_kernel<<<dim3(BNR / 128), b256, 0, stream>>>(ybuf, wcp, c2_b, cbuf);
    ln64gelu_kernel<<<dim3(BNR / 4), b256, 0, stream>>>(cbuf, cn_g, cn_b, cat);
    // 4. q = ap @ q_w.T  (bf16 out)
    gemm_mfma<4><<<dim3(2, BNR / 128), b256, 0, stream>>>(
        ybuf + CD, CC, wq, AD, AD, nullptr, nullptr, 0, qbuf, AD, BNR);
    // 5. SR convs + LN + GELU (bf16 io)
    sr_kernel<8, 7><<<dim3(M1, BB), dim3(192), 0, stream>>>(ybuf + CD, sr1_w, sr1_b, an1_g, an1_b, x1g);
    sr_kernel<4, 14><<<dim3(M2, BB), dim3(192), 0, stream>>>(ybuf + CD, sr2_w, sr2_b, an2_g, an2_b, x2g);
    // 6. kv GEMMs (fp32 out)
    gemm_mfma<0><<<dim3(2, (BB * M1 + 127) / 128), b256, 0, stream>>>(
        x1g, AD, wkv1, AD, AD, nullptr, nullptr, 0, kv1o, AD, BB * M1);
    gemm_mfma<0><<<dim3(2, (BB * M2 + 127) / 128), b256, 0, stream>>>(
        x2g, AD, wkv2, AD, AD, nullptr, nullptr, 0, kv2o, AD, BB * M2);
    // 7. attention -> cat cols [0,192)
    attn_kernel<<<dim3((NN + 255) / 256, NH, BB), b256, 0, stream>>>(qbuf, kv1o, kv2o, cat);
    // 8. proj + bias + residual (in-place into xbuf, fp32)
    gemm_mfma<3><<<dim3(2, BNR / 128), b256, 0, stream>>>(
        cat, CC, wpr, CC, CC, proj_b, xbuf, CC, xbuf, CC, BNR);
    // 9. LN2 -> ybuf bf16
    ln256_kernel<<<dim3(BNR / 4), b256, 0, stream>>>(xbuf, n2_g, n2_b, ybuf);
    // 10. MLP in batch chunks
    ushort* z1 = (ushort*)(ws + zmark);
    ushort* z2 = z1 + (size_t)CB2 * NN * HID;
    for (int c0 = 0; c0 < BB; c0 += CB2) {
        size_t tokoff = (size_t)c0 * NN;
        int Rr = CB2 * NN;
        gemm_mfma<5><<<dim3(HID / 128, (Rr + 127) / 128), b256, 0, stream>>>(
            ybuf + tokoff * CC, CC, wf1, CC, HID, fc1_b, nullptr, 0, z1, HID, Rr);
        dwconv_kernel<<<dim3(HID / 256, NN, CB2), b256, 0, stream>>>(z1, dw_w, dw_b, z2);
        gemm_mfma<3><<<dim3(CC / 128, (Rr + 127) / 128), b256, 0, stream>>>(
            z2, HID, wf2, HID, CC, fc2_b, xbuf + tokoff * CC, CC, out + tokoff * CC, CC, Rr);
    }
}

// Round 6
// 673.867 us; speedup vs baseline: 7.5721x; 1.5815x over previous
//
#include <hip/hip_runtime.h>
#include <math.h>

// Problem constants (B=16, H=W=56, C=256)
#define BB   16
#define HH   56
#define WW   56
#define NN   (HH*WW)        // 3136
#define CC   256
#define CD   64
#define AD   192
#define NH   8
#define HG   4
#define HD   24
#define HID  1024
#define M1   49
#define M2   196
#define BNR  (BB*NN)        // 50176

typedef __attribute__((ext_vector_type(8))) short s8v;   // 8 bf16
typedef __attribute__((ext_vector_type(4))) short s4v;
typedef __attribute__((ext_vector_type(4))) float f4v;

__device__ __forceinline__ float gelu_f(float x) {
    return 0.5f * x * (1.0f + erff(x * 0.70710678118654752f));
}
__device__ __forceinline__ ushort f2bf(float f) {
    union { float f; uint32_t u; } c; c.f = f;
    uint32_t u = c.u;
    return (ushort)((u + 0x7fffu + ((u >> 16) & 1u)) >> 16);
}
__device__ __forceinline__ float bf2f(ushort u) {
    union { uint32_t u; float f; } c; c.u = ((uint32_t)u) << 16;
    return c.f;
}

// ---------------- generic f32 -> bf16 convert ----------------
__global__ __launch_bounds__(256) void cvt_kernel(const float* __restrict__ src,
        ushort* __restrict__ dst, int n) {
    for (int i = blockIdx.x * 256 + threadIdx.x; i < n; i += gridDim.x * 256)
        dst[i] = f2bf(src[i]);
}

// ---------------- depthwise weight transpose: w[C][9] -> wt[9][C] (fp32) ----------------
__global__ __launch_bounds__(256) void dwt_kernel(const float* __restrict__ w,
        float* __restrict__ wt, int Cn) {
    int idx = blockIdx.x * 256 + threadIdx.x;
    if (idx >= Cn * 9) return;
    int c = idx / 9, t = idx - c * 9;
    wt[t * Cn + c] = w[idx];
}

// ---------------- cp weight transform: wt[co][tap*64+ci] = w[co][ci*9+tap] ----------------
__global__ __launch_bounds__(256) void cpwt_kernel(const float* __restrict__ w,
        ushort* __restrict__ wt) {
    int idx = blockIdx.x * 256 + threadIdx.x;
    if (idx >= 64 * 576) return;
    int co = idx / 576, k = idx - co * 576;
    int tap = k >> 6, ci = k & 63;
    wt[idx] = f2bf(w[co * 576 + ci * 9 + tap]);
}

// ---------------- LPU: depthwise 3x3 + bias + residual (fp32, float4 x 4ch) ----------------
// wt layout [9][256]
__global__ __launch_bounds__(256) void lpu_kernel(const float* __restrict__ x,
        const float* __restrict__ wt, const float* __restrict__ bias,
        float* __restrict__ out) {
    int c = (threadIdx.x & 63) * 4;
    int n = blockIdx.x * 4 + (threadIdx.x >> 6);
    int b = blockIdx.y;
    int h = n / WW, wc = n - h * WW;
    const float* xb = x + (size_t)b * NN * CC;
    float4 acc = *(const float4*)(bias + c);
#pragma unroll
    for (int ky = 0; ky < 3; ++ky) {
        int hy = h + ky - 1;
        if ((unsigned)hy >= (unsigned)HH) continue;
#pragma unroll
        for (int kx = 0; kx < 3; ++kx) {
            int wx = wc + kx - 1;
            if ((unsigned)wx >= (unsigned)WW) continue;
            float4 xv = *(const float4*)(xb + (size_t)(hy * WW + wx) * CC + c);
            float4 wv = *(const float4*)(wt + (ky * 3 + kx) * CC + c);
            acc.x = fmaf(xv.x, wv.x, acc.x);
            acc.y = fmaf(xv.y, wv.y, acc.y);
            acc.z = fmaf(xv.z, wv.z, acc.z);
            acc.w = fmaf(xv.w, wv.w, acc.w);
        }
    }
    size_t o = (size_t)b * NN * CC + (size_t)n * CC + c;
    float4 rv = *(const float4*)(x + o);
    acc.x += rv.x; acc.y += rv.y; acc.z += rv.z; acc.w += rv.w;
    *(float4*)(out + o) = acc;
}

// ---------------- LayerNorm over C=256, fp32 in, bf16 out ----------------
__global__ __launch_bounds__(256) void ln256_kernel(const float* __restrict__ x,
        const float* __restrict__ g, const float* __restrict__ bt,
        ushort* __restrict__ y) {
    int lane = threadIdx.x & 63;
    int tok = blockIdx.x * 4 + (threadIdx.x >> 6);
    const float4 v = *(const float4*)(x + (size_t)tok * CC + lane * 4);
    float s = v.x + v.y + v.z + v.w;
    float sq = v.x * v.x + v.y * v.y + v.z * v.z + v.w * v.w;
#pragma unroll
    for (int off = 32; off >= 1; off >>= 1) {
        s += __shfl_xor(s, off, 64);
        sq += __shfl_xor(sq, off, 64);
    }
    float mean = s * (1.0f / 256.0f);
    float var = sq * (1.0f / 256.0f) - mean * mean;
    float rstd = rsqrtf(var + 1e-5f);
    float4 gv = *(const float4*)(g + lane * 4);
    float4 bv = *(const float4*)(bt + lane * 4);
    s4v o;
    o.x = (short)f2bf((v.x - mean) * rstd * gv.x + bv.x);
    o.y = (short)f2bf((v.y - mean) * rstd * gv.y + bv.y);
    o.z = (short)f2bf((v.z - mean) * rstd * gv.z + bv.z);
    o.w = (short)f2bf((v.w - mean) * rstd * gv.w + bv.w);
    *(s4v*)(y + (size_t)tok * CC + lane * 4) = o;
}

// ---------------- cp branch: implicit-GEMM conv via MFMA ----------------
__global__ __launch_bounds__(256) void cpgemm_kernel(
        const ushort* __restrict__ y, const ushort* __restrict__ wt,
        const float* __restrict__ cb, float* __restrict__ cbuf) {
    __shared__ __align__(16) ushort As[128 * 32];
    __shared__ __align__(16) ushort Ws[64 * 32];
    int tid = threadIdx.x;
    int wid = tid >> 6, lane = tid & 63;
    int rt = blockIdx.x * 128;
    int u0 = tid, u1 = tid + 256;
    int r0 = u0 >> 2, c0 = u0 & 3;
    int r1 = u1 >> 2, c1 = u1 & 3;
    int tok0 = rt + r0, tok1 = rt + r1;
    int b0 = tok0 / NN, n0 = tok0 - b0 * NN, h0 = n0 / WW, w0 = n0 - h0 * WW;
    int b1 = tok1 / NN, n1 = tok1 - b1 * NN, h1 = n1 / WW, w1 = n1 - h1 * WW;
    int wr0 = tid >> 2, wc0 = tid & 3;
    const ushort* Wp = wt + (size_t)wr0 * 576 + wc0 * 8;
    f4v acc[2][4];
#pragma unroll
    for (int m = 0; m < 2; ++m)
#pragma unroll
        for (int n = 0; n < 4; ++n) acc[m][n] = (f4v)0.f;
    int lr = lane & 15, lk = (lane >> 4) * 8;
    for (int kt = 0; kt < 576; kt += 32) {
        int tap = kt >> 6, ci0 = kt & 63;
        int t3 = tap / 3, dy = t3 - 1, dx = (tap - t3 * 3) - 1;
        s8v a0 = (s8v)0, a1 = (s8v)0;
        int hy0 = h0 + dy, wx0 = w0 + dx;
        if ((unsigned)hy0 < (unsigned)HH && (unsigned)wx0 < (unsigned)WW)
            a0 = *(const s8v*)(y + ((size_t)b0 * NN + hy0 * WW + wx0) * CC + ci0 + c0 * 8);
        int hy1 = h1 + dy, wx1 = w1 + dx;
        if ((unsigned)hy1 < (unsigned)HH && (unsigned)wx1 < (unsigned)WW)
            a1 = *(const s8v*)(y + ((size_t)b1 * NN + hy1 * WW + wx1) * CC + ci0 + c1 * 8);
        s8v wv = *(const s8v*)(Wp + kt);
        __syncthreads();
        *(s8v*)&As[r0 * 32 + c0 * 8] = a0;
        *(s8v*)&As[r1 * 32 + c1 * 8] = a1;
        *(s8v*)&Ws[wr0 * 32 + wc0 * 8] = wv;
        __syncthreads();
        s8v af[2], bf[4];
#pragma unroll
        for (int m = 0; m < 2; ++m)
            af[m] = *(const s8v*)&As[(wid * 32 + m * 16 + lr) * 32 + lk];
#pragma unroll
        for (int n = 0; n < 4; ++n)
            bf[n] = *(const s8v*)&Ws[(n * 16 + lr) * 32 + lk];
#pragma unroll
        for (int m = 0; m < 2; ++m)
#pragma unroll
            for (int n = 0; n < 4; ++n)
                acc[m][n] = __builtin_amdgcn_mfma_f32_16x16x32_bf16(af[m], bf[n], acc[m][n], 0, 0, 0);
    }
#pragma unroll
    for (int m = 0; m < 2; ++m)
#pragma unroll
        for (int n = 0; n < 4; ++n) {
            int gr = rt + wid * 32 + m * 16 + (lane >> 4) * 4;
            int gc = n * 16 + (lane & 15);
#pragma unroll
            for (int r = 0; r < 4; ++r)
                cbuf[(size_t)(gr + r) * 64 + gc] = acc[m][n][r] + cb[gc];
        }
}

// ---------------- LN(64)+GELU epilogue: cbuf fp32 -> cat bf16 cols [192,256) ----------------
__global__ __launch_bounds__(256) void ln64gelu_kernel(const float* __restrict__ cbuf,
        const float* __restrict__ g, const float* __restrict__ bt,
        ushort* __restrict__ cat) {
    int lane = threadIdx.x & 63;
    int tok = blockIdx.x * 4 + (threadIdx.x >> 6);
    float v = cbuf[(size_t)tok * 64 + lane];
    float s = v, sq = v * v;
#pragma unroll
    for (int off = 32; off >= 1; off >>= 1) {
        s += __shfl_xor(s, off, 64);
        sq += __shfl_xor(sq, off, 64);
    }
    float mean = s * (1.0f / 64.0f);
    float var = sq * (1.0f / 64.0f) - mean * mean;
    float rstd = rsqrtf(var + 1e-5f);
    float o = (v - mean) * rstd * g[lane] + bt[lane];
    cat[(size_t)tok * CC + 192 + lane] = f2bf(gelu_f(o));
}

// ---------------- SR conv (depthwise KSxKS stride KS) + LN(192) + GELU, bf16 io ----------------
template <int KS, int OW>
__global__ __launch_bounds__(192) void sr_kernel(const ushort* __restrict__ yap,
        const float* __restrict__ w, const float* __restrict__ bias,
        const float* __restrict__ g, const float* __restrict__ bt,
        ushort* __restrict__ out) {
    int ch = threadIdx.x;
    int m = blockIdx.x, b = blockIdx.y;
    int oh = m / OW, ow = m - oh * OW;
    const ushort* yb = yap + (size_t)b * NN * CC;
    float acc = bias[ch];
#pragma unroll
    for (int ky = 0; ky < KS; ++ky)
#pragma unroll
        for (int kx = 0; kx < KS; ++kx)
            acc = fmaf(bf2f(yb[(size_t)((oh * KS + ky) * WW + ow * KS + kx) * CC + ch]),
                       w[ch * KS * KS + ky * KS + kx], acc);
    __shared__ float red[2][3];
    float s = acc, sq = acc * acc;
#pragma unroll
    for (int off = 32; off >= 1; off >>= 1) {
        s += __shfl_xor(s, off, 64);
        sq += __shfl_xor(sq, off, 64);
    }
    int wv = threadIdx.x >> 6, lane = threadIdx.x & 63;
    if (lane == 0) { red[0][wv] = s; red[1][wv] = sq; }
    __syncthreads();
    s = red[0][0] + red[0][1] + red[0][2];
    sq = red[1][0] + red[1][1] + red[1][2];
    float mean = s * (1.0f / 192.0f);
    float var = sq * (1.0f / 192.0f) - mean * mean;
    float rstd = rsqrtf(var + 1e-5f);
    float v = (acc - mean) * rstd * g[ch] + bt[ch];
    out[((size_t)b * (OW * OW) + m) * AD + ch] = f2bf(gelu_f(v));
}

// ---------------- generic MFMA GEMM: C[r,o] = sum_k A[r,k]*W[o,k] ----------------
template <int MODE>
__global__ __launch_bounds__(256) void gemm_mfma(
        const ushort* __restrict__ A, int lda,
        const ushort* __restrict__ W, int K, int O,
        const float* __restrict__ bias,
        const float* __restrict__ res, int ldr,
        void* __restrict__ Cout, int ldc, int R) {
    __shared__ __align__(16) ushort As[128 * 32];
    __shared__ __align__(16) ushort Ws[128 * 32];
    int tid = threadIdx.x;
    int wid = tid >> 6, lane = tid & 63;
    int wr = wid >> 1, wc = wid & 1;
    int rt = blockIdx.y * 128, ot = blockIdx.x * 128;
    int u0 = tid, u1 = tid + 256;
    int r0 = u0 >> 2, c0 = u0 & 3;
    int r1 = u1 >> 2, c1 = u1 & 3;
    const ushort* Ap0 = A + (size_t)min(rt + r0, R - 1) * lda + c0 * 8;
    const ushort* Ap1 = A + (size_t)min(rt + r1, R - 1) * lda + c1 * 8;
    const ushort* Wp0 = W + (size_t)min(ot + r0, O - 1) * K + c0 * 8;
    const ushort* Wp1 = W + (size_t)min(ot + r1, O - 1) * K + c1 * 8;
    f4v acc[4][4];
#pragma unroll
    for (int m = 0; m < 4; ++m)
#pragma unroll
        for (int n = 0; n < 4; ++n) acc[m][n] = (f4v)0.f;
    int lr = lane & 15, lk = (lane >> 4) * 8;
    for (int kt = 0; kt < K; kt += 32) {
        s8v a0 = *(const s8v*)(Ap0 + kt);
        s8v a1 = *(const s8v*)(Ap1 + kt);
        s8v w0 = *(const s8v*)(Wp0 + kt);
        s8v w1 = *(const s8v*)(Wp1 + kt);
        __syncthreads();
        *(s8v*)&As[r0 * 32 + c0 * 8] = a0;
        *(s8v*)&As[r1 * 32 + c1 * 8] = a1;
        *(s8v*)&Ws[r0 * 32 + c0 * 8] = w0;
        *(s8v*)&Ws[r1 * 32 + c1 * 8] = w1;
        __syncthreads();
        s8v af[4], bf[4];
#pragma unroll
        for (int m = 0; m < 4; ++m)
            af[m] = *(const s8v*)&As[(wr * 64 + m * 16 + lr) * 32 + lk];
#pragma unroll
        for (int n = 0; n < 4; ++n)
            bf[n] = *(const s8v*)&Ws[(wc * 64 + n * 16 + lr) * 32 + lk];
#pragma unroll
        for (int m = 0; m < 4; ++m)
#pragma unroll
            for (int n = 0; n < 4; ++n)
                acc[m][n] = __builtin_amdgcn_mfma_f32_16x16x32_bf16(af[m], bf[n], acc[m][n], 0, 0, 0);
    }
#pragma unroll
    for (int m = 0; m < 4; ++m)
#pragma unroll
        for (int n = 0; n < 4; ++n) {
            int gr = rt + wr * 64 + m * 16 + (lane >> 4) * 4;
            int gc = ot + wc * 64 + n * 16 + (lane & 15);
            if (gc >= O) continue;
#pragma unroll
            for (int r = 0; r < 4; ++r) {
                int row = gr + r;
                if (row >= R) continue;
                float v = acc[m][n][r];
                if (MODE & 1) v += bias[gc];
                if (MODE & 2) v += res[(size_t)row * ldr + gc];
                if (MODE & 4) ((ushort*)Cout)[(size_t)row * ldc + gc] = f2bf(v);
                else          ((float*)Cout)[(size_t)row * ldc + gc] = v;
            }
        }
}

// ---------------- attention: online softmax single pass; per-group template ----------------
// kvo layout (B*M,192): cols [g*24..): K, [96+g*24..): V. writes cat cols (HOFF+g)*24.
template <int M, int HOFF>
__global__ __launch_bounds__(256) void attn_kernel(const ushort* __restrict__ q,
        const float* __restrict__ kvo, ushort* __restrict__ cat) {
    __shared__ float sk[M * HD];
    __shared__ float sv[M * HD];
    int g = blockIdx.y, b = blockIdx.z;
    int h = HOFF + g;
    int tot = M * HD;
    for (int idx = threadIdx.x; idx < tot; idx += 256) {
        int m = idx / HD, d = idx - m * HD;
        sk[idx] = kvo[((size_t)b * M + m) * AD + g * HD + d];
        sv[idx] = kvo[((size_t)b * M + m) * AD + 96 + g * HD + d];
    }
    __syncthreads();
    int n = blockIdx.x * 256 + threadIdx.x;
    if (n >= NN) return;
    float qv[HD];
    const ushort* qr = q + ((size_t)b * NN + n) * AD + h * HD;
#pragma unroll
    for (int d = 0; d < HD; ++d) qv[d] = bf2f(qr[d]);
    const float scale = 0.20412414523193154f;  // 24^-0.5
    float mx = -3.0e38f, sum = 0.f;
    float acc[HD] = {};
    for (int m = 0; m < M; ++m) {
        float s = 0.f;
        const float* kr = sk + m * HD;
#pragma unroll
        for (int d = 0; d < HD; ++d) s = fmaf(qv[d], kr[d], s);
        s *= scale;
        if (s > mx) {
            float corr = __expf(mx - s);
            sum *= corr;
#pragma unroll
            for (int d = 0; d < HD; ++d) acc[d] *= corr;
            mx = s;
        }
        float p = __expf(s - mx);
        sum += p;
        const float* vr = sv + m * HD;
#pragma unroll
        for (int d = 0; d < HD; ++d) acc[d] = fmaf(p, vr[d], acc[d]);
    }
    float inv = 1.0f / sum;
    ushort* o = cat + ((size_t)b * NN + n) * CC + h * HD;
#pragma unroll
    for (int d = 0; d < HD; ++d) o[d] = f2bf(acc[d] * inv);
}

// ---------------- depthwise 3x3 on hid=1024, bf16 io, 8ch/thread, wt [9][1024] ----------------
__global__ __launch_bounds__(256) void dwconv_kernel(const ushort* __restrict__ z1,
        const float* __restrict__ wt, const float* __restrict__ bias,
        ushort* __restrict__ z2) {
    int c = (threadIdx.x & 127) * 8;
    int n = blockIdx.x * 2 + (threadIdx.x >> 7);
    int b = blockIdx.y;
    int h = n / WW, wc = n - h * WW;
    const ushort* zb = z1 + (size_t)b * NN * HID;
    float acc[8];
    {
        float4 b0 = *(const float4*)(bias + c);
        float4 b1 = *(const float4*)(bias + c + 4);
        acc[0] = b0.x; acc[1] = b0.y; acc[2] = b0.z; acc[3] = b0.w;
        acc[4] = b1.x; acc[5] = b1.y; acc[6] = b1.z; acc[7] = b1.w;
    }
#pragma unroll
    for (int ky = 0; ky < 3; ++ky) {
        int hy = h + ky - 1;
        if ((unsigned)hy >= (unsigned)HH) continue;
#pragma unroll
        for (int kx = 0; kx < 3; ++kx) {
            int wx = wc + kx - 1;
            if ((unsigned)wx >= (unsigned)WW) continue;
            s8v v = *(const s8v*)(zb + (size_t)(hy * WW + wx) * HID + c);
            const float* wp = wt + (ky * 3 + kx) * HID + c;
            float4 w0 = *(const float4*)wp;
            float4 w1 = *(const float4*)(wp + 4);
            acc[0] = fmaf(bf2f((ushort)v[0]), w0.x, acc[0]);
            acc[1] = fmaf(bf2f((ushort)v[1]), w0.y, acc[1]);
            acc[2] = fmaf(bf2f((ushort)v[2]), w0.z, acc[2]);
            acc[3] = fmaf(bf2f((ushort)v[3]), w0.w, acc[3]);
            acc[4] = fmaf(bf2f((ushort)v[4]), w1.x, acc[4]);
            acc[5] = fmaf(bf2f((ushort)v[5]), w1.y, acc[5]);
            acc[6] = fmaf(bf2f((ushort)v[6]), w1.z, acc[6]);
            acc[7] = fmaf(bf2f((ushort)v[7]), w1.w, acc[7]);
        }
    }
    s8v o;
#pragma unroll
    for (int j = 0; j < 8; ++j) o[j] = (short)f2bf(gelu_f(acc[j]));
    *(s8v*)(z2 + (size_t)b * NN * HID + (size_t)n * HID + c) = o;
}

extern "C" void kernel_launch(void* const* d_in, const int* in_sizes, int n_in,
                              void* d_out, int out_size, void* d_ws, size_t ws_size,
                              hipStream_t stream) {
    const float* x      = (const float*)d_in[0];
    const float* lpu_w  = (const float*)d_in[3];
    const float* lpu_b  = (const float*)d_in[4];
    const float* n1_g   = (const float*)d_in[5];
    const float* n1_b   = (const float*)d_in[6];
    const float* c2_w   = (const float*)d_in[7];
    const float* c2_b   = (const float*)d_in[8];
    const float* cn_g   = (const float*)d_in[9];
    const float* cn_b   = (const float*)d_in[10];
    const float* q_w    = (const float*)d_in[11];
    const float* sr1_w  = (const float*)d_in[12];
    const float* sr1_b  = (const float*)d_in[13];
    const float* an1_g  = (const float*)d_in[14];
    const float* an1_b  = (const float*)d_in[15];
    const float* sr2_w  = (const float*)d_in[16];
    const float* sr2_b  = (const float*)d_in[17];
    const float* an2_g  = (const float*)d_in[18];
    const float* an2_b  = (const float*)d_in[19];
    const float* kv1_w  = (const float*)d_in[20];
    const float* kv2_w  = (const float*)d_in[21];
    const float* proj_w = (const float*)d_in[22];
    const float* proj_b = (const float*)d_in[23];
    const float* n2_g   = (const float*)d_in[24];
    const float* n2_b   = (const float*)d_in[25];
    const float* fc1_w  = (const float*)d_in[26];
    const float* fc1_b  = (const float*)d_in[27];
    const float* dw_w   = (const float*)d_in[28];
    const float* dw_b   = (const float*)d_in[29];
    const float* fc2_w  = (const float*)d_in[30];
    const float* fc2_b  = (const float*)d_in[31];
    float* out = (float*)d_out;

    char* ws = (char*)d_ws;
    size_t off = 0;
    auto allocB = [&](size_t bytes) {
        char* p = ws + off;
        off += ((bytes + 255) & ~(size_t)255);
        return p;
    };
    float*  xbuf = (float*)allocB((size_t)BNR * CC * 4);   // fp32 residual spine
    ushort* ybuf = (ushort*)allocB((size_t)BNR * CC * 2);  // LN out (bf16)
    // persistent bf16 weights + transposed dw weights
    ushort* wq   = (ushort*)allocB((size_t)AD * AD * 2);
    ushort* wkv1 = (ushort*)allocB((size_t)AD * AD * 2);
    ushort* wkv2 = (ushort*)allocB((size_t)AD * AD * 2);
    ushort* wpr  = (ushort*)allocB((size_t)CC * CC * 2);
    ushort* wf1  = (ushort*)allocB((size_t)HID * CC * 2);
    ushort* wf2  = (ushort*)allocB((size_t)CC * HID * 2);
    ushort* wcp  = (ushort*)allocB((size_t)64 * 576 * 2);
    float*  lpwt = (float*)allocB((size_t)9 * CC * 4);
    float*  dwwt = (float*)allocB((size_t)9 * HID * 4);
    size_t zmark = off;                                    // overlay region start
    ushort* cat  = (ushort*)allocB((size_t)BNR * CC * 2);  // [o1|o2|cp] bf16
    ushort* qbuf = (ushort*)allocB((size_t)BNR * AD * 2);
    ushort* x1g  = (ushort*)allocB((size_t)BB * M1 * AD * 2);
    ushort* x2g  = (ushort*)allocB((size_t)BB * M2 * AD * 2);
    float*  kv1o = (float*)allocB((size_t)BB * M1 * AD * 4);
    float*  kv2o = (float*)allocB((size_t)BB * M2 * AD * 4);
    float*  cbuf = (float*)allocB((size_t)BNR * CD * 4);

    // MLP batch-chunk size (z1/z2 bf16 overlay from zmark)
    int CB2 = 1;
    for (int cb = 16; cb >= 1; cb >>= 1) {
        if (zmark + 2 * (size_t)cb * NN * HID * 2 <= ws_size) { CB2 = cb; break; }
    }

    dim3 b256(256);
    // 0. weight converts / transposes (independent)
    cvt_kernel<<<dim3(64), b256, 0, stream>>>(q_w, wq, AD * AD);
    cvt_kernel<<<dim3(64), b256, 0, stream>>>(kv1_w, wkv1, AD * AD);
    cvt_kernel<<<dim3(64), b256, 0, stream>>>(kv2_w, wkv2, AD * AD);
    cvt_kernel<<<dim3(64), b256, 0, stream>>>(proj_w, wpr, CC * CC);
    cvt_kernel<<<dim3(256), b256, 0, stream>>>(fc1_w, wf1, HID * CC);
    cvt_kernel<<<dim3(256), b256, 0, stream>>>(fc2_w, wf2, CC * HID);
    cpwt_kernel<<<dim3(144), b256, 0, stream>>>(c2_w, wcp);
    dwt_kernel<<<dim3(9), b256, 0, stream>>>(lpu_w, lpwt, CC);
    dwt_kernel<<<dim3(36), b256, 0, stream>>>(dw_w, dwwt, HID);
    // 1. LPU + residual (vectorized)
    lpu_kernel<<<dim3(NN / 4, BB), b256, 0, stream>>>(x, lpwt, lpu_b, xbuf);
    // 2. LN1 -> ybuf bf16
    ln256_kernel<<<dim3(BNR / 4), b256, 0, stream>>>(xbuf, n1_g, n1_b, ybuf);
    // 3. cp branch: MFMA implicit conv, then LN64+GELU -> cat cols [192,256)
    cpgemm_kernel<<<dim3(BNR / 128), b256, 0, stream>>>(ybuf, wcp, c2_b, cbuf);
    ln64gelu_kernel<<<dim3(BNR / 4), b256, 0, stream>>>(cbuf, cn_g, cn_b, cat);
    // 4. q = ap @ q_w.T  (bf16 out)
    gemm_mfma<4><<<dim3(2, BNR / 128), b256, 0, stream>>>(
        ybuf + CD, CC, wq, AD, AD, nullptr, nullptr, 0, qbuf, AD, BNR);
    // 5. SR convs + LN + GELU (bf16 io)
    sr_kernel<8, 7><<<dim3(M1, BB), dim3(192), 0, stream>>>(ybuf + CD, sr1_w, sr1_b, an1_g, an1_b, x1g);
    sr_kernel<4, 14><<<dim3(M2, BB), dim3(192), 0, stream>>>(ybuf + CD, sr2_w, sr2_b, an2_g, an2_b, x2g);
    // 6. kv GEMMs (fp32 out)
    gemm_mfma<0><<<dim3(2, (BB * M1 + 127) / 128), b256, 0, stream>>>(
        x1g, AD, wkv1, AD, AD, nullptr, nullptr, 0, kv1o, AD, BB * M1);
    gemm_mfma<0><<<dim3(2, (BB * M2 + 127) / 128), b256, 0, stream>>>(
        x2g, AD, wkv2, AD, AD, nullptr, nullptr, 0, kv2o, AD, BB * M2);
    // 7. attention -> cat cols [0,192): two kernels (per KV source), online softmax
    attn_kernel<M1, 0><<<dim3((NN + 255) / 256, HG, BB), b256, 0, stream>>>(qbuf, kv1o, cat);
    attn_kernel<M2, HG><<<dim3((NN + 255) / 256, HG, BB), b256, 0, stream>>>(qbuf, kv2o, cat);
    // 8. proj + bias + residual (in-place into xbuf, fp32)
    gemm_mfma<3><<<dim3(2, BNR / 128), b256, 0, stream>>>(
        cat, CC, wpr, CC, CC, proj_b, xbuf, CC, xbuf, CC, BNR);
    // 9. LN2 -> ybuf bf16
    ln256_kernel<<<dim3(BNR / 4), b256, 0, stream>>>(xbuf, n2_g, n2_b, ybuf);
    // 10. MLP in batch chunks
    ushort* z1 = (ushort*)(ws + zmark);
    ushort* z2 = z1 + (size_t)CB2 * NN * HID;
    for (int c0 = 0; c0 < BB; c0 += CB2) {
        size_t tokoff = (size_t)c0 * NN;
        int Rr = CB2 * NN;
        gemm_mfma<5><<<dim3(HID / 128, (Rr + 127) / 128), b256, 0, stream>>>(
            ybuf + tokoff * CC, CC, wf1, CC, HID, fc1_b, nullptr, 0, z1, HID, Rr);
        dwconv_kernel<<<dim3(NN / 2, CB2), b256, 0, stream>>>(z1, dwwt, dw_b, z2);
        gemm_mfma<3><<<dim3(CC / 128, (Rr + 127) / 128), b256, 0, stream>>>(
            z2, HID, wf2, HID, CC, fc2_b, xbuf + tokoff * CC, CC, out + tokoff * CC, CC, Rr);
    }
}

// Round 7
// 650.189 us; speedup vs baseline: 7.8479x; 1.0364x over previous
//
#include <hip/hip_runtime.h>
#include <math.h>

// Problem constants (B=16, H=W=56, C=256)
#define BB   16
#define HH   56
#define WW   56
#define NN   (HH*WW)        // 3136
#define CC   256
#define CD   64
#define AD   192
#define NH   8
#define HG   4
#define HD   24
#define HID  1024
#define M1   49
#define M2   196
#define BNR  (BB*NN)        // 50176

typedef __attribute__((ext_vector_type(8))) short s8v;   // 8 bf16
typedef __attribute__((ext_vector_type(4))) short s4v;
typedef __attribute__((ext_vector_type(4))) float f4v;

__device__ __forceinline__ float gelu_f(float x) {
    return 0.5f * x * (1.0f + erff(x * 0.70710678118654752f));
}
__device__ __forceinline__ ushort f2bf(float f) {
    union { float f; uint32_t u; } c; c.f = f;
    uint32_t u = c.u;
    return (ushort)((u + 0x7fffu + ((u >> 16) & 1u)) >> 16);
}
__device__ __forceinline__ float bf2f(ushort u) {
    union { uint32_t u; float f; } c; c.u = ((uint32_t)u) << 16;
    return c.f;
}

// ---------------- generic f32 -> bf16 convert ----------------
__global__ __launch_bounds__(256) void cvt_kernel(const float* __restrict__ src,
        ushort* __restrict__ dst, int n) {
    for (int i = blockIdx.x * 256 + threadIdx.x; i < n; i += gridDim.x * 256)
        dst[i] = f2bf(src[i]);
}

// ---------------- depthwise weight transpose: w[C][9] -> wt[9][C] (fp32) ----------------
__global__ __launch_bounds__(256) void dwt_kernel(const float* __restrict__ w,
        float* __restrict__ wt, int Cn) {
    int idx = blockIdx.x * 256 + threadIdx.x;
    if (idx >= Cn * 9) return;
    int c = idx / 9, t = idx - c * 9;
    wt[t * Cn + c] = w[idx];
}

// ---------------- cp weight transform: wt[co][tap*64+ci] = w[co][ci*9+tap] ----------------
__global__ __launch_bounds__(256) void cpwt_kernel(const float* __restrict__ w,
        ushort* __restrict__ wt) {
    int idx = blockIdx.x * 256 + threadIdx.x;
    if (idx >= 64 * 576) return;
    int co = idx / 576, k = idx - co * 576;
    int tap = k >> 6, ci = k & 63;
    wt[idx] = f2bf(w[co * 576 + ci * 9 + tap]);
}

// ---------------- LPU: depthwise 3x3 + bias + residual (fp32, float4 x 4ch) ----------------
// wt layout [9][256]
__global__ __launch_bounds__(256) void lpu_kernel(const float* __restrict__ x,
        const float* __restrict__ wt, const float* __restrict__ bias,
        float* __restrict__ out) {
    int c = (threadIdx.x & 63) * 4;
    int n = blockIdx.x * 4 + (threadIdx.x >> 6);
    int b = blockIdx.y;
    int h = n / WW, wc = n - h * WW;
    const float* xb = x + (size_t)b * NN * CC;
    float4 acc = *(const float4*)(bias + c);
#pragma unroll
    for (int ky = 0; ky < 3; ++ky) {
        int hy = h + ky - 1;
        if ((unsigned)hy >= (unsigned)HH) continue;
#pragma unroll
        for (int kx = 0; kx < 3; ++kx) {
            int wx = wc + kx - 1;
            if ((unsigned)wx >= (unsigned)WW) continue;
            float4 xv = *(const float4*)(xb + (size_t)(hy * WW + wx) * CC + c);
            float4 wv = *(const float4*)(wt + (ky * 3 + kx) * CC + c);
            acc.x = fmaf(xv.x, wv.x, acc.x);
            acc.y = fmaf(xv.y, wv.y, acc.y);
            acc.z = fmaf(xv.z, wv.z, acc.z);
            acc.w = fmaf(xv.w, wv.w, acc.w);
        }
    }
    size_t o = (size_t)b * NN * CC + (size_t)n * CC + c;
    float4 rv = *(const float4*)(x + o);
    acc.x += rv.x; acc.y += rv.y; acc.z += rv.z; acc.w += rv.w;
    *(float4*)(out + o) = acc;
}

// ---------------- LayerNorm over C=256, fp32 in, bf16 out ----------------
__global__ __launch_bounds__(256) void ln256_kernel(const float* __restrict__ x,
        const float* __restrict__ g, const float* __restrict__ bt,
        ushort* __restrict__ y) {
    int lane = threadIdx.x & 63;
    int tok = blockIdx.x * 4 + (threadIdx.x >> 6);
    const float4 v = *(const float4*)(x + (size_t)tok * CC + lane * 4);
    float s = v.x + v.y + v.z + v.w;
    float sq = v.x * v.x + v.y * v.y + v.z * v.z + v.w * v.w;
#pragma unroll
    for (int off = 32; off >= 1; off >>= 1) {
        s += __shfl_xor(s, off, 64);
        sq += __shfl_xor(sq, off, 64);
    }
    float mean = s * (1.0f / 256.0f);
    float var = sq * (1.0f / 256.0f) - mean * mean;
    float rstd = rsqrtf(var + 1e-5f);
    float4 gv = *(const float4*)(g + lane * 4);
    float4 bv = *(const float4*)(bt + lane * 4);
    s4v o;
    o.x = (short)f2bf((v.x - mean) * rstd * gv.x + bv.x);
    o.y = (short)f2bf((v.y - mean) * rstd * gv.y + bv.y);
    o.z = (short)f2bf((v.z - mean) * rstd * gv.z + bv.z);
    o.w = (short)f2bf((v.w - mean) * rstd * gv.w + bv.w);
    *(s4v*)(y + (size_t)tok * CC + lane * 4) = o;
}

// ---------------- cp branch: implicit-GEMM conv via MFMA ----------------
__global__ __launch_bounds__(256) void cpgemm_kernel(
        const ushort* __restrict__ y, const ushort* __restrict__ wt,
        const float* __restrict__ cb, float* __restrict__ cbuf) {
    __shared__ __align__(16) ushort As[128 * 32];
    __shared__ __align__(16) ushort Ws[64 * 32];
    int tid = threadIdx.x;
    int wid = tid >> 6, lane = tid & 63;
    int rt = blockIdx.x * 128;
    int u0 = tid, u1 = tid + 256;
    int r0 = u0 >> 2, c0 = u0 & 3;
    int r1 = u1 >> 2, c1 = u1 & 3;
    int tok0 = rt + r0, tok1 = rt + r1;
    int b0 = tok0 / NN, n0 = tok0 - b0 * NN, h0 = n0 / WW, w0 = n0 - h0 * WW;
    int b1 = tok1 / NN, n1 = tok1 - b1 * NN, h1 = n1 / WW, w1 = n1 - h1 * WW;
    int wr0 = tid >> 2, wc0 = tid & 3;
    const ushort* Wp = wt + (size_t)wr0 * 576 + wc0 * 8;
    f4v acc[2][4];
#pragma unroll
    for (int m = 0; m < 2; ++m)
#pragma unroll
        for (int n = 0; n < 4; ++n) acc[m][n] = (f4v)0.f;
    int lr = lane & 15, lk = (lane >> 4) * 8;
    for (int kt = 0; kt < 576; kt += 32) {
        int tap = kt >> 6, ci0 = kt & 63;
        int t3 = tap / 3, dy = t3 - 1, dx = (tap - t3 * 3) - 1;
        s8v a0 = (s8v)0, a1 = (s8v)0;
        int hy0 = h0 + dy, wx0 = w0 + dx;
        if ((unsigned)hy0 < (unsigned)HH && (unsigned)wx0 < (unsigned)WW)
            a0 = *(const s8v*)(y + ((size_t)b0 * NN + hy0 * WW + wx0) * CC + ci0 + c0 * 8);
        int hy1 = h1 + dy, wx1 = w1 + dx;
        if ((unsigned)hy1 < (unsigned)HH && (unsigned)wx1 < (unsigned)WW)
            a1 = *(const s8v*)(y + ((size_t)b1 * NN + hy1 * WW + wx1) * CC + ci0 + c1 * 8);
        s8v wv = *(const s8v*)(Wp + kt);
        __syncthreads();
        *(s8v*)&As[r0 * 32 + c0 * 8] = a0;
        *(s8v*)&As[r1 * 32 + c1 * 8] = a1;
        *(s8v*)&Ws[wr0 * 32 + wc0 * 8] = wv;
        __syncthreads();
        s8v af[2], bf[4];
#pragma unroll
        for (int m = 0; m < 2; ++m)
            af[m] = *(const s8v*)&As[(wid * 32 + m * 16 + lr) * 32 + lk];
#pragma unroll
        for (int n = 0; n < 4; ++n)
            bf[n] = *(const s8v*)&Ws[(n * 16 + lr) * 32 + lk];
#pragma unroll
        for (int m = 0; m < 2; ++m)
#pragma unroll
            for (int n = 0; n < 4; ++n)
                acc[m][n] = __builtin_amdgcn_mfma_f32_16x16x32_bf16(af[m], bf[n], acc[m][n], 0, 0, 0);
    }
#pragma unroll
    for (int m = 0; m < 2; ++m)
#pragma unroll
        for (int n = 0; n < 4; ++n) {
            int gr = rt + wid * 32 + m * 16 + (lane >> 4) * 4;
            int gc = n * 16 + (lane & 15);
#pragma unroll
            for (int r = 0; r < 4; ++r)
                cbuf[(size_t)(gr + r) * 64 + gc] = acc[m][n][r] + cb[gc];
        }
}

// ---------------- LN(64)+GELU epilogue: cbuf fp32 -> cat bf16 cols [192,256) ----------------
__global__ __launch_bounds__(256) void ln64gelu_kernel(const float* __restrict__ cbuf,
        const float* __restrict__ g, const float* __restrict__ bt,
        ushort* __restrict__ cat) {
    int lane = threadIdx.x & 63;
    int tok = blockIdx.x * 4 + (threadIdx.x >> 6);
    float v = cbuf[(size_t)tok * 64 + lane];
    float s = v, sq = v * v;
#pragma unroll
    for (int off = 32; off >= 1; off >>= 1) {
        s += __shfl_xor(s, off, 64);
        sq += __shfl_xor(sq, off, 64);
    }
    float mean = s * (1.0f / 64.0f);
    float var = sq * (1.0f / 64.0f) - mean * mean;
    float rstd = rsqrtf(var + 1e-5f);
    float o = (v - mean) * rstd * g[lane] + bt[lane];
    cat[(size_t)tok * CC + 192 + lane] = f2bf(gelu_f(o));
}

// ---------------- SR conv (depthwise KSxKS stride KS) + LN(192) + GELU, bf16 io ----------------
template <int KS, int OW>
__global__ __launch_bounds__(192) void sr_kernel(const ushort* __restrict__ yap,
        const float* __restrict__ w, const float* __restrict__ bias,
        const float* __restrict__ g, const float* __restrict__ bt,
        ushort* __restrict__ out) {
    int ch = threadIdx.x;
    int m = blockIdx.x, b = blockIdx.y;
    int oh = m / OW, ow = m - oh * OW;
    const ushort* yb = yap + (size_t)b * NN * CC;
    float acc = bias[ch];
#pragma unroll
    for (int ky = 0; ky < KS; ++ky)
#pragma unroll
        for (int kx = 0; kx < KS; ++kx)
            acc = fmaf(bf2f(yb[(size_t)((oh * KS + ky) * WW + ow * KS + kx) * CC + ch]),
                       w[ch * KS * KS + ky * KS + kx], acc);
    __shared__ float red[2][3];
    float s = acc, sq = acc * acc;
#pragma unroll
    for (int off = 32; off >= 1; off >>= 1) {
        s += __shfl_xor(s, off, 64);
        sq += __shfl_xor(sq, off, 64);
    }
    int wv = threadIdx.x >> 6, lane = threadIdx.x & 63;
    if (lane == 0) { red[0][wv] = s; red[1][wv] = sq; }
    __syncthreads();
    s = red[0][0] + red[0][1] + red[0][2];
    sq = red[1][0] + red[1][1] + red[1][2];
    float mean = s * (1.0f / 192.0f);
    float var = sq * (1.0f / 192.0f) - mean * mean;
    float rstd = rsqrtf(var + 1e-5f);
    float v = (acc - mean) * rstd * g[ch] + bt[ch];
    out[((size_t)b * (OW * OW) + m) * AD + ch] = f2bf(gelu_f(v));
}

// ---------------- generic MFMA GEMM: C[r,o] = sum_k A[r,k]*W[o,k] ----------------
template <int MODE>
__global__ __launch_bounds__(256) void gemm_mfma(
        const ushort* __restrict__ A, int lda,
        const ushort* __restrict__ W, int K, int O,
        const float* __restrict__ bias,
        const float* __restrict__ res, int ldr,
        void* __restrict__ Cout, int ldc, int R) {
    __shared__ __align__(16) ushort As[128 * 32];
    __shared__ __align__(16) ushort Ws[128 * 32];
    int tid = threadIdx.x;
    int wid = tid >> 6, lane = tid & 63;
    int wr = wid >> 1, wc = wid & 1;
    int rt = blockIdx.y * 128, ot = blockIdx.x * 128;
    int u0 = tid, u1 = tid + 256;
    int r0 = u0 >> 2, c0 = u0 & 3;
    int r1 = u1 >> 2, c1 = u1 & 3;
    const ushort* Ap0 = A + (size_t)min(rt + r0, R - 1) * lda + c0 * 8;
    const ushort* Ap1 = A + (size_t)min(rt + r1, R - 1) * lda + c1 * 8;
    const ushort* Wp0 = W + (size_t)min(ot + r0, O - 1) * K + c0 * 8;
    const ushort* Wp1 = W + (size_t)min(ot + r1, O - 1) * K + c1 * 8;
    f4v acc[4][4];
#pragma unroll
    for (int m = 0; m < 4; ++m)
#pragma unroll
        for (int n = 0; n < 4; ++n) acc[m][n] = (f4v)0.f;
    int lr = lane & 15, lk = (lane >> 4) * 8;
    for (int kt = 0; kt < K; kt += 32) {
        s8v a0 = *(const s8v*)(Ap0 + kt);
        s8v a1 = *(const s8v*)(Ap1 + kt);
        s8v w0 = *(const s8v*)(Wp0 + kt);
        s8v w1 = *(const s8v*)(Wp1 + kt);
        __syncthreads();
        *(s8v*)&As[r0 * 32 + c0 * 8] = a0;
        *(s8v*)&As[r1 * 32 + c1 * 8] = a1;
        *(s8v*)&Ws[r0 * 32 + c0 * 8] = w0;
        *(s8v*)&Ws[r1 * 32 + c1 * 8] = w1;
        __syncthreads();
        s8v af[4], bf[4];
#pragma unroll
        for (int m = 0; m < 4; ++m)
            af[m] = *(const s8v*)&As[(wr * 64 + m * 16 + lr) * 32 + lk];
#pragma unroll
        for (int n = 0; n < 4; ++n)
            bf[n] = *(const s8v*)&Ws[(wc * 64 + n * 16 + lr) * 32 + lk];
#pragma unroll
        for (int m = 0; m < 4; ++m)
#pragma unroll
            for (int n = 0; n < 4; ++n)
                acc[m][n] = __builtin_amdgcn_mfma_f32_16x16x32_bf16(af[m], bf[n], acc[m][n], 0, 0, 0);
    }
#pragma unroll
    for (int m = 0; m < 4; ++m)
#pragma unroll
        for (int n = 0; n < 4; ++n) {
            int gr = rt + wr * 64 + m * 16 + (lane >> 4) * 4;
            int gc = ot + wc * 64 + n * 16 + (lane & 15);
            if (gc >= O) continue;
#pragma unroll
            for (int r = 0; r < 4; ++r) {
                int row = gr + r;
                if (row >= R) continue;
                float v = acc[m][n][r];
                if (MODE & 1) v += bias[gc];
                if (MODE & 2) v += res[(size_t)row * ldr + gc];
                if (MODE & 4) ((ushort*)Cout)[(size_t)row * ldc + gc] = f2bf(v);
                else          ((float*)Cout)[(size_t)row * ldc + gc] = v;
            }
        }
}

// ---------------- MFMA attention ----------------
// Per (b,g): S^T = mfma(K,Q) so lane holds col n=lane&15, rows m; softmax over m is
// in-lane + 2 shfl_xor. PV uses m-PERMUTED V^T staged in LDS so the P fragment is the
// lane's own registers (no transpose). M padded to MP (mask -inf; VT zero-filled).
// kvb: bf16 (B*M,192): cols [g*24..): K, [96+g*24..): V. Writes cat cols (HOFF+g)*24.
template <int M, int MP, int HOFF>
__global__ __launch_bounds__(256) void attn_mfma(const ushort* __restrict__ q,
        const ushort* __restrict__ kvb, ushort* __restrict__ cat) {
    constexpr int NT = MP / 16;   // S^T m-tiles
    constexpr int NCH = MP / 32;  // PV k-chunks
    __shared__ __align__(16) ushort Kl[MP * 32];
    __shared__ __align__(16) ushort VT[32 * MP];
    int g = blockIdx.y, b = blockIdx.z;
    int h = HOFF + g;
    int tid = threadIdx.x;
    // stage K: Kl[m][d], zero-padded
    for (int idx = tid; idx < MP * 32; idx += 256) {
        int mm = idx >> 5, d = idx & 31;
        ushort v = 0;
        if (mm < M && d < HD) v = kvb[((size_t)b * M + mm) * AD + g * HD + d];
        Kl[idx] = v;
    }
    // stage V^T with m-axis permutation matching the P fragment register order
    for (int idx = tid; idx < 32 * MP; idx += 256) {
        int d = idx / MP, kk = idx - d * MP;
        int c = kk >> 5, k5 = kk & 31, gg = k5 >> 3, t = k5 & 7;
        int m = c * 32 + ((t < 4) ? (gg * 4 + t) : (16 + gg * 4 + (t - 4)));
        ushort v = 0;
        if (m < M && d < HD) v = kvb[((size_t)b * M + m) * AD + 96 + g * HD + d];
        VT[idx] = v;
    }
    __syncthreads();
    int w = tid >> 6, lane = tid & 63;
    int ln = lane & 15, g4 = lane >> 4;
    int n0 = blockIdx.x * 64 + w * 16 + ln;
    // Q fragment: row n0, k=d (24 real, pad 32 with zeros)
    s8v qf = (s8v)0;
    if (g4 < 3) qf = *(const s8v*)(q + ((size_t)b * NN + n0) * AD + h * HD + g4 * 8);
    // S^T: per lane col n0, rows m = t*16 + g4*4 + r
    f4v sa[NT];
#pragma unroll
    for (int t = 0; t < NT; ++t) sa[t] = (f4v)0.f;
#pragma unroll
    for (int t = 0; t < NT; ++t) {
        s8v kf = *(const s8v*)&Kl[(t * 16 + ln) * 32 + g4 * 8];
        sa[t] = __builtin_amdgcn_mfma_f32_16x16x32_bf16(kf, qf, sa[t], 0, 0, 0);
    }
    const float scale = 0.20412414523193154f;  // 24^-0.5
    float mx = -3.0e38f;
#pragma unroll
    for (int t = 0; t < NT; ++t)
#pragma unroll
        for (int r = 0; r < 4; ++r) {
            int m = t * 16 + g4 * 4 + r;
            float v = (m < M) ? sa[t][r] * scale : -3.0e38f;
            sa[t][r] = v;
            mx = fmaxf(mx, v);
        }
    mx = fmaxf(mx, __shfl_xor(mx, 16, 64));
    mx = fmaxf(mx, __shfl_xor(mx, 32, 64));
    float sum = 0.f;
#pragma unroll
    for (int t = 0; t < NT; ++t)
#pragma unroll
        for (int r = 0; r < 4; ++r) {
            float p = __expf(sa[t][r] - mx);
            sa[t][r] = p;
            sum += p;
        }
    sum += __shfl_xor(sum, 16, 64);
    sum += __shfl_xor(sum, 32, 64);
    float inv = 1.0f / sum;
    // PV: O^T[d][n] — P fragment is the lane's own p-registers (V^T pre-permuted)
    f4v oa[2] = {(f4v)0.f, (f4v)0.f};
#pragma unroll
    for (int c = 0; c < NCH; ++c) {
        s8v pb;
#pragma unroll
        for (int t = 0; t < 4; ++t) {
            pb[t]     = (short)f2bf(sa[c * 2][t]);
            pb[4 + t] = (short)f2bf(sa[c * 2 + 1][t]);
        }
#pragma unroll
        for (int dt = 0; dt < 2; ++dt) {
            s8v vf = *(const s8v*)&VT[(dt * 16 + ln) * MP + c * 32 + g4 * 8];
            oa[dt] = __builtin_amdgcn_mfma_f32_16x16x32_bf16(vf, pb, oa[dt], 0, 0, 0);
        }
    }
    // store: lane col n0 fixed; rows d = dt*16 + g4*4 + r (keep d < 24)
    ushort* op = cat + ((size_t)b * NN + n0) * CC + h * HD;
    s4v o0;
#pragma unroll
    for (int r = 0; r < 4; ++r) o0[r] = (short)f2bf(oa[0][r] * inv);
    *(s4v*)(op + g4 * 4) = o0;
    if (g4 < 2) {
        s4v o1;
#pragma unroll
        for (int r = 0; r < 4; ++r) o1[r] = (short)f2bf(oa[1][r] * inv);
        *(s4v*)(op + 16 + g4 * 4) = o1;
    }
}

// ---------------- depthwise 3x3 on hid=1024, bf16 io, 8ch/thread, wt [9][1024] ----------------
__global__ __launch_bounds__(256) void dwconv_kernel(const ushort* __restrict__ z1,
        const float* __restrict__ wt, const float* __restrict__ bias,
        ushort* __restrict__ z2) {
    int c = (threadIdx.x & 127) * 8;
    int n = blockIdx.x * 2 + (threadIdx.x >> 7);
    int b = blockIdx.y;
    int h = n / WW, wc = n - h * WW;
    const ushort* zb = z1 + (size_t)b * NN * HID;
    float acc[8];
    {
        float4 b0 = *(const float4*)(bias + c);
        float4 b1 = *(const float4*)(bias + c + 4);
        acc[0] = b0.x; acc[1] = b0.y; acc[2] = b0.z; acc[3] = b0.w;
        acc[4] = b1.x; acc[5] = b1.y; acc[6] = b1.z; acc[7] = b1.w;
    }
#pragma unroll
    for (int ky = 0; ky < 3; ++ky) {
        int hy = h + ky - 1;
        if ((unsigned)hy >= (unsigned)HH) continue;
#pragma unroll
        for (int kx = 0; kx < 3; ++kx) {
            int wx = wc + kx - 1;
            if ((unsigned)wx >= (unsigned)WW) continue;
            s8v v = *(const s8v*)(zb + (size_t)(hy * WW + wx) * HID + c);
            const float* wp = wt + (ky * 3 + kx) * HID + c;
            float4 w0 = *(const float4*)wp;
            float4 w1 = *(const float4*)(wp + 4);
            acc[0] = fmaf(bf2f((ushort)v[0]), w0.x, acc[0]);
            acc[1] = fmaf(bf2f((ushort)v[1]), w0.y, acc[1]);
            acc[2] = fmaf(bf2f((ushort)v[2]), w0.z, acc[2]);
            acc[3] = fmaf(bf2f((ushort)v[3]), w0.w, acc[3]);
            acc[4] = fmaf(bf2f((ushort)v[4]), w1.x, acc[4]);
            acc[5] = fmaf(bf2f((ushort)v[5]), w1.y, acc[5]);
            acc[6] = fmaf(bf2f((ushort)v[6]), w1.z, acc[6]);
            acc[7] = fmaf(bf2f((ushort)v[7]), w1.w, acc[7]);
        }
    }
    s8v o;
#pragma unroll
    for (int j = 0; j < 8; ++j) o[j] = (short)f2bf(gelu_f(acc[j]));
    *(s8v*)(z2 + (size_t)b * NN * HID + (size_t)n * HID + c) = o;
}

extern "C" void kernel_launch(void* const* d_in, const int* in_sizes, int n_in,
                              void* d_out, int out_size, void* d_ws, size_t ws_size,
                              hipStream_t stream) {
    const float* x      = (const float*)d_in[0];
    const float* lpu_w  = (const float*)d_in[3];
    const float* lpu_b  = (const float*)d_in[4];
    const float* n1_g   = (const float*)d_in[5];
    const float* n1_b   = (const float*)d_in[6];
    const float* c2_w   = (const float*)d_in[7];
    const float* c2_b   = (const float*)d_in[8];
    const float* cn_g   = (const float*)d_in[9];
    const float* cn_b   = (const float*)d_in[10];
    const float* q_w    = (const float*)d_in[11];
    const float* sr1_w  = (const float*)d_in[12];
    const float* sr1_b  = (const float*)d_in[13];
    const float* an1_g  = (const float*)d_in[14];
    const float* an1_b  = (const float*)d_in[15];
    const float* sr2_w  = (const float*)d_in[16];
    const float* sr2_b  = (const float*)d_in[17];
    const float* an2_g  = (const float*)d_in[18];
    const float* an2_b  = (const float*)d_in[19];
    const float* kv1_w  = (const float*)d_in[20];
    const float* kv2_w  = (const float*)d_in[21];
    const float* proj_w = (const float*)d_in[22];
    const float* proj_b = (const float*)d_in[23];
    const float* n2_g   = (const float*)d_in[24];
    const float* n2_b   = (const float*)d_in[25];
    const float* fc1_w  = (const float*)d_in[26];
    const float* fc1_b  = (const float*)d_in[27];
    const float* dw_w   = (const float*)d_in[28];
    const float* dw_b   = (const float*)d_in[29];
    const float* fc2_w  = (const float*)d_in[30];
    const float* fc2_b  = (const float*)d_in[31];
    float* out = (float*)d_out;

    char* ws = (char*)d_ws;
    size_t off = 0;
    auto allocB = [&](size_t bytes) {
        char* p = ws + off;
        off += ((bytes + 255) & ~(size_t)255);
        return p;
    };
    float*  xbuf = (float*)allocB((size_t)BNR * CC * 4);   // fp32 residual spine
    ushort* ybuf = (ushort*)allocB((size_t)BNR * CC * 2);  // LN out (bf16)
    // persistent bf16 weights + transposed dw weights
    ushort* wq   = (ushort*)allocB((size_t)AD * AD * 2);
    ushort* wkv1 = (ushort*)allocB((size_t)AD * AD * 2);
    ushort* wkv2 = (ushort*)allocB((size_t)AD * AD * 2);
    ushort* wpr  = (ushort*)allocB((size_t)CC * CC * 2);
    ushort* wf1  = (ushort*)allocB((size_t)HID * CC * 2);
    ushort* wf2  = (ushort*)allocB((size_t)CC * HID * 2);
    ushort* wcp  = (ushort*)allocB((size_t)64 * 576 * 2);
    float*  lpwt = (float*)allocB((size_t)9 * CC * 4);
    float*  dwwt = (float*)allocB((size_t)9 * HID * 4);
    size_t zmark = off;                                    // overlay region start
    ushort* cat  = (ushort*)allocB((size_t)BNR * CC * 2);  // [o1|o2|cp] bf16
    ushort* qbuf = (ushort*)allocB((size_t)BNR * AD * 2);
    ushort* x1g  = (ushort*)allocB((size_t)BB * M1 * AD * 2);
    ushort* x2g  = (ushort*)allocB((size_t)BB * M2 * AD * 2);
    ushort* kv1b = (ushort*)allocB((size_t)BB * M1 * AD * 2);  // bf16 kv
    ushort* kv2b = (ushort*)allocB((size_t)BB * M2 * AD * 2);
    float*  cbuf = (float*)allocB((size_t)BNR * CD * 4);

    // MLP batch-chunk size (z1/z2 bf16 overlay from zmark)
    int CB2 = 1;
    for (int cb = 16; cb >= 1; cb >>= 1) {
        if (zmark + 2 * (size_t)cb * NN * HID * 2 <= ws_size) { CB2 = cb; break; }
    }

    dim3 b256(256);
    // 0. weight converts / transposes (independent)
    cvt_kernel<<<dim3(64), b256, 0, stream>>>(q_w, wq, AD * AD);
    cvt_kernel<<<dim3(64), b256, 0, stream>>>(kv1_w, wkv1, AD * AD);
    cvt_kernel<<<dim3(64), b256, 0, stream>>>(kv2_w, wkv2, AD * AD);
    cvt_kernel<<<dim3(64), b256, 0, stream>>>(proj_w, wpr, CC * CC);
    cvt_kernel<<<dim3(256), b256, 0, stream>>>(fc1_w, wf1, HID * CC);
    cvt_kernel<<<dim3(256), b256, 0, stream>>>(fc2_w, wf2, CC * HID);
    cpwt_kernel<<<dim3(144), b256, 0, stream>>>(c2_w, wcp);
    dwt_kernel<<<dim3(9), b256, 0, stream>>>(lpu_w, lpwt, CC);
    dwt_kernel<<<dim3(36), b256, 0, stream>>>(dw_w, dwwt, HID);
    // 1. LPU + residual (vectorized)
    lpu_kernel<<<dim3(NN / 4, BB), b256, 0, stream>>>(x, lpwt, lpu_b, xbuf);
    // 2. LN1 -> ybuf bf16
    ln256_kernel<<<dim3(BNR / 4), b256, 0, stream>>>(xbuf, n1_g, n1_b, ybuf);
    // 3. cp branch: MFMA implicit conv, then LN64+GELU -> cat cols [192,256)
    cpgemm_kernel<<<dim3(BNR / 128), b256, 0, stream>>>(ybuf, wcp, c2_b, cbuf);
    ln64gelu_kernel<<<dim3(BNR / 4), b256, 0, stream>>>(cbuf, cn_g, cn_b, cat);
    // 4. q = ap @ q_w.T  (bf16 out)
    gemm_mfma<4><<<dim3(2, BNR / 128), b256, 0, stream>>>(
        ybuf + CD, CC, wq, AD, AD, nullptr, nullptr, 0, qbuf, AD, BNR);
    // 5. SR convs + LN + GELU (bf16 io)
    sr_kernel<8, 7><<<dim3(M1, BB), dim3(192), 0, stream>>>(ybuf + CD, sr1_w, sr1_b, an1_g, an1_b, x1g);
    sr_kernel<4, 14><<<dim3(M2, BB), dim3(192), 0, stream>>>(ybuf + CD, sr2_w, sr2_b, an2_g, an2_b, x2g);
    // 6. kv GEMMs (bf16 out)
    gemm_mfma<4><<<dim3(2, (BB * M1 + 127) / 128), b256, 0, stream>>>(
        x1g, AD, wkv1, AD, AD, nullptr, nullptr, 0, kv1b, AD, BB * M1);
    gemm_mfma<4><<<dim3(2, (BB * M2 + 127) / 128), b256, 0, stream>>>(
        x2g, AD, wkv2, AD, AD, nullptr, nullptr, 0, kv2b, AD, BB * M2);
    // 7. attention (MFMA) -> cat cols [0,192)
    attn_mfma<M1, 64, 0><<<dim3(NN / 64, HG, BB), b256, 0, stream>>>(qbuf, kv1b, cat);
    attn_mfma<M2, 224, HG><<<dim3(NN / 64, HG, BB), b256, 0, stream>>>(qbuf, kv2b, cat);
    // 8. proj + bias + residual (in-place into xbuf, fp32)
    gemm_mfma<3><<<dim3(2, BNR / 128), b256, 0, stream>>>(
        cat, CC, wpr, CC, CC, proj_b, xbuf, CC, xbuf, CC, BNR);
    // 9. LN2 -> ybuf bf16
    ln256_kernel<<<dim3(BNR / 4), b256, 0, stream>>>(xbuf, n2_g, n2_b, ybuf);
    // 10. MLP in batch chunks
    ushort* z1 = (ushort*)(ws + zmark);
    ushort* z2 = z1 + (size_t)CB2 * NN * HID;
    for (int c0 = 0; c0 < BB; c0 += CB2) {
        size_t tokoff = (size_t)c0 * NN;
        int Rr = CB2 * NN;
        gemm_mfma<5><<<dim3(HID / 128, (Rr + 127) / 128), b256, 0, stream>>>(
            ybuf + tokoff * CC, CC, wf1, CC, HID, fc1_b, nullptr, 0, z1, HID, Rr);
        dwconv_kernel<<<dim3(NN / 2, CB2), b256, 0, stream>>>(z1, dwwt, dw_b, z2);
        gemm_mfma<3><<<dim3(CC / 128, (Rr + 127) / 128), b256, 0, stream>>>(
            z2, HID, wf2, HID, CC, fc2_b, xbuf + tokoff * CC, CC, out + tokoff * CC, CC, Rr);
    }
}

// Round 9
// 585.511 us; speedup vs baseline: 8.7148x; 1.1105x over previous
//
#include <hip/hip_runtime.h>
#include <math.h>

// Problem constants (B=16, H=W=56, C=256)
#define BB   16
#define HH   56
#define WW   56
#define NN   (HH*WW)        // 3136
#define CC   256
#define CD   64
#define AD   192
#define NH   8
#define HG   4
#define HD   24
#define HID  1024
#define M1   49
#define M2   196
#define BNR  (BB*NN)        // 50176

typedef __attribute__((ext_vector_type(8))) short s8v;   // 8 bf16
typedef __attribute__((ext_vector_type(4))) short s4v;
typedef __attribute__((ext_vector_type(4))) float f4v;

__device__ __forceinline__ float gelu_f(float x) {
    return 0.5f * x * (1.0f + erff(x * 0.70710678118654752f));
}
__device__ __forceinline__ ushort f2bf(float f) {
    union { float f; uint32_t u; } c; c.f = f;
    uint32_t u = c.u;
    return (ushort)((u + 0x7fffu + ((u >> 16) & 1u)) >> 16);
}
__device__ __forceinline__ float bf2f(ushort u) {
    union { uint32_t u; float f; } c; c.u = ((uint32_t)u) << 16;
    return c.f;
}
// async global->LDS, 16B per lane; dest = wave-uniform base + lane*16
__device__ __forceinline__ void load_lds16(const void* gsrc, void* ldst) {
    __builtin_amdgcn_global_load_lds(
        (const __attribute__((address_space(1))) void*)gsrc,
        (__attribute__((address_space(3))) void*)ldst, 16, 0, 0);
}

// ---------------- generic f32 -> bf16 convert ----------------
__global__ __launch_bounds__(256) void cvt_kernel(const float* __restrict__ src,
        ushort* __restrict__ dst, int n) {
    for (int i = blockIdx.x * 256 + threadIdx.x; i < n; i += gridDim.x * 256)
        dst[i] = f2bf(src[i]);
}

// ---------------- depthwise weight transpose: w[C][9] -> wt[9][C] (fp32) ----------------
__global__ __launch_bounds__(256) void dwt_kernel(const float* __restrict__ w,
        float* __restrict__ wt, int Cn) {
    int idx = blockIdx.x * 256 + threadIdx.x;
    if (idx >= Cn * 9) return;
    int c = idx / 9, t = idx - c * 9;
    wt[t * Cn + c] = w[idx];
}

// ---------------- cp weight transform: wt[co][tap*64+ci] = w[co][ci*9+tap] ----------------
__global__ __launch_bounds__(256) void cpwt_kernel(const float* __restrict__ w,
        ushort* __restrict__ wt) {
    int idx = blockIdx.x * 256 + threadIdx.x;
    if (idx >= 64 * 576) return;
    int co = idx / 576, k = idx - co * 576;
    int tap = k >> 6, ci = k & 63;
    wt[idx] = f2bf(w[co * 576 + ci * 9 + tap]);
}

// ---------------- LPU: depthwise 3x3 + bias + residual (fp32, float4 x 4ch) ----------------
__global__ __launch_bounds__(256) void lpu_kernel(const float* __restrict__ x,
        const float* __restrict__ wt, const float* __restrict__ bias,
        float* __restrict__ out) {
    int c = (threadIdx.x & 63) * 4;
    int n = blockIdx.x * 4 + (threadIdx.x >> 6);
    int b = blockIdx.y;
    int h = n / WW, wc = n - h * WW;
    const float* xb = x + (size_t)b * NN * CC;
    float4 acc = *(const float4*)(bias + c);
#pragma unroll
    for (int ky = 0; ky < 3; ++ky) {
        int hy = h + ky - 1;
        if ((unsigned)hy >= (unsigned)HH) continue;
#pragma unroll
        for (int kx = 0; kx < 3; ++kx) {
            int wx = wc + kx - 1;
            if ((unsigned)wx >= (unsigned)WW) continue;
            float4 xv = *(const float4*)(xb + (size_t)(hy * WW + wx) * CC + c);
            float4 wv = *(const float4*)(wt + (ky * 3 + kx) * CC + c);
            acc.x = fmaf(xv.x, wv.x, acc.x);
            acc.y = fmaf(xv.y, wv.y, acc.y);
            acc.z = fmaf(xv.z, wv.z, acc.z);
            acc.w = fmaf(xv.w, wv.w, acc.w);
        }
    }
    size_t o = (size_t)b * NN * CC + (size_t)n * CC + c;
    float4 rv = *(const float4*)(x + o);
    acc.x += rv.x; acc.y += rv.y; acc.z += rv.z; acc.w += rv.w;
    *(float4*)(out + o) = acc;
}

// ---------------- LayerNorm over C=256, fp32 in, bf16 out ----------------
__global__ __launch_bounds__(256) void ln256_kernel(const float* __restrict__ x,
        const float* __restrict__ g, const float* __restrict__ bt,
        ushort* __restrict__ y) {
    int lane = threadIdx.x & 63;
    int tok = blockIdx.x * 4 + (threadIdx.x >> 6);
    const float4 v = *(const float4*)(x + (size_t)tok * CC + lane * 4);
    float s = v.x + v.y + v.z + v.w;
    float sq = v.x * v.x + v.y * v.y + v.z * v.z + v.w * v.w;
#pragma unroll
    for (int off = 32; off >= 1; off >>= 1) {
        s += __shfl_xor(s, off, 64);
        sq += __shfl_xor(sq, off, 64);
    }
    float mean = s * (1.0f / 256.0f);
    float var = sq * (1.0f / 256.0f) - mean * mean;
    float rstd = rsqrtf(var + 1e-5f);
    float4 gv = *(const float4*)(g + lane * 4);
    float4 bv = *(const float4*)(bt + lane * 4);
    s4v o;
    o.x = (short)f2bf((v.x - mean) * rstd * gv.x + bv.x);
    o.y = (short)f2bf((v.y - mean) * rstd * gv.y + bv.y);
    o.z = (short)f2bf((v.z - mean) * rstd * gv.z + bv.z);
    o.w = (short)f2bf((v.w - mean) * rstd * gv.w + bv.w);
    *(s4v*)(y + (size_t)tok * CC + lane * 4) = o;
}

// ---------------- cp branch: implicit-GEMM conv via MFMA (swizzled LDS) ----------------
__global__ __launch_bounds__(256) void cpgemm_kernel(
        const ushort* __restrict__ y, const ushort* __restrict__ wt,
        const float* __restrict__ cb, float* __restrict__ cbuf) {
    __shared__ __align__(16) ushort As[128 * 32];
    __shared__ __align__(16) ushort Ws[64 * 32];
    int tid = threadIdx.x;
    int wid = tid >> 6, lane = tid & 63;
    int rt = blockIdx.x * 128;
    int r0 = tid >> 2, c0 = tid & 3;
    int r1 = r0 + 64;
    int tok0 = rt + r0, tok1 = rt + r1;
    int b0 = tok0 / NN, n0 = tok0 - b0 * NN, h0 = n0 / WW, w0 = n0 - h0 * WW;
    int b1 = tok1 / NN, n1 = tok1 - b1 * NN, h1 = n1 / WW, w1 = n1 - h1 * WW;
    const ushort* Wp = wt + (size_t)r0 * 576 + c0 * 8;
    int aw0 = (c0 ^ (r0 & 3)) << 3;   // swizzled write slot (same for r0/r1: r1=r0+64)
    f4v acc[2][4];
#pragma unroll
    for (int m = 0; m < 2; ++m)
#pragma unroll
        for (int n = 0; n < 4; ++n) acc[m][n] = (f4v)0.f;
    int lr = lane & 15;
    int swz = ((lane >> 4) ^ (lr & 3)) << 3;
    for (int kt = 0; kt < 576; kt += 32) {
        int tap = kt >> 6, ci0 = kt & 63;
        int t3 = tap / 3, dy = t3 - 1, dx = (tap - t3 * 3) - 1;
        s8v a0 = (s8v)0, a1 = (s8v)0;
        int hy0 = h0 + dy, wx0 = w0 + dx;
        if ((unsigned)hy0 < (unsigned)HH && (unsigned)wx0 < (unsigned)WW)
            a0 = *(const s8v*)(y + ((size_t)b0 * NN + hy0 * WW + wx0) * CC + ci0 + c0 * 8);
        int hy1 = h1 + dy, wx1 = w1 + dx;
        if ((unsigned)hy1 < (unsigned)HH && (unsigned)wx1 < (unsigned)WW)
            a1 = *(const s8v*)(y + ((size_t)b1 * NN + hy1 * WW + wx1) * CC + ci0 + c0 * 8);
        s8v wv = *(const s8v*)(Wp + kt);
        __syncthreads();
        *(s8v*)&As[r0 * 32 + aw0] = a0;
        *(s8v*)&As[r1 * 32 + aw0] = a1;
        *(s8v*)&Ws[r0 * 32 + aw0] = wv;
        __syncthreads();
        s8v af[2], bf[4];
#pragma unroll
        for (int m = 0; m < 2; ++m)
            af[m] = *(const s8v*)&As[(wid * 32 + m * 16 + lr) * 32 + swz];
#pragma unroll
        for (int n = 0; n < 4; ++n)
            bf[n] = *(const s8v*)&Ws[(n * 16 + lr) * 32 + swz];
#pragma unroll
        for (int m = 0; m < 2; ++m)
#pragma unroll
            for (int n = 0; n < 4; ++n)
                acc[m][n] = __builtin_amdgcn_mfma_f32_16x16x32_bf16(af[m], bf[n], acc[m][n], 0, 0, 0);
    }
#pragma unroll
    for (int m = 0; m < 2; ++m)
#pragma unroll
        for (int n = 0; n < 4; ++n) {
            int gr = rt + wid * 32 + m * 16 + (lane >> 4) * 4;
            int gc = n * 16 + (lane & 15);
#pragma unroll
            for (int r = 0; r < 4; ++r)
                cbuf[(size_t)(gr + r) * 64 + gc] = acc[m][n][r] + cb[gc];
        }
}

// ---------------- LN(64)+GELU epilogue: cbuf fp32 -> cat bf16 cols [192,256) ----------------
__global__ __launch_bounds__(256) void ln64gelu_kernel(const float* __restrict__ cbuf,
        const float* __restrict__ g, const float* __restrict__ bt,
        ushort* __restrict__ cat) {
    int lane = threadIdx.x & 63;
    int tok = blockIdx.x * 4 + (threadIdx.x >> 6);
    float v = cbuf[(size_t)tok * 64 + lane];
    float s = v, sq = v * v;
#pragma unroll
    for (int off = 32; off >= 1; off >>= 1) {
        s += __shfl_xor(s, off, 64);
        sq += __shfl_xor(sq, off, 64);
    }
    float mean = s * (1.0f / 64.0f);
    float var = sq * (1.0f / 64.0f) - mean * mean;
    float rstd = rsqrtf(var + 1e-5f);
    float o = (v - mean) * rstd * g[lane] + bt[lane];
    cat[(size_t)tok * CC + 192 + lane] = f2bf(gelu_f(o));
}

// ---------------- SR conv (depthwise KSxKS stride KS) + LN(192) + GELU, bf16 io ----------------
template <int KS, int OW>
__global__ __launch_bounds__(192) void sr_kernel(const ushort* __restrict__ yap,
        const float* __restrict__ w, const float* __restrict__ bias,
        const float* __restrict__ g, const float* __restrict__ bt,
        ushort* __restrict__ out) {
    int ch = threadIdx.x;
    int m = blockIdx.x, b = blockIdx.y;
    int oh = m / OW, ow = m - oh * OW;
    const ushort* yb = yap + (size_t)b * NN * CC;
    float acc = bias[ch];
#pragma unroll
    for (int ky = 0; ky < KS; ++ky)
#pragma unroll
        for (int kx = 0; kx < KS; ++kx)
            acc = fmaf(bf2f(yb[(size_t)((oh * KS + ky) * WW + ow * KS + kx) * CC + ch]),
                       w[ch * KS * KS + ky * KS + kx], acc);
    __shared__ float red[2][3];
    float s = acc, sq = acc * acc;
#pragma unroll
    for (int off = 32; off >= 1; off >>= 1) {
        s += __shfl_xor(s, off, 64);
        sq += __shfl_xor(sq, off, 64);
    }
    int wv = threadIdx.x >> 6, lane = threadIdx.x & 63;
    if (lane == 0) { red[0][wv] = s; red[1][wv] = sq; }
    __syncthreads();
    s = red[0][0] + red[0][1] + red[0][2];
    sq = red[1][0] + red[1][1] + red[1][2];
    float mean = s * (1.0f / 192.0f);
    float var = sq * (1.0f / 192.0f) - mean * mean;
    float rstd = rsqrtf(var + 1e-5f);
    float v = (acc - mean) * rstd * g[ch] + bt[ch];
    out[((size_t)b * (OW * OW) + m) * AD + ch] = f2bf(gelu_f(v));
}

// ---------------- generic MFMA GEMM with global_load_lds + swizzled LDS ----------------
// bf16 A (R x lda), bf16 W (O x K). Tile 128x128, BK=32, 4 waves (2x2), 4x4 frags.
// MODE bits: 1=bias(fp32), 2=residual(fp32, stride ldr), 4=output bf16 (else fp32)
template <int MODE>
__global__ __launch_bounds__(256) void gemm_mfma(
        const ushort* __restrict__ A, int lda,
        const ushort* __restrict__ W, int K, int O,
        const float* __restrict__ bias,
        const float* __restrict__ res, int ldr,
        void* __restrict__ Cout, int ldc, int R) {
    __shared__ __align__(16) ushort As[128 * 32];
    __shared__ __align__(16) ushort Ws[128 * 32];
    int tid = threadIdx.x;
    int w4 = tid >> 6, lane = tid & 63;
    int wr = w4 >> 1, wc = w4 & 1;
    int rt = blockIdx.y * 128, ot = blockIdx.x * 128;
    int r0 = tid >> 2, cslot = tid & 3;
    int csrc = (cslot ^ (r0 & 3)) * 8;   // inverse-swizzled source column
    const ushort* Ap0 = A + (size_t)min(rt + r0, R - 1) * lda + csrc;
    const ushort* Ap1 = A + (size_t)min(rt + r0 + 64, R - 1) * lda + csrc;
    const ushort* Wp0 = W + (size_t)min(ot + r0, O - 1) * K + csrc;
    const ushort* Wp1 = W + (size_t)min(ot + r0 + 64, O - 1) * K + csrc;
    char* lA0 = (char*)As + w4 * 1024;
    char* lA1 = (char*)As + 4096 + w4 * 1024;
    char* lW0 = (char*)Ws + w4 * 1024;
    char* lW1 = (char*)Ws + 4096 + w4 * 1024;
    f4v acc[4][4];
#pragma unroll
    for (int m = 0; m < 4; ++m)
#pragma unroll
        for (int n = 0; n < 4; ++n) acc[m][n] = (f4v)0.f;
    int lr = lane & 15;
    int swz = ((lane >> 4) ^ (lr & 3)) << 3;
    for (int kt = 0; kt < K; kt += 32) {
        __syncthreads();
        load_lds16(Ap0 + kt, lA0);
        load_lds16(Ap1 + kt, lA1);
        load_lds16(Wp0 + kt, lW0);
        load_lds16(Wp1 + kt, lW1);
        __syncthreads();
        s8v af[4], bf[4];
#pragma unroll
        for (int m = 0; m < 4; ++m)
            af[m] = *(const s8v*)&As[(wr * 64 + m * 16 + lr) * 32 + swz];
#pragma unroll
        for (int n = 0; n < 4; ++n)
            bf[n] = *(const s8v*)&Ws[(wc * 64 + n * 16 + lr) * 32 + swz];
#pragma unroll
        for (int m = 0; m < 4; ++m)
#pragma unroll
            for (int n = 0; n < 4; ++n)
                acc[m][n] = __builtin_amdgcn_mfma_f32_16x16x32_bf16(af[m], bf[n], acc[m][n], 0, 0, 0);
    }
#pragma unroll
    for (int m = 0; m < 4; ++m)
#pragma unroll
        for (int n = 0; n < 4; ++n) {
            int gr = rt + wr * 64 + m * 16 + (lane >> 4) * 4;
            int gc = ot + wc * 64 + n * 16 + (lane & 15);
            if (gc >= O) continue;
#pragma unroll
            for (int r = 0; r < 4; ++r) {
                int row = gr + r;
                if (row >= R) continue;
                float v = acc[m][n][r];
                if (MODE & 1) v += bias[gc];
                if (MODE & 2) v += res[(size_t)row * ldr + gc];
                if (MODE & 4) ((ushort*)Cout)[(size_t)row * ldc + gc] = f2bf(v);
                else          ((float*)Cout)[(size_t)row * ldc + gc] = v;
            }
        }
}

// ---------------- MFMA attention, 256 queries/block, vectorized swizzled staging ----------------
// Per (b,g): S^T = mfma(K,Q); softmax in-lane + 2 shfl; PV via m-permuted V^T in LDS.
// LDS 16B-groups XOR-swizzled by (row&3) on both buffers (4-way instead of 8-way).
template <int M, int MP, int HOFF>
__global__ __launch_bounds__(256) void attn_mfma(const ushort* __restrict__ q,
        const ushort* __restrict__ kvb, ushort* __restrict__ cat) {
    constexpr int NT = MP / 16;
    constexpr int NCH = MP / 32;
    __shared__ __align__(16) ushort Kl[MP * 32];
    __shared__ __align__(16) ushort VT[32 * MP];
    int g = blockIdx.y, b = blockIdx.z;
    int h = HOFF + g;
    int tid = threadIdx.x;
    // zero-fill (pads stay 0)
    for (int i = tid; i < MP * 4; i += 256) ((s8v*)Kl)[i] = (s8v)0;
    for (int i = tid; i < MP * 4; i += 256) ((s8v*)VT)[i] = (s8v)0;
    __syncthreads();
    // stage K: vector loads, swizzled 16B-group slot = d0 ^ (m&3)
    for (int u = tid; u < M * 3; u += 256) {
        int m = u / 3, d0 = u - m * 3;
        s8v kv8 = *(const s8v*)(kvb + ((size_t)b * M + m) * AD + g * HD + d0 * 8);
        *(s8v*)&Kl[m * 32 + ((d0 ^ (m & 3)) << 3)] = kv8;
    }
    // stage V^T: vector load of V[m][d0*8..+8], scatter to permuted cols, row-swizzled groups
    for (int u = tid; u < M * 3; u += 256) {
        int m = u / 3, d0 = u - m * 3;
        s8v vv = *(const s8v*)(kvb + ((size_t)b * M + m) * AD + 96 + g * HD + d0 * 8);
        int c = m >> 5, mm = m & 31;
        int gg = (mm >> 2) & 3;
        int t = (mm & 3) + ((mm & 16) >> 2);
#pragma unroll
        for (int j = 0; j < 8; ++j) {
            int d = d0 * 8 + j;
            VT[d * MP + ((c * 4 + (gg ^ (d & 3))) << 3) + t] = (ushort)vv[j];
        }
    }
    __syncthreads();
    int w = tid >> 6, lane = tid & 63;
    int ln = lane & 15, g4 = lane >> 4;
    int swz = (g4 ^ (ln & 3)) << 3;
    const float scale = 0.20412414523193154f;  // 24^-0.5
    for (int nt = 0; nt < 4; ++nt) {
        int nbase = blockIdx.x * 256 + nt * 64;
        if (nbase >= NN) break;
        int n0 = nbase + w * 16 + ln;
        s8v qf = (s8v)0;
        if (g4 < 3) qf = *(const s8v*)(q + ((size_t)b * NN + n0) * AD + h * HD + g4 * 8);
        f4v sa[NT];
#pragma unroll
        for (int t = 0; t < NT; ++t) sa[t] = (f4v)0.f;
#pragma unroll
        for (int t = 0; t < NT; ++t) {
            s8v kf = *(const s8v*)&Kl[(t * 16 + ln) * 32 + swz];
            sa[t] = __builtin_amdgcn_mfma_f32_16x16x32_bf16(kf, qf, sa[t], 0, 0, 0);
        }
        float mx = -3.0e38f;
#pragma unroll
        for (int t = 0; t < NT; ++t)
#pragma unroll
            for (int r = 0; r < 4; ++r) {
                int m = t * 16 + g4 * 4 + r;
                float v = (m < M) ? sa[t][r] * scale : -3.0e38f;
                sa[t][r] = v;
                mx = fmaxf(mx, v);
            }
        mx = fmaxf(mx, __shfl_xor(mx, 16, 64));
        mx = fmaxf(mx, __shfl_xor(mx, 32, 64));
        float sum = 0.f;
#pragma unroll
        for (int t = 0; t < NT; ++t)
#pragma unroll
            for (int r = 0; r < 4; ++r) {
                float p = __expf(sa[t][r] - mx);
                sa[t][r] = p;
                sum += p;
            }
        sum += __shfl_xor(sum, 16, 64);
        sum += __shfl_xor(sum, 32, 64);
        float inv = 1.0f / sum;
        f4v oa[2] = {(f4v)0.f, (f4v)0.f};
#pragma unroll
        for (int c = 0; c < NCH; ++c) {
            s8v pb;
#pragma unroll
            for (int t = 0; t < 4; ++t) {
                pb[t]     = (short)f2bf(sa[c * 2][t]);
                pb[4 + t] = (short)f2bf(sa[c * 2 + 1][t]);
            }
#pragma unroll
            for (int dt = 0; dt < 2; ++dt) {
                s8v vf = *(const s8v*)&VT[(dt * 16 + ln) * MP + c * 32 + swz];
                oa[dt] = __builtin_amdgcn_mfma_f32_16x16x32_bf16(vf, pb, oa[dt], 0, 0, 0);
            }
        }
        ushort* op = cat + ((size_t)b * NN + n0) * CC + h * HD;
        s4v o0;
#pragma unroll
        for (int r = 0; r < 4; ++r) o0[r] = (short)f2bf(oa[0][r] * inv);
        *(s4v*)(op + g4 * 4) = o0;
        if (g4 < 2) {
            s4v o1;
#pragma unroll
            for (int r = 0; r < 4; ++r) o1[r] = (short)f2bf(oa[1][r] * inv);
            *(s4v*)(op + 16 + g4 * 4) = o1;
        }
    }
}

// ---------------- depthwise 3x3 on hid=1024, bf16 io, 8ch/thread, wt [9][1024] ----------------
__global__ __launch_bounds__(256) void dwconv_kernel(const ushort* __restrict__ z1,
        const float* __restrict__ wt, const float* __restrict__ bias,
        ushort* __restrict__ z2) {
    int c = (threadIdx.x & 127) * 8;
    int n = blockIdx.x * 2 + (threadIdx.x >> 7);
    int b = blockIdx.y;
    int h = n / WW, wc = n - h * WW;
    const ushort* zb = z1 + (size_t)b * NN * HID;
    float acc[8];
    {
        float4 b0 = *(const float4*)(bias + c);
        float4 b1 = *(const float4*)(bias + c + 4);
        acc[0] = b0.x; acc[1] = b0.y; acc[2] = b0.z; acc[3] = b0.w;
        acc[4] = b1.x; acc[5] = b1.y; acc[6] = b1.z; acc[7] = b1.w;
    }
#pragma unroll
    for (int ky = 0; ky < 3; ++ky) {
        int hy = h + ky - 1;
        if ((unsigned)hy >= (unsigned)HH) continue;
#pragma unroll
        for (int kx = 0; kx < 3; ++kx) {
            int wx = wc + kx - 1;
            if ((unsigned)wx >= (unsigned)WW) continue;
            s8v v = *(const s8v*)(zb + (size_t)(hy * WW + wx) * HID + c);
            const float* wp = wt + (ky * 3 + kx) * HID + c;
            float4 w0 = *(const float4*)wp;
            float4 w1 = *(const float4*)(wp + 4);
            acc[0] = fmaf(bf2f((ushort)v[0]), w0.x, acc[0]);
            acc[1] = fmaf(bf2f((ushort)v[1]), w0.y, acc[1]);
            acc[2] = fmaf(bf2f((ushort)v[2]), w0.z, acc[2]);
            acc[3] = fmaf(bf2f((ushort)v[3]), w0.w, acc[3]);
            acc[4] = fmaf(bf2f((ushort)v[4]), w1.x, acc[4]);
            acc[5] = fmaf(bf2f((ushort)v[5]), w1.y, acc[5]);
            acc[6] = fmaf(bf2f((ushort)v[6]), w1.z, acc[6]);
            acc[7] = fmaf(bf2f((ushort)v[7]), w1.w, acc[7]);
        }
    }
    s8v o;
#pragma unroll
    for (int j = 0; j < 8; ++j) o[j] = (short)f2bf(gelu_f(acc[j]));
    *(s8v*)(z2 + (size_t)b * NN * HID + (size_t)n * HID + c) = o;
}

extern "C" void kernel_launch(void* const* d_in, const int* in_sizes, int n_in,
                              void* d_out, int out_size, void* d_ws, size_t ws_size,
                              hipStream_t stream) {
    const float* x      = (const float*)d_in[0];
    const float* lpu_w  = (const float*)d_in[3];
    const float* lpu_b  = (const float*)d_in[4];
    const float* n1_g   = (const float*)d_in[5];
    const float* n1_b   = (const float*)d_in[6];
    const float* c2_w   = (const float*)d_in[7];
    const float* c2_b   = (const float*)d_in[8];
    const float* cn_g   = (const float*)d_in[9];
    const float* cn_b   = (const float*)d_in[10];
    const float* q_w    = (const float*)d_in[11];
    const float* sr1_w  = (const float*)d_in[12];
    const float* sr1_b  = (const float*)d_in[13];
    const float* an1_g  = (const float*)d_in[14];
    const float* an1_b  = (const float*)d_in[15];
    const float* sr2_w  = (const float*)d_in[16];
    const float* sr2_b  = (const float*)d_in[17];
    const float* an2_g  = (const float*)d_in[18];
    const float* an2_b  = (const float*)d_in[19];
    const float* kv1_w  = (const float*)d_in[20];
    const float* kv2_w  = (const float*)d_in[21];
    const float* proj_w = (const float*)d_in[22];
    const float* proj_b = (const float*)d_in[23];
    const float* n2_g   = (const float*)d_in[24];
    const float* n2_b   = (const float*)d_in[25];
    const float* fc1_w  = (const float*)d_in[26];
    const float* fc1_b  = (const float*)d_in[27];
    const float* dw_w   = (const float*)d_in[28];
    const float* dw_b   = (const float*)d_in[29];
    const float* fc2_w  = (const float*)d_in[30];
    const float* fc2_b  = (const float*)d_in[31];
    float* out = (float*)d_out;

    char* ws = (char*)d_ws;
    size_t off = 0;
    auto allocB = [&](size_t bytes) {
        char* p = ws + off;
        off += ((bytes + 255) & ~(size_t)255);
        return p;
    };
    float*  xbuf = (float*)allocB((size_t)BNR * CC * 4);   // fp32 residual spine
    ushort* ybuf = (ushort*)allocB((size_t)BNR * CC * 2);  // LN out (bf16)
    ushort* wq   = (ushort*)allocB((size_t)AD * AD * 2);
    ushort* wkv1 = (ushort*)allocB((size_t)AD * AD * 2);
    ushort* wkv2 = (ushort*)allocB((size_t)AD * AD * 2);
    ushort* wpr  = (ushort*)allocB((size_t)CC * CC * 2);
    ushort* wf1  = (ushort*)allocB((size_t)HID * CC * 2);
    ushort* wf2  = (ushort*)allocB((size_t)CC * HID * 2);
    ushort* wcp  = (ushort*)allocB((size_t)64 * 576 * 2);
    float*  lpwt = (float*)allocB((size_t)9 * CC * 4);
    float*  dwwt = (float*)allocB((size_t)9 * HID * 4);
    size_t zmark = off;                                    // overlay region start
    ushort* cat  = (ushort*)allocB((size_t)BNR * CC * 2);  // [o1|o2|cp] bf16
    ushort* qbuf = (ushort*)allocB((size_t)BNR * AD * 2);
    ushort* x1g  = (ushort*)allocB((size_t)BB * M1 * AD * 2);
    ushort* x2g  = (ushort*)allocB((size_t)BB * M2 * AD * 2);
    ushort* kv1b = (ushort*)allocB((size_t)BB * M1 * AD * 2);  // bf16 kv
    ushort* kv2b = (ushort*)allocB((size_t)BB * M2 * AD * 2);
    float*  cbuf = (float*)allocB((size_t)BNR * CD * 4);

    int CB2 = 1;
    for (int cb = 16; cb >= 1; cb >>= 1) {
        if (zmark + 2 * (size_t)cb * NN * HID * 2 <= ws_size) { CB2 = cb; break; }
    }

    dim3 b256(256);
    // 0. weight converts / transposes
    cvt_kernel<<<dim3(64), b256, 0, stream>>>(q_w, wq, AD * AD);
    cvt_kernel<<<dim3(64), b256, 0, stream>>>(kv1_w, wkv1, AD * AD);
    cvt_kernel<<<dim3(64), b256, 0, stream>>>(kv2_w, wkv2, AD * AD);
    cvt_kernel<<<dim3(64), b256, 0, stream>>>(proj_w, wpr, CC * CC);
    cvt_kernel<<<dim3(256), b256, 0, stream>>>(fc1_w, wf1, HID * CC);
    cvt_kernel<<<dim3(256), b256, 0, stream>>>(fc2_w, wf2, CC * HID);
    cpwt_kernel<<<dim3(144), b256, 0, stream>>>(c2_w, wcp);
    dwt_kernel<<<dim3(9), b256, 0, stream>>>(lpu_w, lpwt, CC);
    dwt_kernel<<<dim3(36), b256, 0, stream>>>(dw_w, dwwt, HID);
    // 1. LPU + residual
    lpu_kernel<<<dim3(NN / 4, BB), b256, 0, stream>>>(x, lpwt, lpu_b, xbuf);
    // 2. LN1 -> ybuf bf16
    ln256_kernel<<<dim3(BNR / 4), b256, 0, stream>>>(xbuf, n1_g, n1_b, ybuf);
    // 3. cp branch
    cpgemm_kernel<<<dim3(BNR / 128), b256, 0, stream>>>(ybuf, wcp, c2_b, cbuf);
    ln64gelu_kernel<<<dim3(BNR / 4), b256, 0, stream>>>(cbuf, cn_g, cn_b, cat);
    // 4. q = ap @ q_w.T  (bf16 out)
    gemm_mfma<4><<<dim3(2, BNR / 128), b256, 0, stream>>>(
        ybuf + CD, CC, wq, AD, AD, nullptr, nullptr, 0, qbuf, AD, BNR);
    // 5. SR convs + LN + GELU
    sr_kernel<8, 7><<<dim3(M1, BB), dim3(192), 0, stream>>>(ybuf + CD, sr1_w, sr1_b, an1_g, an1_b, x1g);
    sr_kernel<4, 14><<<dim3(M2, BB), dim3(192), 0, stream>>>(ybuf + CD, sr2_w, sr2_b, an2_g, an2_b, x2g);
    // 6. kv GEMMs (bf16 out)
    gemm_mfma<4><<<dim3(2, (BB * M1 + 127) / 128), b256, 0, stream>>>(
        x1g, AD, wkv1, AD, AD, nullptr, nullptr, 0, kv1b, AD, BB * M1);
    gemm_mfma<4><<<dim3(2, (BB * M2 + 127) / 128), b256, 0, stream>>>(
        x2g, AD, wkv2, AD, AD, nullptr, nullptr, 0, kv2b, AD, BB * M2);
    // 7. attention (MFMA, 256 q/block) -> cat cols [0,192)
    attn_mfma<M1, 64, 0><<<dim3((NN + 255) / 256, HG, BB), b256, 0, stream>>>(qbuf, kv1b, cat);
    attn_mfma<M2, 224, HG><<<dim3((NN + 255) / 256, HG, BB), b256, 0, stream>>>(qbuf, kv2b, cat);
    // 8. proj + bias + residual (in-place into xbuf, fp32)
    gemm_mfma<3><<<dim3(2, BNR / 128), b256, 0, stream>>>(
        cat, CC, wpr, CC, CC, proj_b, xbuf, CC, xbuf, CC, BNR);
    // 9. LN2 -> ybuf bf16
    ln256_kernel<<<dim3(BNR / 4), b256, 0, stream>>>(xbuf, n2_g, n2_b, ybuf);
    // 10. MLP in batch chunks
    ushort* z1 = (ushort*)(ws + zmark);
    ushort* z2 = z1 + (size_t)CB2 * NN * HID;
    for (int c0 = 0; c0 < BB; c0 += CB2) {
        size_t tokoff = (size_t)c0 * NN;
        int Rr = CB2 * NN;
        gemm_mfma<5><<<dim3(HID / 128, (Rr + 127) / 128), b256, 0, stream>>>(
            ybuf + tokoff * CC, CC, wf1, CC, HID, fc1_b, nullptr, 0, z1, HID, Rr);
        dwconv_kernel<<<dim3(NN / 2, CB2), b256, 0, stream>>>(z1, dwwt, dw_b, z2);
        gemm_mfma<3><<<dim3(CC / 128, (Rr + 127) / 128), b256, 0, stream>>>(
            z2, HID, wf2, HID, CC, fc2_b, xbuf + tokoff * CC, CC, out + tokoff * CC, CC, Rr);
    }
}

// Round 10
// 555.678 us; speedup vs baseline: 9.1827x; 1.0537x over previous
//
#include <hip/hip_runtime.h>
#include <math.h>

// Problem constants (B=16, H=W=56, C=256)
#define BB   16
#define HH   56
#define WW   56
#define NN   (HH*WW)        // 3136
#define CC   256
#define CD   64
#define AD   192
#define NH   8
#define HG   4
#define HD   24
#define HID  1024
#define M1   49
#define M2   196
#define BNR  (BB*NN)        // 50176

typedef __attribute__((ext_vector_type(8))) short s8v;   // 8 bf16
typedef __attribute__((ext_vector_type(4))) short s4v;
typedef __attribute__((ext_vector_type(4))) float f4v;

// tanh-form GELU: x*sigmoid(1.702-ish exact tanh arg); max dev from erf-GELU ~3e-4
__device__ __forceinline__ float gelu_f(float x) {
    float u = x * (1.0f + 0.044715f * x * x);
    float t = __expf(-1.5957691216f * u);
    return x * __builtin_amdgcn_rcpf(1.0f + t);
}
__device__ __forceinline__ ushort f2bf(float f) {
    union { float f; uint32_t u; } c; c.f = f;
    uint32_t u = c.u;
    return (ushort)((u + 0x7fffu + ((u >> 16) & 1u)) >> 16);
}
__device__ __forceinline__ float bf2f(ushort u) {
    union { uint32_t u; float f; } c; c.u = ((uint32_t)u) << 16;
    return c.f;
}
// async global->LDS, 16B per lane; dest = wave-uniform base + lane*16
__device__ __forceinline__ void load_lds16(const void* gsrc, void* ldst) {
    __builtin_amdgcn_global_load_lds(
        (const __attribute__((address_space(1))) void*)gsrc,
        (__attribute__((address_space(3))) void*)ldst, 16, 0, 0);
}
// bijective XCD-chunked block swizzle (m204): contiguous work per XCD
__device__ __forceinline__ int xcd_swz(int bid, int nwg) {
    int q = nwg >> 3, r = nwg & 7;
    int x = bid & 7, i = bid >> 3;
    return (x < r ? x * (q + 1) : r * (q + 1) + (x - r) * q) + i;
}

// ---------------- generic f32 -> bf16 convert ----------------
__global__ __launch_bounds__(256) void cvt_kernel(const float* __restrict__ src,
        ushort* __restrict__ dst, int n) {
    for (int i = blockIdx.x * 256 + threadIdx.x; i < n; i += gridDim.x * 256)
        dst[i] = f2bf(src[i]);
}

// ---------------- depthwise weight transpose: w[C][9] -> wt[9][C] (fp32) ----------------
__global__ __launch_bounds__(256) void dwt_kernel(const float* __restrict__ w,
        float* __restrict__ wt, int Cn) {
    int idx = blockIdx.x * 256 + threadIdx.x;
    if (idx >= Cn * 9) return;
    int c = idx / 9, t = idx - c * 9;
    wt[t * Cn + c] = w[idx];
}

// ---------------- cp weight transform: wt[co][tap*64+ci] = w[co][ci*9+tap] ----------------
__global__ __launch_bounds__(256) void cpwt_kernel(const float* __restrict__ w,
        ushort* __restrict__ wt) {
    int idx = blockIdx.x * 256 + threadIdx.x;
    if (idx >= 64 * 576) return;
    int co = idx / 576, k = idx - co * 576;
    int tap = k >> 6, ci = k & 63;
    wt[idx] = f2bf(w[co * 576 + ci * 9 + tap]);
}

// ---------------- LPU: depthwise 3x3 + bias + residual (fp32, float4 x 4ch) ----------------
__global__ __launch_bounds__(256) void lpu_kernel(const float* __restrict__ x,
        const float* __restrict__ wt, const float* __restrict__ bias,
        float* __restrict__ out) {
    int c = (threadIdx.x & 63) * 4;
    int bx = xcd_swz(blockIdx.x, NN / 4);
    int n = bx * 4 + (threadIdx.x >> 6);
    int b = blockIdx.y;
    int h = n / WW, wc = n - h * WW;
    const float* xb = x + (size_t)b * NN * CC;
    float4 acc = *(const float4*)(bias + c);
#pragma unroll
    for (int ky = 0; ky < 3; ++ky) {
        int hy = h + ky - 1;
        if ((unsigned)hy >= (unsigned)HH) continue;
#pragma unroll
        for (int kx = 0; kx < 3; ++kx) {
            int wx = wc + kx - 1;
            if ((unsigned)wx >= (unsigned)WW) continue;
            float4 xv = *(const float4*)(xb + (size_t)(hy * WW + wx) * CC + c);
            float4 wv = *(const float4*)(wt + (ky * 3 + kx) * CC + c);
            acc.x = fmaf(xv.x, wv.x, acc.x);
            acc.y = fmaf(xv.y, wv.y, acc.y);
            acc.z = fmaf(xv.z, wv.z, acc.z);
            acc.w = fmaf(xv.w, wv.w, acc.w);
        }
    }
    size_t o = (size_t)b * NN * CC + (size_t)n * CC + c;
    float4 rv = *(const float4*)(x + o);
    acc.x += rv.x; acc.y += rv.y; acc.z += rv.z; acc.w += rv.w;
    *(float4*)(out + o) = acc;
}

// ---------------- LayerNorm over C=256, fp32 in, bf16 out ----------------
__global__ __launch_bounds__(256) void ln256_kernel(const float* __restrict__ x,
        const float* __restrict__ g, const float* __restrict__ bt,
        ushort* __restrict__ y) {
    int lane = threadIdx.x & 63;
    int tok = blockIdx.x * 4 + (threadIdx.x >> 6);
    const float4 v = *(const float4*)(x + (size_t)tok * CC + lane * 4);
    float s = v.x + v.y + v.z + v.w;
    float sq = v.x * v.x + v.y * v.y + v.z * v.z + v.w * v.w;
#pragma unroll
    for (int off = 32; off >= 1; off >>= 1) {
        s += __shfl_xor(s, off, 64);
        sq += __shfl_xor(sq, off, 64);
    }
    float mean = s * (1.0f / 256.0f);
    float var = sq * (1.0f / 256.0f) - mean * mean;
    float rstd = rsqrtf(var + 1e-5f);
    float4 gv = *(const float4*)(g + lane * 4);
    float4 bv = *(const float4*)(bt + lane * 4);
    s4v o;
    o.x = (short)f2bf((v.x - mean) * rstd * gv.x + bv.x);
    o.y = (short)f2bf((v.y - mean) * rstd * gv.y + bv.y);
    o.z = (short)f2bf((v.z - mean) * rstd * gv.z + bv.z);
    o.w = (short)f2bf((v.w - mean) * rstd * gv.w + bv.w);
    *(s4v*)(y + (size_t)tok * CC + lane * 4) = o;
}

// ---------------- cp branch: implicit-GEMM conv via MFMA (swizzled LDS) ----------------
__global__ __launch_bounds__(256) void cpgemm_kernel(
        const ushort* __restrict__ y, const ushort* __restrict__ wt,
        const float* __restrict__ cb, float* __restrict__ cbuf) {
    __shared__ __align__(16) ushort As[128 * 32];
    __shared__ __align__(16) ushort Ws[64 * 32];
    int tid = threadIdx.x;
    int wid = tid >> 6, lane = tid & 63;
    int rt = xcd_swz(blockIdx.x, BNR / 128) * 128;
    int r0 = tid >> 2, c0 = tid & 3;
    int r1 = r0 + 64;
    int tok0 = rt + r0, tok1 = rt + r1;
    int b0 = tok0 / NN, n0 = tok0 - b0 * NN, h0 = n0 / WW, w0 = n0 - h0 * WW;
    int b1 = tok1 / NN, n1 = tok1 - b1 * NN, h1 = n1 / WW, w1 = n1 - h1 * WW;
    const ushort* Wp = wt + (size_t)r0 * 576 + c0 * 8;
    int aw0 = (c0 ^ (r0 & 3)) << 3;   // swizzled write slot (same for r0/r1: r1=r0+64)
    f4v acc[2][4];
#pragma unroll
    for (int m = 0; m < 2; ++m)
#pragma unroll
        for (int n = 0; n < 4; ++n) acc[m][n] = (f4v)0.f;
    int lr = lane & 15;
    int swz = ((lane >> 4) ^ (lr & 3)) << 3;
    for (int kt = 0; kt < 576; kt += 32) {
        int tap = kt >> 6, ci0 = kt & 63;
        int t3 = tap / 3, dy = t3 - 1, dx = (tap - t3 * 3) - 1;
        s8v a0 = (s8v)0, a1 = (s8v)0;
        int hy0 = h0 + dy, wx0 = w0 + dx;
        if ((unsigned)hy0 < (unsigned)HH && (unsigned)wx0 < (unsigned)WW)
            a0 = *(const s8v*)(y + ((size_t)b0 * NN + hy0 * WW + wx0) * CC + ci0 + c0 * 8);
        int hy1 = h1 + dy, wx1 = w1 + dx;
        if ((unsigned)hy1 < (unsigned)HH && (unsigned)wx1 < (unsigned)WW)
            a1 = *(const s8v*)(y + ((size_t)b1 * NN + hy1 * WW + wx1) * CC + ci0 + c0 * 8);
        s8v wv = *(const s8v*)(Wp + kt);
        __syncthreads();
        *(s8v*)&As[r0 * 32 + aw0] = a0;
        *(s8v*)&As[r1 * 32 + aw0] = a1;
        *(s8v*)&Ws[r0 * 32 + aw0] = wv;
        __syncthreads();
        s8v af[2], bf[4];
#pragma unroll
        for (int m = 0; m < 2; ++m)
            af[m] = *(const s8v*)&As[(wid * 32 + m * 16 + lr) * 32 + swz];
#pragma unroll
        for (int n = 0; n < 4; ++n)
            bf[n] = *(const s8v*)&Ws[(n * 16 + lr) * 32 + swz];
#pragma unroll
        for (int m = 0; m < 2; ++m)
#pragma unroll
            for (int n = 0; n < 4; ++n)
                acc[m][n] = __builtin_amdgcn_mfma_f32_16x16x32_bf16(af[m], bf[n], acc[m][n], 0, 0, 0);
    }
#pragma unroll
    for (int m = 0; m < 2; ++m)
#pragma unroll
        for (int n = 0; n < 4; ++n) {
            int gr = rt + wid * 32 + m * 16 + (lane >> 4) * 4;
            int gc = n * 16 + (lane & 15);
#pragma unroll
            for (int r = 0; r < 4; ++r)
                cbuf[(size_t)(gr + r) * 64 + gc] = acc[m][n][r] + cb[gc];
        }
}

// ---------------- LN(64)+GELU epilogue: cbuf fp32 -> cat bf16 cols [192,256) ----------------
__global__ __launch_bounds__(256) void ln64gelu_kernel(const float* __restrict__ cbuf,
        const float* __restrict__ g, const float* __restrict__ bt,
        ushort* __restrict__ cat) {
    int lane = threadIdx.x & 63;
    int tok = blockIdx.x * 4 + (threadIdx.x >> 6);
    float v = cbuf[(size_t)tok * 64 + lane];
    float s = v, sq = v * v;
#pragma unroll
    for (int off = 32; off >= 1; off >>= 1) {
        s += __shfl_xor(s, off, 64);
        sq += __shfl_xor(sq, off, 64);
    }
    float mean = s * (1.0f / 64.0f);
    float var = sq * (1.0f / 64.0f) - mean * mean;
    float rstd = rsqrtf(var + 1e-5f);
    float o = (v - mean) * rstd * g[lane] + bt[lane];
    cat[(size_t)tok * CC + 192 + lane] = f2bf(gelu_f(o));
}

// ---------------- SR conv (depthwise KSxKS stride KS) + LN(192) + GELU, bf16 io ----------------
template <int KS, int OW>
__global__ __launch_bounds__(192) void sr_kernel(const ushort* __restrict__ yap,
        const float* __restrict__ w, const float* __restrict__ bias,
        const float* __restrict__ g, const float* __restrict__ bt,
        ushort* __restrict__ out) {
    int ch = threadIdx.x;
    int m = blockIdx.x, b = blockIdx.y;
    int oh = m / OW, ow = m - oh * OW;
    const ushort* yb = yap + (size_t)b * NN * CC;
    float acc = bias[ch];
#pragma unroll
    for (int ky = 0; ky < KS; ++ky)
#pragma unroll
        for (int kx = 0; kx < KS; ++kx)
            acc = fmaf(bf2f(yb[(size_t)((oh * KS + ky) * WW + ow * KS + kx) * CC + ch]),
                       w[ch * KS * KS + ky * KS + kx], acc);
    __shared__ float red[2][3];
    float s = acc, sq = acc * acc;
#pragma unroll
    for (int off = 32; off >= 1; off >>= 1) {
        s += __shfl_xor(s, off, 64);
        sq += __shfl_xor(sq, off, 64);
    }
    int wv = threadIdx.x >> 6, lane = threadIdx.x & 63;
    if (lane == 0) { red[0][wv] = s; red[1][wv] = sq; }
    __syncthreads();
    s = red[0][0] + red[0][1] + red[0][2];
    sq = red[1][0] + red[1][1] + red[1][2];
    float mean = s * (1.0f / 192.0f);
    float var = sq * (1.0f / 192.0f) - mean * mean;
    float rstd = rsqrtf(var + 1e-5f);
    float v = (acc - mean) * rstd * g[ch] + bt[ch];
    out[((size_t)b * (OW * OW) + m) * AD + ch] = f2bf(gelu_f(v));
}

// ---------------- generic MFMA GEMM with global_load_lds + swizzled LDS ----------------
// bf16 A (R x lda), bf16 W (O x K). Tile 128x128, BK=32, 4 waves (2x2), 4x4 frags.
// MODE bits: 1=bias(fp32), 2=residual(fp32, stride ldr), 4=output bf16 (else fp32)
template <int MODE>
__global__ __launch_bounds__(256) void gemm_mfma(
        const ushort* __restrict__ A, int lda,
        const ushort* __restrict__ W, int K, int O,
        const float* __restrict__ bias,
        const float* __restrict__ res, int ldr,
        void* __restrict__ Cout, int ldc, int R) {
    __shared__ __align__(16) ushort As[128 * 32];
    __shared__ __align__(16) ushort Ws[128 * 32];
    int tid = threadIdx.x;
    int w4 = tid >> 6, lane = tid & 63;
    int wr = w4 >> 1, wc = w4 & 1;
    int nwg = gridDim.x * gridDim.y;
    int swzb = xcd_swz(blockIdx.y * gridDim.x + blockIdx.x, nwg);
    int rt = (swzb / gridDim.x) * 128, ot = (swzb % gridDim.x) * 128;
    int r0 = tid >> 2, cslot = tid & 3;
    int csrc = (cslot ^ (r0 & 3)) * 8;   // inverse-swizzled source column
    const ushort* Ap0 = A + (size_t)min(rt + r0, R - 1) * lda + csrc;
    const ushort* Ap1 = A + (size_t)min(rt + r0 + 64, R - 1) * lda + csrc;
    const ushort* Wp0 = W + (size_t)min(ot + r0, O - 1) * K + csrc;
    const ushort* Wp1 = W + (size_t)min(ot + r0 + 64, O - 1) * K + csrc;
    char* lA0 = (char*)As + w4 * 1024;
    char* lA1 = (char*)As + 4096 + w4 * 1024;
    char* lW0 = (char*)Ws + w4 * 1024;
    char* lW1 = (char*)Ws + 4096 + w4 * 1024;
    f4v acc[4][4];
#pragma unroll
    for (int m = 0; m < 4; ++m)
#pragma unroll
        for (int n = 0; n < 4; ++n) acc[m][n] = (f4v)0.f;
    int lr = lane & 15;
    int swz = ((lane >> 4) ^ (lr & 3)) << 3;
    for (int kt = 0; kt < K; kt += 32) {
        __syncthreads();
        load_lds16(Ap0 + kt, lA0);
        load_lds16(Ap1 + kt, lA1);
        load_lds16(Wp0 + kt, lW0);
        load_lds16(Wp1 + kt, lW1);
        __syncthreads();
        s8v af[4], bf[4];
#pragma unroll
        for (int m = 0; m < 4; ++m)
            af[m] = *(const s8v*)&As[(wr * 64 + m * 16 + lr) * 32 + swz];
#pragma unroll
        for (int n = 0; n < 4; ++n)
            bf[n] = *(const s8v*)&Ws[(wc * 64 + n * 16 + lr) * 32 + swz];
#pragma unroll
        for (int m = 0; m < 4; ++m)
#pragma unroll
            for (int n = 0; n < 4; ++n)
                acc[m][n] = __builtin_amdgcn_mfma_f32_16x16x32_bf16(af[m], bf[n], acc[m][n], 0, 0, 0);
    }
#pragma unroll
    for (int m = 0; m < 4; ++m)
#pragma unroll
        for (int n = 0; n < 4; ++n) {
            int gr = rt + wr * 64 + m * 16 + (lane >> 4) * 4;
            int gc = ot + wc * 64 + n * 16 + (lane & 15);
            if (gc >= O) continue;
#pragma unroll
            for (int r = 0; r < 4; ++r) {
                int row = gr + r;
                if (row >= R) continue;
                float v = acc[m][n][r];
                if (MODE & 1) v += bias[gc];
                if (MODE & 2) v += res[(size_t)row * ldr + gc];
                if (MODE & 4) ((ushort*)Cout)[(size_t)row * ldc + gc] = f2bf(v);
                else          ((float*)Cout)[(size_t)row * ldc + gc] = v;
            }
        }
}

// ---------------- MFMA attention, 256 queries/block, vectorized swizzled staging ----------------
template <int M, int MP, int HOFF>
__global__ __launch_bounds__(256) void attn_mfma(const ushort* __restrict__ q,
        const ushort* __restrict__ kvb, ushort* __restrict__ cat) {
    constexpr int NT = MP / 16;
    constexpr int NCH = MP / 32;
    __shared__ __align__(16) ushort Kl[MP * 32];
    __shared__ __align__(16) ushort VT[32 * MP];
    int g = blockIdx.y, b = blockIdx.z;
    int h = HOFF + g;
    int tid = threadIdx.x;
    for (int i = tid; i < MP * 4; i += 256) ((s8v*)Kl)[i] = (s8v)0;
    for (int i = tid; i < MP * 4; i += 256) ((s8v*)VT)[i] = (s8v)0;
    __syncthreads();
    for (int u = tid; u < M * 3; u += 256) {
        int m = u / 3, d0 = u - m * 3;
        s8v kv8 = *(const s8v*)(kvb + ((size_t)b * M + m) * AD + g * HD + d0 * 8);
        *(s8v*)&Kl[m * 32 + ((d0 ^ (m & 3)) << 3)] = kv8;
    }
    for (int u = tid; u < M * 3; u += 256) {
        int m = u / 3, d0 = u - m * 3;
        s8v vv = *(const s8v*)(kvb + ((size_t)b * M + m) * AD + 96 + g * HD + d0 * 8);
        int c = m >> 5, mm = m & 31;
        int gg = (mm >> 2) & 3;
        int t = (mm & 3) + ((mm & 16) >> 2);
#pragma unroll
        for (int j = 0; j < 8; ++j) {
            int d = d0 * 8 + j;
            VT[d * MP + ((c * 4 + (gg ^ (d & 3))) << 3) + t] = (ushort)vv[j];
        }
    }
    __syncthreads();
    int w = tid >> 6, lane = tid & 63;
    int ln = lane & 15, g4 = lane >> 4;
    int swz = (g4 ^ (ln & 3)) << 3;
    const float scale = 0.20412414523193154f;  // 24^-0.5
    for (int nt = 0; nt < 4; ++nt) {
        int nbase = blockIdx.x * 256 + nt * 64;
        if (nbase >= NN) break;
        int n0 = nbase + w * 16 + ln;
        s8v qf = (s8v)0;
        if (g4 < 3) qf = *(const s8v*)(q + ((size_t)b * NN + n0) * AD + h * HD + g4 * 8);
        f4v sa[NT];
#pragma unroll
        for (int t = 0; t < NT; ++t) sa[t] = (f4v)0.f;
#pragma unroll
        for (int t = 0; t < NT; ++t) {
            s8v kf = *(const s8v*)&Kl[(t * 16 + ln) * 32 + swz];
            sa[t] = __builtin_amdgcn_mfma_f32_16x16x32_bf16(kf, qf, sa[t], 0, 0, 0);
        }
        float mx = -3.0e38f;
#pragma unroll
        for (int t = 0; t < NT; ++t)
#pragma unroll
            for (int r = 0; r < 4; ++r) {
                int m = t * 16 + g4 * 4 + r;
                float v = (m < M) ? sa[t][r] * scale : -3.0e38f;
                sa[t][r] = v;
                mx = fmaxf(mx, v);
            }
        mx = fmaxf(mx, __shfl_xor(mx, 16, 64));
        mx = fmaxf(mx, __shfl_xor(mx, 32, 64));
        float sum = 0.f;
#pragma unroll
        for (int t = 0; t < NT; ++t)
#pragma unroll
            for (int r = 0; r < 4; ++r) {
                float p = __expf(sa[t][r] - mx);
                sa[t][r] = p;
                sum += p;
            }
        sum += __shfl_xor(sum, 16, 64);
        sum += __shfl_xor(sum, 32, 64);
        float inv = 1.0f / sum;
        f4v oa[2] = {(f4v)0.f, (f4v)0.f};
#pragma unroll
        for (int c = 0; c < NCH; ++c) {
            s8v pb;
#pragma unroll
            for (int t = 0; t < 4; ++t) {
                pb[t]     = (short)f2bf(sa[c * 2][t]);
                pb[4 + t] = (short)f2bf(sa[c * 2 + 1][t]);
            }
#pragma unroll
            for (int dt = 0; dt < 2; ++dt) {
                s8v vf = *(const s8v*)&VT[(dt * 16 + ln) * MP + c * 32 + swz];
                oa[dt] = __builtin_amdgcn_mfma_f32_16x16x32_bf16(vf, pb, oa[dt], 0, 0, 0);
            }
        }
        ushort* op = cat + ((size_t)b * NN + n0) * CC + h * HD;
        s4v o0;
#pragma unroll
        for (int r = 0; r < 4; ++r) o0[r] = (short)f2bf(oa[0][r] * inv);
        *(s4v*)(op + g4 * 4) = o0;
        if (g4 < 2) {
            s4v o1;
#pragma unroll
            for (int r = 0; r < 4; ++r) o1[r] = (short)f2bf(oa[1][r] * inv);
            *(s4v*)(op + 16 + g4 * 4) = o1;
        }
    }
}

// ---------------- depthwise 3x3 on hid=1024, bf16 io, 8ch/thread, wt [9][1024] ----------------
__global__ __launch_bounds__(256) void dwconv_kernel(const ushort* __restrict__ z1,
        const float* __restrict__ wt, const float* __restrict__ bias,
        ushort* __restrict__ z2) {
    int c = (threadIdx.x & 127) * 8;
    int bx = xcd_swz(blockIdx.x, NN / 2);
    int n = bx * 2 + (threadIdx.x >> 7);
    int b = blockIdx.y;
    int h = n / WW, wc = n - h * WW;
    const ushort* zb = z1 + (size_t)b * NN * HID;
    float acc[8];
    {
        float4 b0 = *(const float4*)(bias + c);
        float4 b1 = *(const float4*)(bias + c + 4);
        acc[0] = b0.x; acc[1] = b0.y; acc[2] = b0.z; acc[3] = b0.w;
        acc[4] = b1.x; acc[5] = b1.y; acc[6] = b1.z; acc[7] = b1.w;
    }
#pragma unroll
    for (int ky = 0; ky < 3; ++ky) {
        int hy = h + ky - 1;
        if ((unsigned)hy >= (unsigned)HH) continue;
#pragma unroll
        for (int kx = 0; kx < 3; ++kx) {
            int wx = wc + kx - 1;
            if ((unsigned)wx >= (unsigned)WW) continue;
            s8v v = *(const s8v*)(zb + (size_t)(hy * WW + wx) * HID + c);
            const float* wp = wt + (ky * 3 + kx) * HID + c;
            float4 w0 = *(const float4*)wp;
            float4 w1 = *(const float4*)(wp + 4);
            acc[0] = fmaf(bf2f((ushort)v[0]), w0.x, acc[0]);
            acc[1] = fmaf(bf2f((ushort)v[1]), w0.y, acc[1]);
            acc[2] = fmaf(bf2f((ushort)v[2]), w0.z, acc[2]);
            acc[3] = fmaf(bf2f((ushort)v[3]), w0.w, acc[3]);
            acc[4] = fmaf(bf2f((ushort)v[4]), w1.x, acc[4]);
            acc[5] = fmaf(bf2f((ushort)v[5]), w1.y, acc[5]);
            acc[6] = fmaf(bf2f((ushort)v[6]), w1.z, acc[6]);
            acc[7] = fmaf(bf2f((ushort)v[7]), w1.w, acc[7]);
        }
    }
    s8v o;
#pragma unroll
    for (int j = 0; j < 8; ++j) o[j] = (short)f2bf(gelu_f(acc[j]));
    *(s8v*)(z2 + (size_t)b * NN * HID + (size_t)n * HID + c) = o;
}

extern "C" void kernel_launch(void* const* d_in, const int* in_sizes, int n_in,
                              void* d_out, int out_size, void* d_ws, size_t ws_size,
                              hipStream_t stream) {
    const float* x      = (const float*)d_in[0];
    const float* lpu_w  = (const float*)d_in[3];
    const float* lpu_b  = (const float*)d_in[4];
    const float* n1_g   = (const float*)d_in[5];
    const float* n1_b   = (const float*)d_in[6];
    const float* c2_w   = (const float*)d_in[7];
    const float* c2_b   = (const float*)d_in[8];
    const float* cn_g   = (const float*)d_in[9];
    const float* cn_b   = (const float*)d_in[10];
    const float* q_w    = (const float*)d_in[11];
    const float* sr1_w  = (const float*)d_in[12];
    const float* sr1_b  = (const float*)d_in[13];
    const float* an1_g  = (const float*)d_in[14];
    const float* an1_b  = (const float*)d_in[15];
    const float* sr2_w  = (const float*)d_in[16];
    const float* sr2_b  = (const float*)d_in[17];
    const float* an2_g  = (const float*)d_in[18];
    const float* an2_b  = (const float*)d_in[19];
    const float* kv1_w  = (const float*)d_in[20];
    const float* kv2_w  = (const float*)d_in[21];
    const float* proj_w = (const float*)d_in[22];
    const float* proj_b = (const float*)d_in[23];
    const float* n2_g   = (const float*)d_in[24];
    const float* n2_b   = (const float*)d_in[25];
    const float* fc1_w  = (const float*)d_in[26];
    const float* fc1_b  = (const float*)d_in[27];
    const float* dw_w   = (const float*)d_in[28];
    const float* dw_b   = (const float*)d_in[29];
    const float* fc2_w  = (const float*)d_in[30];
    const float* fc2_b  = (const float*)d_in[31];
    float* out = (float*)d_out;

    char* ws = (char*)d_ws;
    size_t off = 0;
    auto allocB = [&](size_t bytes) {
        char* p = ws + off;
        off += ((bytes + 255) & ~(size_t)255);
        return p;
    };
    float*  xbuf = (float*)allocB((size_t)BNR * CC * 4);   // fp32 residual spine
    ushort* ybuf = (ushort*)allocB((size_t)BNR * CC * 2);  // LN out (bf16)
    ushort* wq   = (ushort*)allocB((size_t)AD * AD * 2);
    ushort* wkv1 = (ushort*)allocB((size_t)AD * AD * 2);
    ushort* wkv2 = (ushort*)allocB((size_t)AD * AD * 2);
    ushort* wpr  = (ushort*)allocB((size_t)CC * CC * 2);
    ushort* wf1  = (ushort*)allocB((size_t)HID * CC * 2);
    ushort* wf2  = (ushort*)allocB((size_t)CC * HID * 2);
    ushort* wcp  = (ushort*)allocB((size_t)64 * 576 * 2);
    float*  lpwt = (float*)allocB((size_t)9 * CC * 4);
    float*  dwwt = (float*)allocB((size_t)9 * HID * 4);
    size_t zmark = off;                                    // overlay region start
    ushort* cat  = (ushort*)allocB((size_t)BNR * CC * 2);  // [o1|o2|cp] bf16
    ushort* qbuf = (ushort*)allocB((size_t)BNR * AD * 2);
    ushort* x1g  = (ushort*)allocB((size_t)BB * M1 * AD * 2);
    ushort* x2g  = (ushort*)allocB((size_t)BB * M2 * AD * 2);
    ushort* kv1b = (ushort*)allocB((size_t)BB * M1 * AD * 2);  // bf16 kv
    ushort* kv2b = (ushort*)allocB((size_t)BB * M2 * AD * 2);
    float*  cbuf = (float*)allocB((size_t)BNR * CD * 4);

    int CB2 = 1;
    for (int cb = 16; cb >= 1; cb >>= 1) {
        if (zmark + 2 * (size_t)cb * NN * HID * 2 <= ws_size) { CB2 = cb; break; }
    }

    dim3 b256(256);
    // 0. weight converts / transposes
    cvt_kernel<<<dim3(64), b256, 0, stream>>>(q_w, wq, AD * AD);
    cvt_kernel<<<dim3(64), b256, 0, stream>>>(kv1_w, wkv1, AD * AD);
    cvt_kernel<<<dim3(64), b256, 0, stream>>>(kv2_w, wkv2, AD * AD);
    cvt_kernel<<<dim3(64), b256, 0, stream>>>(proj_w, wpr, CC * CC);
    cvt_kernel<<<dim3(256), b256, 0, stream>>>(fc1_w, wf1, HID * CC);
    cvt_kernel<<<dim3(256), b256, 0, stream>>>(fc2_w, wf2, CC * HID);
    cpwt_kernel<<<dim3(144), b256, 0, stream>>>(c2_w, wcp);
    dwt_kernel<<<dim3(9), b256, 0, stream>>>(lpu_w, lpwt, CC);
    dwt_kernel<<<dim3(36), b256, 0, stream>>>(dw_w, dwwt, HID);
    // 1. LPU + residual (XCD-swizzled)
    lpu_kernel<<<dim3(NN / 4, BB), b256, 0, stream>>>(x, lpwt, lpu_b, xbuf);
    // 2. LN1 -> ybuf bf16
    ln256_kernel<<<dim3(BNR / 4), b256, 0, stream>>>(xbuf, n1_g, n1_b, ybuf);
    // 3. cp branch
    cpgemm_kernel<<<dim3(BNR / 128), b256, 0, stream>>>(ybuf, wcp, c2_b, cbuf);
    ln64gelu_kernel<<<dim3(BNR / 4), b256, 0, stream>>>(cbuf, cn_g, cn_b, cat);
    // 4. q = ap @ q_w.T  (bf16 out)
    gemm_mfma<4><<<dim3(2, BNR / 128), b256, 0, stream>>>(
        ybuf + CD, CC, wq, AD, AD, nullptr, nullptr, 0, qbuf, AD, BNR);
    // 5. SR convs + LN + GELU
    sr_kernel<8, 7><<<dim3(M1, BB), dim3(192), 0, stream>>>(ybuf + CD, sr1_w, sr1_b, an1_g, an1_b, x1g);
    sr_kernel<4, 14><<<dim3(M2, BB), dim3(192), 0, stream>>>(ybuf + CD, sr2_w, sr2_b, an2_g, an2_b, x2g);
    // 6. kv GEMMs (bf16 out)
    gemm_mfma<4><<<dim3(2, (BB * M1 + 127) / 128), b256, 0, stream>>>(
        x1g, AD, wkv1, AD, AD, nullptr, nullptr, 0, kv1b, AD, BB * M1);
    gemm_mfma<4><<<dim3(2, (BB * M2 + 127) / 128), b256, 0, stream>>>(
        x2g, AD, wkv2, AD, AD, nullptr, nullptr, 0, kv2b, AD, BB * M2);
    // 7. attention (MFMA, 256 q/block) -> cat cols [0,192)
    attn_mfma<M1, 64, 0><<<dim3((NN + 255) / 256, HG, BB), b256, 0, stream>>>(qbuf, kv1b, cat);
    attn_mfma<M2, 224, HG><<<dim3((NN + 255) / 256, HG, BB), b256, 0, stream>>>(qbuf, kv2b, cat);
    // 8. proj + bias + residual (in-place into xbuf, fp32)
    gemm_mfma<3><<<dim3(2, BNR / 128), b256, 0, stream>>>(
        cat, CC, wpr, CC, CC, proj_b, xbuf, CC, xbuf, CC, BNR);
    // 9. LN2 -> ybuf bf16
    ln256_kernel<<<dim3(BNR / 4), b256, 0, stream>>>(xbuf, n2_g, n2_b, ybuf);
    // 10. MLP in batch chunks
    ushort* z1 = (ushort*)(ws + zmark);
    ushort* z2 = z1 + (size_t)CB2 * NN * HID;
    for (int c0 = 0; c0 < BB; c0 += CB2) {
        size_t tokoff = (size_t)c0 * NN;
        int Rr = CB2 * NN;
        gemm_mfma<5><<<dim3(HID / 128, (Rr + 127) / 128), b256, 0, stream>>>(
            ybuf + tokoff * CC, CC, wf1, CC, HID, fc1_b, nullptr, 0, z1, HID, Rr);
        dwconv_kernel<<<dim3(NN / 2, CB2), b256, 0, stream>>>(z1, dwwt, dw_b, z2);
        gemm_mfma<3><<<dim3(CC / 128, (Rr + 127) / 128), b256, 0, stream>>>(
            z2, HID, wf2, HID, CC, fc2_b, xbuf + tokoff * CC, CC, out + tokoff * CC, CC, Rr);
    }
}

// Round 11
// 513.539 us; speedup vs baseline: 9.9362x; 1.0821x over previous
//
#include <hip/hip_runtime.h>
#include <math.h>

// Problem constants (B=16, H=W=56, C=256)
#define BB   16
#define HH   56
#define WW   56
#define NN   (HH*WW)        // 3136
#define CC   256
#define CD   64
#define AD   192
#define NH   8
#define HG   4
#define HD   24
#define HID  1024
#define M1   49
#define M2   196
#define BNR  (BB*NN)        // 50176

typedef __attribute__((ext_vector_type(8))) short s8v;   // 8 bf16
typedef __attribute__((ext_vector_type(4))) short s4v;
typedef __attribute__((ext_vector_type(4))) float f4v;

// tanh-form GELU; max dev from erf-GELU ~3e-4
__device__ __forceinline__ float gelu_f(float x) {
    float u = x * (1.0f + 0.044715f * x * x);
    float t = __expf(-1.5957691216f * u);
    return x * __builtin_amdgcn_rcpf(1.0f + t);
}
__device__ __forceinline__ ushort f2bf(float f) {
    union { float f; uint32_t u; } c; c.f = f;
    uint32_t u = c.u;
    return (ushort)((u + 0x7fffu + ((u >> 16) & 1u)) >> 16);
}
__device__ __forceinline__ float bf2f(ushort u) {
    union { uint32_t u; float f; } c; c.u = ((uint32_t)u) << 16;
    return c.f;
}
// async global->LDS, 16B per lane; dest = wave-uniform base + lane*16
__device__ __forceinline__ void load_lds16(const void* gsrc, void* ldst) {
    __builtin_amdgcn_global_load_lds(
        (const __attribute__((address_space(1))) void*)gsrc,
        (__attribute__((address_space(3))) void*)ldst, 16, 0, 0);
}
// bijective XCD-chunked block swizzle (m204)
__device__ __forceinline__ int xcd_swz(int bid, int nwg) {
    int q = nwg >> 3, r = nwg & 7;
    int x = bid & 7, i = bid >> 3;
    return (x < r ? x * (q + 1) : r * (q + 1) + (x - r) * q) + i;
}

// ---------------- generic f32 -> bf16 convert ----------------
__global__ __launch_bounds__(256) void cvt_kernel(const float* __restrict__ src,
        ushort* __restrict__ dst, int n) {
    for (int i = blockIdx.x * 256 + threadIdx.x; i < n; i += gridDim.x * 256)
        dst[i] = f2bf(src[i]);
}

// ---------------- depthwise weight transpose: w[C][9] -> wt[9][C] (fp32) ----------------
__global__ __launch_bounds__(256) void dwt_kernel(const float* __restrict__ w,
        float* __restrict__ wt, int Cn) {
    int idx = blockIdx.x * 256 + threadIdx.x;
    if (idx >= Cn * 9) return;
    int c = idx / 9, t = idx - c * 9;
    wt[t * Cn + c] = w[idx];
}

// ---------------- cp weight transform: wt[co][tap*64+ci] = w[co][ci*9+tap] ----------------
__global__ __launch_bounds__(256) void cpwt_kernel(const float* __restrict__ w,
        ushort* __restrict__ wt) {
    int idx = blockIdx.x * 256 + threadIdx.x;
    if (idx >= 64 * 576) return;
    int co = idx / 576, k = idx - co * 576;
    int tap = k >> 6, ci = k & 63;
    wt[idx] = f2bf(w[co * 576 + ci * 9 + tap]);
}

// ---------------- LPU: depthwise 3x3 + bias + residual + fused LN1 ----------------
// writes xbuf (fp32 spine) AND ybuf (bf16 LN output). wave = one pixel (256 ch).
__global__ __launch_bounds__(256) void lpu_kernel(const float* __restrict__ x,
        const float* __restrict__ wt, const float* __restrict__ bias,
        const float* __restrict__ n1g, const float* __restrict__ n1b,
        float* __restrict__ xbuf, ushort* __restrict__ ybuf) {
    int lane = threadIdx.x & 63;
    int c = lane * 4;
    int bx = xcd_swz(blockIdx.x, NN / 4);
    int n = bx * 4 + (threadIdx.x >> 6);
    int b = blockIdx.y;
    int h = n / WW, wc = n - h * WW;
    const float* xb = x + (size_t)b * NN * CC;
    float4 acc = *(const float4*)(bias + c);
#pragma unroll
    for (int ky = 0; ky < 3; ++ky) {
        int hy = h + ky - 1;
        if ((unsigned)hy >= (unsigned)HH) continue;
#pragma unroll
        for (int kx = 0; kx < 3; ++kx) {
            int wx = wc + kx - 1;
            if ((unsigned)wx >= (unsigned)WW) continue;
            float4 xv = *(const float4*)(xb + (size_t)(hy * WW + wx) * CC + c);
            float4 wv = *(const float4*)(wt + (ky * 3 + kx) * CC + c);
            acc.x = fmaf(xv.x, wv.x, acc.x);
            acc.y = fmaf(xv.y, wv.y, acc.y);
            acc.z = fmaf(xv.z, wv.z, acc.z);
            acc.w = fmaf(xv.w, wv.w, acc.w);
        }
    }
    size_t o = (size_t)b * NN * CC + (size_t)n * CC + c;
    float4 rv = *(const float4*)(x + o);
    acc.x += rv.x; acc.y += rv.y; acc.z += rv.z; acc.w += rv.w;
    *(float4*)(xbuf + o) = acc;
    // fused LN over the wave's 256 channels
    float s = acc.x + acc.y + acc.z + acc.w;
    float sq = acc.x * acc.x + acc.y * acc.y + acc.z * acc.z + acc.w * acc.w;
#pragma unroll
    for (int off = 32; off >= 1; off >>= 1) {
        s += __shfl_xor(s, off, 64);
        sq += __shfl_xor(sq, off, 64);
    }
    float mean = s * (1.0f / 256.0f);
    float var = sq * (1.0f / 256.0f) - mean * mean;
    float rstd = rsqrtf(var + 1e-5f);
    float4 gv = *(const float4*)(n1g + c);
    float4 bv = *(const float4*)(n1b + c);
    s4v ov;
    ov.x = (short)f2bf((acc.x - mean) * rstd * gv.x + bv.x);
    ov.y = (short)f2bf((acc.y - mean) * rstd * gv.y + bv.y);
    ov.z = (short)f2bf((acc.z - mean) * rstd * gv.z + bv.z);
    ov.w = (short)f2bf((acc.w - mean) * rstd * gv.w + bv.w);
    *(s4v*)(ybuf + o) = ov;
}

// ---------------- LayerNorm over C=256, fp32 in, bf16 out (LN2) ----------------
__global__ __launch_bounds__(256) void ln256_kernel(const float* __restrict__ x,
        const float* __restrict__ g, const float* __restrict__ bt,
        ushort* __restrict__ y) {
    int lane = threadIdx.x & 63;
    int tok = blockIdx.x * 4 + (threadIdx.x >> 6);
    const float4 v = *(const float4*)(x + (size_t)tok * CC + lane * 4);
    float s = v.x + v.y + v.z + v.w;
    float sq = v.x * v.x + v.y * v.y + v.z * v.z + v.w * v.w;
#pragma unroll
    for (int off = 32; off >= 1; off >>= 1) {
        s += __shfl_xor(s, off, 64);
        sq += __shfl_xor(sq, off, 64);
    }
    float mean = s * (1.0f / 256.0f);
    float var = sq * (1.0f / 256.0f) - mean * mean;
    float rstd = rsqrtf(var + 1e-5f);
    float4 gv = *(const float4*)(g + lane * 4);
    float4 bv = *(const float4*)(bt + lane * 4);
    s4v o;
    o.x = (short)f2bf((v.x - mean) * rstd * gv.x + bv.x);
    o.y = (short)f2bf((v.y - mean) * rstd * gv.y + bv.y);
    o.z = (short)f2bf((v.z - mean) * rstd * gv.z + bv.z);
    o.w = (short)f2bf((v.w - mean) * rstd * gv.w + bv.w);
    *(s4v*)(y + (size_t)tok * CC + lane * 4) = o;
}

// ---------------- cp branch: implicit-GEMM conv + fused LN(64)+GELU epilogue ----------------
// writes cat cols [192,256) directly (no cbuf).
__global__ __launch_bounds__(256) void cpgemm_kernel(
        const ushort* __restrict__ y, const ushort* __restrict__ wt,
        const float* __restrict__ cb, const float* __restrict__ cng,
        const float* __restrict__ cnb, ushort* __restrict__ cat) {
    __shared__ __align__(16) ushort As[128 * 32];
    __shared__ __align__(16) ushort Ws[64 * 32];
    int tid = threadIdx.x;
    int wid = tid >> 6, lane = tid & 63;
    int rt = xcd_swz(blockIdx.x, BNR / 128) * 128;
    int r0 = tid >> 2, c0 = tid & 3;
    int r1 = r0 + 64;
    int tok0 = rt + r0, tok1 = rt + r1;
    int b0 = tok0 / NN, n0 = tok0 - b0 * NN, h0 = n0 / WW, w0 = n0 - h0 * WW;
    int b1 = tok1 / NN, n1 = tok1 - b1 * NN, h1 = n1 / WW, w1 = n1 - h1 * WW;
    const ushort* Wp = wt + (size_t)r0 * 576 + c0 * 8;
    int aw0 = (c0 ^ (r0 & 3)) << 3;
    f4v acc[2][4];
#pragma unroll
    for (int m = 0; m < 2; ++m)
#pragma unroll
        for (int n = 0; n < 4; ++n) acc[m][n] = (f4v)0.f;
    int lr = lane & 15, g4 = lane >> 4;
    int swz = (g4 ^ (lr & 3)) << 3;
    for (int kt = 0; kt < 576; kt += 32) {
        int tap = kt >> 6, ci0 = kt & 63;
        int t3 = tap / 3, dy = t3 - 1, dx = (tap - t3 * 3) - 1;
        s8v a0 = (s8v)0, a1 = (s8v)0;
        int hy0 = h0 + dy, wx0 = w0 + dx;
        if ((unsigned)hy0 < (unsigned)HH && (unsigned)wx0 < (unsigned)WW)
            a0 = *(const s8v*)(y + ((size_t)b0 * NN + hy0 * WW + wx0) * CC + ci0 + c0 * 8);
        int hy1 = h1 + dy, wx1 = w1 + dx;
        if ((unsigned)hy1 < (unsigned)HH && (unsigned)wx1 < (unsigned)WW)
            a1 = *(const s8v*)(y + ((size_t)b1 * NN + hy1 * WW + wx1) * CC + ci0 + c0 * 8);
        s8v wv = *(const s8v*)(Wp + kt);
        __syncthreads();
        *(s8v*)&As[r0 * 32 + aw0] = a0;
        *(s8v*)&As[r1 * 32 + aw0] = a1;
        *(s8v*)&Ws[r0 * 32 + aw0] = wv;
        __syncthreads();
        s8v af[2], bf[4];
#pragma unroll
        for (int m = 0; m < 2; ++m)
            af[m] = *(const s8v*)&As[(wid * 32 + m * 16 + lr) * 32 + swz];
#pragma unroll
        for (int n = 0; n < 4; ++n)
            bf[n] = *(const s8v*)&Ws[(n * 16 + lr) * 32 + swz];
#pragma unroll
        for (int m = 0; m < 2; ++m)
#pragma unroll
            for (int n = 0; n < 4; ++n)
                acc[m][n] = __builtin_amdgcn_mfma_f32_16x16x32_bf16(af[m], bf[n], acc[m][n], 0, 0, 0);
    }
    // bias, then LN over the 64-wide row (spread over 4 n-frags x 16 lanes of this g4 group)
    float gv[4], bv[4], cbv[4];
#pragma unroll
    for (int n = 0; n < 4; ++n) {
        int gc = n * 16 + lr;
        cbv[n] = cb[gc];
        gv[n] = cng[gc];
        bv[n] = cnb[gc];
    }
#pragma unroll
    for (int m = 0; m < 2; ++m)
#pragma unroll
        for (int r = 0; r < 4; ++r) {
            float s = 0.f, sq = 0.f;
#pragma unroll
            for (int n = 0; n < 4; ++n) {
                float v = acc[m][n][r] + cbv[n];
                acc[m][n][r] = v;
                s += v; sq += v * v;
            }
#pragma unroll
            for (int off = 1; off < 16; off <<= 1) {
                s += __shfl_xor(s, off, 64);
                sq += __shfl_xor(sq, off, 64);
            }
            float mean = s * (1.0f / 64.0f);
            float var = sq * (1.0f / 64.0f) - mean * mean;
            float rstd = rsqrtf(var + 1e-5f);
            int row = rt + wid * 32 + m * 16 + g4 * 4 + r;
            ushort* op = cat + (size_t)row * CC + 192;
#pragma unroll
            for (int n = 0; n < 4; ++n) {
                float v = (acc[m][n][r] - mean) * rstd * gv[n] + bv[n];
                op[n * 16 + lr] = f2bf(gelu_f(v));
            }
        }
}

// ---------------- SR conv (depthwise KSxKS stride KS) + LN(192) + GELU, bf16 io ----------------
template <int KS, int OW>
__global__ __launch_bounds__(192) void sr_kernel(const ushort* __restrict__ yap,
        const float* __restrict__ w, const float* __restrict__ bias,
        const float* __restrict__ g, const float* __restrict__ bt,
        ushort* __restrict__ out) {
    int ch = threadIdx.x;
    int m = blockIdx.x, b = blockIdx.y;
    int oh = m / OW, ow = m - oh * OW;
    const ushort* yb = yap + (size_t)b * NN * CC;
    float acc = bias[ch];
#pragma unroll
    for (int ky = 0; ky < KS; ++ky)
#pragma unroll
        for (int kx = 0; kx < KS; ++kx)
            acc = fmaf(bf2f(yb[(size_t)((oh * KS + ky) * WW + ow * KS + kx) * CC + ch]),
                       w[ch * KS * KS + ky * KS + kx], acc);
    __shared__ float red[2][3];
    float s = acc, sq = acc * acc;
#pragma unroll
    for (int off = 32; off >= 1; off >>= 1) {
        s += __shfl_xor(s, off, 64);
        sq += __shfl_xor(sq, off, 64);
    }
    int wv = threadIdx.x >> 6, lane = threadIdx.x & 63;
    if (lane == 0) { red[0][wv] = s; red[1][wv] = sq; }
    __syncthreads();
    s = red[0][0] + red[0][1] + red[0][2];
    sq = red[1][0] + red[1][1] + red[1][2];
    float mean = s * (1.0f / 192.0f);
    float var = sq * (1.0f / 192.0f) - mean * mean;
    float rstd = rsqrtf(var + 1e-5f);
    float v = (acc - mean) * rstd * g[ch] + bt[ch];
    out[((size_t)b * (OW * OW) + m) * AD + ch] = f2bf(gelu_f(v));
}

// ---------------- generic MFMA GEMM with global_load_lds + swizzled LDS ----------------
template <int MODE>
__global__ __launch_bounds__(256) void gemm_mfma(
        const ushort* __restrict__ A, int lda,
        const ushort* __restrict__ W, int K, int O,
        const float* __restrict__ bias,
        const float* __restrict__ res, int ldr,
        void* __restrict__ Cout, int ldc, int R) {
    __shared__ __align__(16) ushort As[128 * 32];
    __shared__ __align__(16) ushort Ws[128 * 32];
    int tid = threadIdx.x;
    int w4 = tid >> 6, lane = tid & 63;
    int wr = w4 >> 1, wc = w4 & 1;
    int nwg = gridDim.x * gridDim.y;
    int swzb = xcd_swz(blockIdx.y * gridDim.x + blockIdx.x, nwg);
    int rt = (swzb / gridDim.x) * 128, ot = (swzb % gridDim.x) * 128;
    int r0 = tid >> 2, cslot = tid & 3;
    int csrc = (cslot ^ (r0 & 3)) * 8;
    const ushort* Ap0 = A + (size_t)min(rt + r0, R - 1) * lda + csrc;
    const ushort* Ap1 = A + (size_t)min(rt + r0 + 64, R - 1) * lda + csrc;
    const ushort* Wp0 = W + (size_t)min(ot + r0, O - 1) * K + csrc;
    const ushort* Wp1 = W + (size_t)min(ot + r0 + 64, O - 1) * K + csrc;
    char* lA0 = (char*)As + w4 * 1024;
    char* lA1 = (char*)As + 4096 + w4 * 1024;
    char* lW0 = (char*)Ws + w4 * 1024;
    char* lW1 = (char*)Ws + 4096 + w4 * 1024;
    f4v acc[4][4];
#pragma unroll
    for (int m = 0; m < 4; ++m)
#pragma unroll
        for (int n = 0; n < 4; ++n) acc[m][n] = (f4v)0.f;
    int lr = lane & 15;
    int swz = ((lane >> 4) ^ (lr & 3)) << 3;
    for (int kt = 0; kt < K; kt += 32) {
        __syncthreads();
        load_lds16(Ap0 + kt, lA0);
        load_lds16(Ap1 + kt, lA1);
        load_lds16(Wp0 + kt, lW0);
        load_lds16(Wp1 + kt, lW1);
        __syncthreads();
        s8v af[4], bf[4];
#pragma unroll
        for (int m = 0; m < 4; ++m)
            af[m] = *(const s8v*)&As[(wr * 64 + m * 16 + lr) * 32 + swz];
#pragma unroll
        for (int n = 0; n < 4; ++n)
            bf[n] = *(const s8v*)&Ws[(wc * 64 + n * 16 + lr) * 32 + swz];
#pragma unroll
        for (int m = 0; m < 4; ++m)
#pragma unroll
            for (int n = 0; n < 4; ++n)
                acc[m][n] = __builtin_amdgcn_mfma_f32_16x16x32_bf16(af[m], bf[n], acc[m][n], 0, 0, 0);
    }
#pragma unroll
    for (int m = 0; m < 4; ++m)
#pragma unroll
        for (int n = 0; n < 4; ++n) {
            int gr = rt + wr * 64 + m * 16 + (lane >> 4) * 4;
            int gc = ot + wc * 64 + n * 16 + (lane & 15);
            if (gc >= O) continue;
#pragma unroll
            for (int r = 0; r < 4; ++r) {
                int row = gr + r;
                if (row >= R) continue;
                float v = acc[m][n][r];
                if (MODE & 1) v += bias[gc];
                if (MODE & 2) v += res[(size_t)row * ldr + gc];
                if (MODE & 4) ((ushort*)Cout)[(size_t)row * ldc + gc] = f2bf(v);
                else          ((float*)Cout)[(size_t)row * ldc + gc] = v;
            }
        }
}

// ---------------- MFMA attention, 256 queries/block, vectorized swizzled staging ----------------
template <int M, int MP, int HOFF>
__global__ __launch_bounds__(256) void attn_mfma(const ushort* __restrict__ q,
        const ushort* __restrict__ kvb, ushort* __restrict__ cat) {
    constexpr int NT = MP / 16;
    constexpr int NCH = MP / 32;
    __shared__ __align__(16) ushort Kl[MP * 32];
    __shared__ __align__(16) ushort VT[32 * MP];
    int g = blockIdx.y, b = blockIdx.z;
    int h = HOFF + g;
    int tid = threadIdx.x;
    for (int i = tid; i < MP * 4; i += 256) ((s8v*)Kl)[i] = (s8v)0;
    for (int i = tid; i < MP * 4; i += 256) ((s8v*)VT)[i] = (s8v)0;
    __syncthreads();
    for (int u = tid; u < M * 3; u += 256) {
        int m = u / 3, d0 = u - m * 3;
        s8v kv8 = *(const s8v*)(kvb + ((size_t)b * M + m) * AD + g * HD + d0 * 8);
        *(s8v*)&Kl[m * 32 + ((d0 ^ (m & 3)) << 3)] = kv8;
    }
    for (int u = tid; u < M * 3; u += 256) {
        int m = u / 3, d0 = u - m * 3;
        s8v vv = *(const s8v*)(kvb + ((size_t)b * M + m) * AD + 96 + g * HD + d0 * 8);
        int c = m >> 5, mm = m & 31;
        int gg = (mm >> 2) & 3;
        int t = (mm & 3) + ((mm & 16) >> 2);
#pragma unroll
        for (int j = 0; j < 8; ++j) {
            int d = d0 * 8 + j;
            VT[d * MP + ((c * 4 + (gg ^ (d & 3))) << 3) + t] = (ushort)vv[j];
        }
    }
    __syncthreads();
    int w = tid >> 6, lane = tid & 63;
    int ln = lane & 15, g4 = lane >> 4;
    int swz = (g4 ^ (ln & 3)) << 3;
    const float scale = 0.20412414523193154f;  // 24^-0.5
    for (int nt = 0; nt < 4; ++nt) {
        int nbase = blockIdx.x * 256 + nt * 64;
        if (nbase >= NN) break;
        int n0 = nbase + w * 16 + ln;
        s8v qf = (s8v)0;
        if (g4 < 3) qf = *(const s8v*)(q + ((size_t)b * NN + n0) * AD + h * HD + g4 * 8);
        f4v sa[NT];
#pragma unroll
        for (int t = 0; t < NT; ++t) sa[t] = (f4v)0.f;
#pragma unroll
        for (int t = 0; t < NT; ++t) {
            s8v kf = *(const s8v*)&Kl[(t * 16 + ln) * 32 + swz];
            sa[t] = __builtin_amdgcn_mfma_f32_16x16x32_bf16(kf, qf, sa[t], 0, 0, 0);
        }
        float mx = -3.0e38f;
#pragma unroll
        for (int t = 0; t < NT; ++t)
#pragma unroll
            for (int r = 0; r < 4; ++r) {
                int m = t * 16 + g4 * 4 + r;
                float v = (m < M) ? sa[t][r] * scale : -3.0e38f;
                sa[t][r] = v;
                mx = fmaxf(mx, v);
            }
        mx = fmaxf(mx, __shfl_xor(mx, 16, 64));
        mx = fmaxf(mx, __shfl_xor(mx, 32, 64));
        float sum = 0.f;
#pragma unroll
        for (int t = 0; t < NT; ++t)
#pragma unroll
            for (int r = 0; r < 4; ++r) {
                float p = __expf(sa[t][r] - mx);
                sa[t][r] = p;
                sum += p;
            }
        sum += __shfl_xor(sum, 16, 64);
        sum += __shfl_xor(sum, 32, 64);
        float inv = 1.0f / sum;
        f4v oa[2] = {(f4v)0.f, (f4v)0.f};
#pragma unroll
        for (int c = 0; c < NCH; ++c) {
            s8v pb;
#pragma unroll
            for (int t = 0; t < 4; ++t) {
                pb[t]     = (short)f2bf(sa[c * 2][t]);
                pb[4 + t] = (short)f2bf(sa[c * 2 + 1][t]);
            }
#pragma unroll
            for (int dt = 0; dt < 2; ++dt) {
                s8v vf = *(const s8v*)&VT[(dt * 16 + ln) * MP + c * 32 + swz];
                oa[dt] = __builtin_amdgcn_mfma_f32_16x16x32_bf16(vf, pb, oa[dt], 0, 0, 0);
            }
        }
        ushort* op = cat + ((size_t)b * NN + n0) * CC + h * HD;
        s4v o0;
#pragma unroll
        for (int r = 0; r < 4; ++r) o0[r] = (short)f2bf(oa[0][r] * inv);
        *(s4v*)(op + g4 * 4) = o0;
        if (g4 < 2) {
            s4v o1;
#pragma unroll
            for (int r = 0; r < 4; ++r) o1[r] = (short)f2bf(oa[1][r] * inv);
            *(s4v*)(op + 16 + g4 * 4) = o1;
        }
    }
}

// ---------------- depthwise 3x3 hid=1024: x-walk, 4 outputs x 8ch per thread ----------------
// grid (392, CB): bid -> (h, bx); thread -> (xg, cg). wt [9][1024].
__global__ __launch_bounds__(256) void dwconv_kernel(const ushort* __restrict__ z1,
        const float* __restrict__ wt, const float* __restrict__ bias,
        ushort* __restrict__ z2) {
    int bid = xcd_swz(blockIdx.x, HH * 7);
    int h = bid / 7, bx = bid - h * 7;
    int b = blockIdx.y;
    int c = (threadIdx.x & 127) * 8;
    int x0 = bx * 8 + (threadIdx.x >> 7) * 4;
    const ushort* zrow = z1 + ((size_t)b * NN + h * WW) * HID + c;
    // preload weights [9][8]
    float wreg[9][8];
#pragma unroll
    for (int t = 0; t < 9; ++t) {
        float4 w0 = *(const float4*)(wt + t * HID + c);
        float4 w1 = *(const float4*)(wt + t * HID + c + 4);
        wreg[t][0] = w0.x; wreg[t][1] = w0.y; wreg[t][2] = w0.z; wreg[t][3] = w0.w;
        wreg[t][4] = w1.x; wreg[t][5] = w1.y; wreg[t][6] = w1.z; wreg[t][7] = w1.w;
    }
    float acc[4][8];
    {
        float4 b0 = *(const float4*)(bias + c);
        float4 b1 = *(const float4*)(bias + c + 4);
#pragma unroll
        for (int xo = 0; xo < 4; ++xo) {
            acc[xo][0] = b0.x; acc[xo][1] = b0.y; acc[xo][2] = b0.z; acc[xo][3] = b0.w;
            acc[xo][4] = b1.x; acc[xo][5] = b1.y; acc[xo][6] = b1.z; acc[xo][7] = b1.w;
        }
    }
#pragma unroll
    for (int cx = 0; cx < 6; ++cx) {
        int wx = x0 + cx - 1;
        if ((unsigned)wx >= (unsigned)WW) continue;
#pragma unroll
        for (int ky = 0; ky < 3; ++ky) {
            int hy = h + ky - 1;
            if ((unsigned)hy >= (unsigned)HH) continue;
            s8v v = *(const s8v*)(zrow + ((size_t)(ky - 1) * WW + wx) * HID);
            float vf[8];
#pragma unroll
            for (int j = 0; j < 8; ++j) vf[j] = bf2f((ushort)v[j]);
#pragma unroll
            for (int xo = 0; xo < 4; ++xo) {
                int kx = cx - xo;
                if (kx < 0 || kx > 2) continue;
#pragma unroll
                for (int j = 0; j < 8; ++j)
                    acc[xo][j] = fmaf(vf[j], wreg[ky * 3 + kx][j], acc[xo][j]);
            }
        }
    }
    ushort* zo = z2 + ((size_t)b * NN + h * WW + x0) * HID + c;
#pragma unroll
    for (int xo = 0; xo < 4; ++xo) {
        s8v o;
#pragma unroll
        for (int j = 0; j < 8; ++j) o[j] = (short)f2bf(gelu_f(acc[xo][j]));
        *(s8v*)(zo + (size_t)xo * HID) = o;
    }
}

extern "C" void kernel_launch(void* const* d_in, const int* in_sizes, int n_in,
                              void* d_out, int out_size, void* d_ws, size_t ws_size,
                              hipStream_t stream) {
    const float* x      = (const float*)d_in[0];
    const float* lpu_w  = (const float*)d_in[3];
    const float* lpu_b  = (const float*)d_in[4];
    const float* n1_g   = (const float*)d_in[5];
    const float* n1_b   = (const float*)d_in[6];
    const float* c2_w   = (const float*)d_in[7];
    const float* c2_b   = (const float*)d_in[8];
    const float* cn_g   = (const float*)d_in[9];
    const float* cn_b   = (const float*)d_in[10];
    const float* q_w    = (const float*)d_in[11];
    const float* sr1_w  = (const float*)d_in[12];
    const float* sr1_b  = (const float*)d_in[13];
    const float* an1_g  = (const float*)d_in[14];
    const float* an1_b  = (const float*)d_in[15];
    const float* sr2_w  = (const float*)d_in[16];
    const float* sr2_b  = (const float*)d_in[17];
    const float* an2_g  = (const float*)d_in[18];
    const float* an2_b  = (const float*)d_in[19];
    const float* kv1_w  = (const float*)d_in[20];
    const float* kv2_w  = (const float*)d_in[21];
    const float* proj_w = (const float*)d_in[22];
    const float* proj_b = (const float*)d_in[23];
    const float* n2_g   = (const float*)d_in[24];
    const float* n2_b   = (const float*)d_in[25];
    const float* fc1_w  = (const float*)d_in[26];
    const float* fc1_b  = (const float*)d_in[27];
    const float* dw_w   = (const float*)d_in[28];
    const float* dw_b   = (const float*)d_in[29];
    const float* fc2_w  = (const float*)d_in[30];
    const float* fc2_b  = (const float*)d_in[31];
    float* out = (float*)d_out;

    char* ws = (char*)d_ws;
    size_t off = 0;
    auto allocB = [&](size_t bytes) {
        char* p = ws + off;
        off += ((bytes + 255) & ~(size_t)255);
        return p;
    };
    float*  xbuf = (float*)allocB((size_t)BNR * CC * 4);   // fp32 residual spine
    ushort* ybuf = (ushort*)allocB((size_t)BNR * CC * 2);  // LN out (bf16)
    ushort* wq   = (ushort*)allocB((size_t)AD * AD * 2);
    ushort* wkv1 = (ushort*)allocB((size_t)AD * AD * 2);
    ushort* wkv2 = (ushort*)allocB((size_t)AD * AD * 2);
    ushort* wpr  = (ushort*)allocB((size_t)CC * CC * 2);
    ushort* wf1  = (ushort*)allocB((size_t)HID * CC * 2);
    ushort* wf2  = (ushort*)allocB((size_t)CC * HID * 2);
    ushort* wcp  = (ushort*)allocB((size_t)64 * 576 * 2);
    float*  lpwt = (float*)allocB((size_t)9 * CC * 4);
    float*  dwwt = (float*)allocB((size_t)9 * HID * 4);
    size_t zmark = off;                                    // overlay region start
    ushort* cat  = (ushort*)allocB((size_t)BNR * CC * 2);  // [o1|o2|cp] bf16
    ushort* qbuf = (ushort*)allocB((size_t)BNR * AD * 2);
    ushort* x1g  = (ushort*)allocB((size_t)BB * M1 * AD * 2);
    ushort* x2g  = (ushort*)allocB((size_t)BB * M2 * AD * 2);
    ushort* kv1b = (ushort*)allocB((size_t)BB * M1 * AD * 2);  // bf16 kv
    ushort* kv2b = (ushort*)allocB((size_t)BB * M2 * AD * 2);

    int CB2 = 1;
    for (int cb = 16; cb >= 1; cb >>= 1) {
        if (zmark + 2 * (size_t)cb * NN * HID * 2 <= ws_size) { CB2 = cb; break; }
    }

    dim3 b256(256);
    // 0. weight converts / transposes
    cvt_kernel<<<dim3(64), b256, 0, stream>>>(q_w, wq, AD * AD);
    cvt_kernel<<<dim3(64), b256, 0, stream>>>(kv1_w, wkv1, AD * AD);
    cvt_kernel<<<dim3(64), b256, 0, stream>>>(kv2_w, wkv2, AD * AD);
    cvt_kernel<<<dim3(64), b256, 0, stream>>>(proj_w, wpr, CC * CC);
    cvt_kernel<<<dim3(256), b256, 0, stream>>>(fc1_w, wf1, HID * CC);
    cvt_kernel<<<dim3(256), b256, 0, stream>>>(fc2_w, wf2, CC * HID);
    cpwt_kernel<<<dim3(144), b256, 0, stream>>>(c2_w, wcp);
    dwt_kernel<<<dim3(9), b256, 0, stream>>>(lpu_w, lpwt, CC);
    dwt_kernel<<<dim3(36), b256, 0, stream>>>(dw_w, dwwt, HID);
    // 1. LPU + residual + fused LN1 (writes xbuf fp32 and ybuf bf16)
    lpu_kernel<<<dim3(NN / 4, BB), b256, 0, stream>>>(x, lpwt, lpu_b, n1_g, n1_b, xbuf, ybuf);
    // 3. cp branch: MFMA implicit conv + fused LN64+GELU -> cat cols [192,256)
    cpgemm_kernel<<<dim3(BNR / 128), b256, 0, stream>>>(ybuf, wcp, c2_b, cn_g, cn_b, cat);
    // 4. q = ap @ q_w.T  (bf16 out)
    gemm_mfma<4><<<dim3(2, BNR / 128), b256, 0, stream>>>(
        ybuf + CD, CC, wq, AD, AD, nullptr, nullptr, 0, qbuf, AD, BNR);
    // 5. SR convs + LN + GELU
    sr_kernel<8, 7><<<dim3(M1, BB), dim3(192), 0, stream>>>(ybuf + CD, sr1_w, sr1_b, an1_g, an1_b, x1g);
    sr_kernel<4, 14><<<dim3(M2, BB), dim3(192), 0, stream>>>(ybuf + CD, sr2_w, sr2_b, an2_g, an2_b, x2g);
    // 6. kv GEMMs (bf16 out)
    gemm_mfma<4><<<dim3(2, (BB * M1 + 127) / 128), b256, 0, stream>>>(
        x1g, AD, wkv1, AD, AD, nullptr, nullptr, 0, kv1b, AD, BB * M1);
    gemm_mfma<4><<<dim3(2, (BB * M2 + 127) / 128), b256, 0, stream>>>(
        x2g, AD, wkv2, AD, AD, nullptr, nullptr, 0, kv2b, AD, BB * M2);
    // 7. attention (MFMA, 256 q/block) -> cat cols [0,192)
    attn_mfma<M1, 64, 0><<<dim3((NN + 255) / 256, HG, BB), b256, 0, stream>>>(qbuf, kv1b, cat);
    attn_mfma<M2, 224, HG><<<dim3((NN + 255) / 256, HG, BB), b256, 0, stream>>>(qbuf, kv2b, cat);
    // 8. proj + bias + residual (in-place into xbuf, fp32)
    gemm_mfma<3><<<dim3(2, BNR / 128), b256, 0, stream>>>(
        cat, CC, wpr, CC, CC, proj_b, xbuf, CC, xbuf, CC, BNR);
    // 9. LN2 -> ybuf bf16
    ln256_kernel<<<dim3(BNR / 4), b256, 0, stream>>>(xbuf, n2_g, n2_b, ybuf);
    // 10. MLP in batch chunks
    ushort* z1 = (ushort*)(ws + zmark);
    ushort* z2 = z1 + (size_t)CB2 * NN * HID;
    for (int c0 = 0; c0 < BB; c0 += CB2) {
        size_t tokoff = (size_t)c0 * NN;
        int Rr = CB2 * NN;
        gemm_mfma<5><<<dim3(HID / 128, (Rr + 127) / 128), b256, 0, stream>>>(
            ybuf + tokoff * CC, CC, wf1, CC, HID, fc1_b, nullptr, 0, z1, HID, Rr);
        dwconv_kernel<<<dim3(HH * 7, CB2), b256, 0, stream>>>(z1, dwwt, dw_b, z2);
        gemm_mfma<3><<<dim3(CC / 128, (Rr + 127) / 128), b256, 0, stream>>>(
            z2, HID, wf2, HID, CC, fc2_b, xbuf + tokoff * CC, CC, out + tokoff * CC, CC, Rr);
    }
}

// Round 12
// 459.716 us; speedup vs baseline: 11.0995x; 1.1171x over previous
//
#include <hip/hip_runtime.h>
#include <math.h>

// Problem constants (B=16, H=W=56, C=256)
#define BB   16
#define HH   56
#define WW   56
#define NN   (HH*WW)        // 3136
#define CC   256
#define CD   64
#define AD   192
#define NH   8
#define HG   4
#define HD   24
#define HID  1024
#define M1   49
#define M2   196
#define BNR  (BB*NN)        // 50176

typedef __attribute__((ext_vector_type(8))) short s8v;   // 8 bf16
typedef __attribute__((ext_vector_type(4))) short s4v;
typedef __attribute__((ext_vector_type(4))) float f4v;

// tanh-form GELU; max dev from erf-GELU ~3e-4
__device__ __forceinline__ float gelu_f(float x) {
    float u = x * (1.0f + 0.044715f * x * x);
    float t = __expf(-1.5957691216f * u);
    return x * __builtin_amdgcn_rcpf(1.0f + t);
}
__device__ __forceinline__ ushort f2bf(float f) {
    union { float f; uint32_t u; } c; c.f = f;
    uint32_t u = c.u;
    return (ushort)((u + 0x7fffu + ((u >> 16) & 1u)) >> 16);
}
__device__ __forceinline__ float bf2f(ushort u) {
    union { uint32_t u; float f; } c; c.u = ((uint32_t)u) << 16;
    return c.f;
}
// async global->LDS, 16B per lane; dest = wave-uniform base + lane*16
__device__ __forceinline__ void load_lds16(const void* gsrc, void* ldst) {
    __builtin_amdgcn_global_load_lds(
        (const __attribute__((address_space(1))) void*)gsrc,
        (__attribute__((address_space(3))) void*)ldst, 16, 0, 0);
}
// bijective XCD-chunked block swizzle (m204)
__device__ __forceinline__ int xcd_swz(int bid, int nwg) {
    int q = nwg >> 3, r = nwg & 7;
    int x = bid & 7, i = bid >> 3;
    return (x < r ? x * (q + 1) : r * (q + 1) + (x - r) * q) + i;
}

// ---------------- fused weight prep: all converts/transposes in ONE launch ----------------
__global__ __launch_bounds__(256) void wprep_kernel(
        const float* __restrict__ qw, const float* __restrict__ k1,
        const float* __restrict__ k2, const float* __restrict__ pw,
        const float* __restrict__ f1, const float* __restrict__ f2,
        const float* __restrict__ cw, const float* __restrict__ lw,
        const float* __restrict__ dw,
        ushort* __restrict__ wq, ushort* __restrict__ wkv1,
        ushort* __restrict__ wkv2, ushort* __restrict__ wpr,
        ushort* __restrict__ wf1, ushort* __restrict__ wf2,
        ushort* __restrict__ wcp, float* __restrict__ lpwt,
        float* __restrict__ dwwt) {
    int i = blockIdx.x * 256 + threadIdx.x;
    if (i < 36864) { wq[i] = f2bf(qw[i]); return; } i -= 36864;
    if (i < 36864) { wkv1[i] = f2bf(k1[i]); return; } i -= 36864;
    if (i < 36864) { wkv2[i] = f2bf(k2[i]); return; } i -= 36864;
    if (i < 65536) { wpr[i] = f2bf(pw[i]); return; } i -= 65536;
    if (i < 262144) { wf1[i] = f2bf(f1[i]); return; } i -= 262144;
    if (i < 262144) { wf2[i] = f2bf(f2[i]); return; } i -= 262144;
    if (i < 36864) {
        int co = i / 576, k = i - co * 576;
        int tap = k >> 6, ci = k & 63;
        wcp[i] = f2bf(cw[co * 576 + ci * 9 + tap]);
        return;
    } i -= 36864;
    if (i < 2304) { int c = i / 9, t = i - c * 9; lpwt[t * CC + c] = lw[i]; return; } i -= 2304;
    if (i < 9216) { int c = i / 9, t = i - c * 9; dwwt[t * HID + c] = dw[i]; }
}

// ---------------- LPU x-walk: dw3x3 + bias + residual + fused LN1; 4 px/wave ----------------
__global__ __launch_bounds__(256) void lpu_kernel(const float* __restrict__ x,
        const float* __restrict__ wt, const float* __restrict__ bias,
        const float* __restrict__ n1g, const float* __restrict__ n1b,
        float* __restrict__ xbuf, ushort* __restrict__ ybuf) {
    int tid = threadIdx.x;
    int lane = tid & 63, wv = tid >> 6;
    int c = lane * 4;
    int grp = xcd_swz(blockIdx.x, NN / 16) * 4 + wv;   // 0..783
    int n0 = grp * 4;
    int h = n0 / WW, x0 = n0 - h * WW;                 // x0 in {0,4,..,52}
    int b = blockIdx.y;
    const float* xb = x + (size_t)b * NN * CC + c;
    float4 wreg[9];
#pragma unroll
    for (int t = 0; t < 9; ++t) wreg[t] = *(const float4*)(wt + t * CC + c);
    float4 bz = *(const float4*)(bias + c);
    float4 acc[4] = {bz, bz, bz, bz};
#pragma unroll
    for (int cx = 0; cx < 6; ++cx) {
        int wx = x0 + cx - 1;
        if ((unsigned)wx >= (unsigned)WW) continue;
#pragma unroll
        for (int ky = 0; ky < 3; ++ky) {
            int hy = h + ky - 1;
            if ((unsigned)hy >= (unsigned)HH) continue;
            float4 xv = *(const float4*)(xb + (size_t)(hy * WW + wx) * CC);
#pragma unroll
            for (int xo = 0; xo < 4; ++xo) {
                int kx = cx - xo;
                if (kx < 0 || kx > 2) continue;
                float4 wv4 = wreg[ky * 3 + kx];
                acc[xo].x = fmaf(xv.x, wv4.x, acc[xo].x);
                acc[xo].y = fmaf(xv.y, wv4.y, acc[xo].y);
                acc[xo].z = fmaf(xv.z, wv4.z, acc[xo].z);
                acc[xo].w = fmaf(xv.w, wv4.w, acc[xo].w);
            }
        }
    }
    float4 gv = *(const float4*)(n1g + c);
    float4 bv = *(const float4*)(n1b + c);
#pragma unroll
    for (int xo = 0; xo < 4; ++xo) {
        size_t o = ((size_t)b * NN + n0 + xo) * CC + c;
        float4 rv = *(const float4*)(x + o);
        float4 a = acc[xo];
        a.x += rv.x; a.y += rv.y; a.z += rv.z; a.w += rv.w;
        *(float4*)(xbuf + o) = a;
        float s = a.x + a.y + a.z + a.w;
        float sq = a.x * a.x + a.y * a.y + a.z * a.z + a.w * a.w;
#pragma unroll
        for (int off = 32; off >= 1; off >>= 1) {
            s += __shfl_xor(s, off, 64);
            sq += __shfl_xor(sq, off, 64);
        }
        float mean = s * (1.0f / 256.0f);
        float var = sq * (1.0f / 256.0f) - mean * mean;
        float rstd = rsqrtf(var + 1e-5f);
        s4v ov;
        ov.x = (short)f2bf((a.x - mean) * rstd * gv.x + bv.x);
        ov.y = (short)f2bf((a.y - mean) * rstd * gv.y + bv.y);
        ov.z = (short)f2bf((a.z - mean) * rstd * gv.z + bv.z);
        ov.w = (short)f2bf((a.w - mean) * rstd * gv.w + bv.w);
        *(s4v*)(ybuf + o) = ov;
    }
}

// ---------------- cp branch: implicit-GEMM conv + fused LN(64)+GELU epilogue ----------------
__global__ __launch_bounds__(256) void cpgemm_kernel(
        const ushort* __restrict__ y, const ushort* __restrict__ wt,
        const float* __restrict__ cb, const float* __restrict__ cng,
        const float* __restrict__ cnb, ushort* __restrict__ cat) {
    __shared__ __align__(16) ushort As[128 * 32];
    __shared__ __align__(16) ushort Ws[64 * 32];
    int tid = threadIdx.x;
    int wid = tid >> 6, lane = tid & 63;
    int rt = xcd_swz(blockIdx.x, BNR / 128) * 128;
    int r0 = tid >> 2, c0 = tid & 3;
    int r1 = r0 + 64;
    int tok0 = rt + r0, tok1 = rt + r1;
    int b0 = tok0 / NN, n0 = tok0 - b0 * NN, h0 = n0 / WW, w0 = n0 - h0 * WW;
    int b1 = tok1 / NN, n1 = tok1 - b1 * NN, h1 = n1 / WW, w1 = n1 - h1 * WW;
    const ushort* Wp = wt + (size_t)r0 * 576 + c0 * 8;
    int aw0 = (c0 ^ (r0 & 3)) << 3;
    f4v acc[2][4];
#pragma unroll
    for (int m = 0; m < 2; ++m)
#pragma unroll
        for (int n = 0; n < 4; ++n) acc[m][n] = (f4v)0.f;
    int lr = lane & 15, g4 = lane >> 4;
    int swz = (g4 ^ (lr & 3)) << 3;
    for (int kt = 0; kt < 576; kt += 32) {
        int tap = kt >> 6, ci0 = kt & 63;
        int t3 = tap / 3, dy = t3 - 1, dx = (tap - t3 * 3) - 1;
        s8v a0 = (s8v)0, a1 = (s8v)0;
        int hy0 = h0 + dy, wx0 = w0 + dx;
        if ((unsigned)hy0 < (unsigned)HH && (unsigned)wx0 < (unsigned)WW)
            a0 = *(const s8v*)(y + ((size_t)b0 * NN + hy0 * WW + wx0) * CC + ci0 + c0 * 8);
        int hy1 = h1 + dy, wx1 = w1 + dx;
        if ((unsigned)hy1 < (unsigned)HH && (unsigned)wx1 < (unsigned)WW)
            a1 = *(const s8v*)(y + ((size_t)b1 * NN + hy1 * WW + wx1) * CC + ci0 + c0 * 8);
        s8v wv = *(const s8v*)(Wp + kt);
        __syncthreads();
        *(s8v*)&As[r0 * 32 + aw0] = a0;
        *(s8v*)&As[r1 * 32 + aw0] = a1;
        *(s8v*)&Ws[r0 * 32 + aw0] = wv;
        __syncthreads();
        s8v af[2], bf[4];
#pragma unroll
        for (int m = 0; m < 2; ++m)
            af[m] = *(const s8v*)&As[(wid * 32 + m * 16 + lr) * 32 + swz];
#pragma unroll
        for (int n = 0; n < 4; ++n)
            bf[n] = *(const s8v*)&Ws[(n * 16 + lr) * 32 + swz];
#pragma unroll
        for (int m = 0; m < 2; ++m)
#pragma unroll
            for (int n = 0; n < 4; ++n)
                acc[m][n] = __builtin_amdgcn_mfma_f32_16x16x32_bf16(af[m], bf[n], acc[m][n], 0, 0, 0);
    }
    float gv[4], bv[4], cbv[4];
#pragma unroll
    for (int n = 0; n < 4; ++n) {
        int gc = n * 16 + lr;
        cbv[n] = cb[gc];
        gv[n] = cng[gc];
        bv[n] = cnb[gc];
    }
#pragma unroll
    for (int m = 0; m < 2; ++m)
#pragma unroll
        for (int r = 0; r < 4; ++r) {
            float s = 0.f, sq = 0.f;
#pragma unroll
            for (int n = 0; n < 4; ++n) {
                float v = acc[m][n][r] + cbv[n];
                acc[m][n][r] = v;
                s += v; sq += v * v;
            }
#pragma unroll
            for (int off = 1; off < 16; off <<= 1) {
                s += __shfl_xor(s, off, 64);
                sq += __shfl_xor(sq, off, 64);
            }
            float mean = s * (1.0f / 64.0f);
            float var = sq * (1.0f / 64.0f) - mean * mean;
            float rstd = rsqrtf(var + 1e-5f);
            int row = rt + wid * 32 + m * 16 + g4 * 4 + r;
            ushort* op = cat + (size_t)row * CC + 192;
#pragma unroll
            for (int n = 0; n < 4; ++n) {
                float v = (acc[m][n][r] - mean) * rstd * gv[n] + bv[n];
                op[n * 16 + lr] = f2bf(gelu_f(v));
            }
        }
}

// ---------------- SR conv (depthwise KSxKS stride KS) + LN(192) + GELU, bf16 io ----------------
template <int KS, int OW>
__global__ __launch_bounds__(192) void sr_kernel(const ushort* __restrict__ yap,
        const float* __restrict__ w, const float* __restrict__ bias,
        const float* __restrict__ g, const float* __restrict__ bt,
        ushort* __restrict__ out) {
    int ch = threadIdx.x;
    int m = blockIdx.x, b = blockIdx.y;
    int oh = m / OW, ow = m - oh * OW;
    const ushort* yb = yap + (size_t)b * NN * CC;
    float acc = bias[ch];
#pragma unroll
    for (int ky = 0; ky < KS; ++ky)
#pragma unroll
        for (int kx = 0; kx < KS; ++kx)
            acc = fmaf(bf2f(yb[(size_t)((oh * KS + ky) * WW + ow * KS + kx) * CC + ch]),
                       w[ch * KS * KS + ky * KS + kx], acc);
    __shared__ float red[2][3];
    float s = acc, sq = acc * acc;
#pragma unroll
    for (int off = 32; off >= 1; off >>= 1) {
        s += __shfl_xor(s, off, 64);
        sq += __shfl_xor(sq, off, 64);
    }
    int wv = threadIdx.x >> 6, lane = threadIdx.x & 63;
    if (lane == 0) { red[0][wv] = s; red[1][wv] = sq; }
    __syncthreads();
    s = red[0][0] + red[0][1] + red[0][2];
    sq = red[1][0] + red[1][1] + red[1][2];
    float mean = s * (1.0f / 192.0f);
    float var = sq * (1.0f / 192.0f) - mean * mean;
    float rstd = rsqrtf(var + 1e-5f);
    float v = (acc - mean) * rstd * g[ch] + bt[ch];
    out[((size_t)b * (OW * OW) + m) * AD + ch] = f2bf(gelu_f(v));
}

// ---------------- generic MFMA GEMM with global_load_lds + swizzled LDS ----------------
template <int MODE>
__global__ __launch_bounds__(256) void gemm_mfma(
        const ushort* __restrict__ A, int lda,
        const ushort* __restrict__ W, int K, int O,
        const float* __restrict__ bias,
        const float* __restrict__ res, int ldr,
        void* __restrict__ Cout, int ldc, int R) {
    __shared__ __align__(16) ushort As[128 * 32];
    __shared__ __align__(16) ushort Ws[128 * 32];
    int tid = threadIdx.x;
    int w4 = tid >> 6, lane = tid & 63;
    int wr = w4 >> 1, wc = w4 & 1;
    int nwg = gridDim.x * gridDim.y;
    int swzb = xcd_swz(blockIdx.y * gridDim.x + blockIdx.x, nwg);
    int rt = (swzb / gridDim.x) * 128, ot = (swzb % gridDim.x) * 128;
    int r0 = tid >> 2, cslot = tid & 3;
    int csrc = (cslot ^ (r0 & 3)) * 8;
    const ushort* Ap0 = A + (size_t)min(rt + r0, R - 1) * lda + csrc;
    const ushort* Ap1 = A + (size_t)min(rt + r0 + 64, R - 1) * lda + csrc;
    const ushort* Wp0 = W + (size_t)min(ot + r0, O - 1) * K + csrc;
    const ushort* Wp1 = W + (size_t)min(ot + r0 + 64, O - 1) * K + csrc;
    char* lA0 = (char*)As + w4 * 1024;
    char* lA1 = (char*)As + 4096 + w4 * 1024;
    char* lW0 = (char*)Ws + w4 * 1024;
    char* lW1 = (char*)Ws + 4096 + w4 * 1024;
    f4v acc[4][4];
#pragma unroll
    for (int m = 0; m < 4; ++m)
#pragma unroll
        for (int n = 0; n < 4; ++n) acc[m][n] = (f4v)0.f;
    int lr = lane & 15;
    int swz = ((lane >> 4) ^ (lr & 3)) << 3;
    for (int kt = 0; kt < K; kt += 32) {
        __syncthreads();
        load_lds16(Ap0 + kt, lA0);
        load_lds16(Ap1 + kt, lA1);
        load_lds16(Wp0 + kt, lW0);
        load_lds16(Wp1 + kt, lW1);
        __syncthreads();
        s8v af[4], bf[4];
#pragma unroll
        for (int m = 0; m < 4; ++m)
            af[m] = *(const s8v*)&As[(wr * 64 + m * 16 + lr) * 32 + swz];
#pragma unroll
        for (int n = 0; n < 4; ++n)
            bf[n] = *(const s8v*)&Ws[(wc * 64 + n * 16 + lr) * 32 + swz];
#pragma unroll
        for (int m = 0; m < 4; ++m)
#pragma unroll
            for (int n = 0; n < 4; ++n)
                acc[m][n] = __builtin_amdgcn_mfma_f32_16x16x32_bf16(af[m], bf[n], acc[m][n], 0, 0, 0);
    }
#pragma unroll
    for (int m = 0; m < 4; ++m)
#pragma unroll
        for (int n = 0; n < 4; ++n) {
            int gr = rt + wr * 64 + m * 16 + (lane >> 4) * 4;
            int gc = ot + wc * 64 + n * 16 + (lane & 15);
            if (gc >= O) continue;
#pragma unroll
            for (int r = 0; r < 4; ++r) {
                int row = gr + r;
                if (row >= R) continue;
                float v = acc[m][n][r];
                if (MODE & 1) v += bias[gc];
                if (MODE & 2) v += res[(size_t)row * ldr + gc];
                if (MODE & 4) ((ushort*)Cout)[(size_t)row * ldc + gc] = f2bf(v);
                else          ((float*)Cout)[(size_t)row * ldc + gc] = v;
            }
        }
}

// ---------------- proj (O=256 full width) + bias + residual + fused LN2 ----------------
// tile 128 rows x 256 cols, wave = 32 rows x 256 cols. Writes xbuf fp32 + ybuf bf16 (LN2).
__global__ __launch_bounds__(256) void projln_kernel(
        const ushort* __restrict__ A, const ushort* __restrict__ W,
        const float* __restrict__ bias,
        const float* __restrict__ n2g, const float* __restrict__ n2b,
        float* __restrict__ xbuf, ushort* __restrict__ ybuf) {
    __shared__ __align__(16) ushort As[128 * 32];
    __shared__ __align__(16) ushort Ws[256 * 32];
    int tid = threadIdx.x;
    int w4 = tid >> 6, lane = tid & 63;
    int rt = xcd_swz(blockIdx.x, BNR / 128) * 128;
    int r0 = tid >> 2, cslot = tid & 3;
    int csrc = (cslot ^ (r0 & 3)) * 8;
    const ushort* Ap0 = A + (size_t)(rt + r0) * CC + csrc;
    const ushort* Ap1 = A + (size_t)(rt + r0 + 64) * CC + csrc;
    const ushort* Wp0 = W + (size_t)r0 * CC + csrc;
    const ushort* Wp1 = W + (size_t)(r0 + 64) * CC + csrc;
    const ushort* Wp2 = W + (size_t)(r0 + 128) * CC + csrc;
    const ushort* Wp3 = W + (size_t)(r0 + 192) * CC + csrc;
    char* lA0 = (char*)As + w4 * 1024;
    char* lA1 = (char*)As + 4096 + w4 * 1024;
    char* lW0 = (char*)Ws + w4 * 1024;
    char* lW1 = (char*)Ws + 4096 + w4 * 1024;
    char* lW2 = (char*)Ws + 8192 + w4 * 1024;
    char* lW3 = (char*)Ws + 12288 + w4 * 1024;
    int lr = lane & 15, g4 = lane >> 4;
    int swz = (g4 ^ (lr & 3)) << 3;
    f4v acc[2][16];
#pragma unroll
    for (int m = 0; m < 2; ++m)
#pragma unroll
        for (int n = 0; n < 16; ++n) acc[m][n] = (f4v)(bias[n * 16 + lr]);
    for (int kt = 0; kt < CC; kt += 32) {
        __syncthreads();
        load_lds16(Ap0 + kt, lA0);
        load_lds16(Ap1 + kt, lA1);
        load_lds16(Wp0 + kt, lW0);
        load_lds16(Wp1 + kt, lW1);
        load_lds16(Wp2 + kt, lW2);
        load_lds16(Wp3 + kt, lW3);
        __syncthreads();
        s8v af0 = *(const s8v*)&As[(w4 * 32 + lr) * 32 + swz];
        s8v af1 = *(const s8v*)&As[(w4 * 32 + 16 + lr) * 32 + swz];
#pragma unroll
        for (int n = 0; n < 16; ++n) {
            s8v bf = *(const s8v*)&Ws[(n * 16 + lr) * 32 + swz];
            acc[0][n] = __builtin_amdgcn_mfma_f32_16x16x32_bf16(af0, bf, acc[0][n], 0, 0, 0);
            acc[1][n] = __builtin_amdgcn_mfma_f32_16x16x32_bf16(af1, bf, acc[1][n], 0, 0, 0);
        }
    }
    // epilogue: + residual -> xbuf fp32; LN over 256 -> ybuf bf16
#pragma unroll
    for (int m = 0; m < 2; ++m)
#pragma unroll
        for (int r = 0; r < 4; ++r) {
            int row = rt + w4 * 32 + m * 16 + g4 * 4 + r;
            float* xr = xbuf + (size_t)row * CC;
            ushort* yr = ybuf + (size_t)row * CC;
            float s = 0.f, sq = 0.f;
#pragma unroll
            for (int n = 0; n < 16; ++n) {
                float v = acc[m][n][r] + xr[n * 16 + lr];
                acc[m][n][r] = v;
                s += v; sq += v * v;
            }
#pragma unroll
            for (int off = 1; off < 16; off <<= 1) {
                s += __shfl_xor(s, off, 64);
                sq += __shfl_xor(sq, off, 64);
            }
            float mean = s * (1.0f / 256.0f);
            float var = sq * (1.0f / 256.0f) - mean * mean;
            float rstd = rsqrtf(var + 1e-5f);
#pragma unroll
            for (int n = 0; n < 16; ++n) {
                int col = n * 16 + lr;
                float v = acc[m][n][r];
                xr[col] = v;
                yr[col] = f2bf((v - mean) * rstd * n2g[col] + n2b[col]);
            }
        }
}

// ---------------- MFMA attention, 256 queries/block, vectorized swizzled staging ----------------
template <int M, int MP, int HOFF>
__global__ __launch_bounds__(256) void attn_mfma(const ushort* __restrict__ q,
        const ushort* __restrict__ kvb, ushort* __restrict__ cat) {
    constexpr int NT = MP / 16;
    constexpr int NCH = MP / 32;
    __shared__ __align__(16) ushort Kl[MP * 32];
    __shared__ __align__(16) ushort VT[32 * MP];
    int g = blockIdx.y, b = blockIdx.z;
    int h = HOFF + g;
    int tid = threadIdx.x;
    for (int i = tid; i < MP * 4; i += 256) ((s8v*)Kl)[i] = (s8v)0;
    for (int i = tid; i < MP * 4; i += 256) ((s8v*)VT)[i] = (s8v)0;
    __syncthreads();
    for (int u = tid; u < M * 3; u += 256) {
        int m = u / 3, d0 = u - m * 3;
        s8v kv8 = *(const s8v*)(kvb + ((size_t)b * M + m) * AD + g * HD + d0 * 8);
        *(s8v*)&Kl[m * 32 + ((d0 ^ (m & 3)) << 3)] = kv8;
    }
    for (int u = tid; u < M * 3; u += 256) {
        int m = u / 3, d0 = u - m * 3;
        s8v vv = *(const s8v*)(kvb + ((size_t)b * M + m) * AD + 96 + g * HD + d0 * 8);
        int c = m >> 5, mm = m & 31;
        int gg = (mm >> 2) & 3;
        int t = (mm & 3) + ((mm & 16) >> 2);
#pragma unroll
        for (int j = 0; j < 8; ++j) {
            int d = d0 * 8 + j;
            VT[d * MP + ((c * 4 + (gg ^ (d & 3))) << 3) + t] = (ushort)vv[j];
        }
    }
    __syncthreads();
    int w = tid >> 6, lane = tid & 63;
    int ln = lane & 15, g4 = lane >> 4;
    int swz = (g4 ^ (ln & 3)) << 3;
    const float scale = 0.20412414523193154f;  // 24^-0.5
    for (int nt = 0; nt < 4; ++nt) {
        int nbase = blockIdx.x * 256 + nt * 64;
        if (nbase >= NN) break;
        int n0 = nbase + w * 16 + ln;
        s8v qf = (s8v)0;
        if (g4 < 3) qf = *(const s8v*)(q + ((size_t)b * NN + n0) * AD + h * HD + g4 * 8);
        f4v sa[NT];
#pragma unroll
        for (int t = 0; t < NT; ++t) sa[t] = (f4v)0.f;
#pragma unroll
        for (int t = 0; t < NT; ++t) {
            s8v kf = *(const s8v*)&Kl[(t * 16 + ln) * 32 + swz];
            sa[t] = __builtin_amdgcn_mfma_f32_16x16x32_bf16(kf, qf, sa[t], 0, 0, 0);
        }
        float mx = -3.0e38f;
#pragma unroll
        for (int t = 0; t < NT; ++t)
#pragma unroll
            for (int r = 0; r < 4; ++r) {
                int m = t * 16 + g4 * 4 + r;
                float v = (m < M) ? sa[t][r] * scale : -3.0e38f;
                sa[t][r] = v;
                mx = fmaxf(mx, v);
            }
        mx = fmaxf(mx, __shfl_xor(mx, 16, 64));
        mx = fmaxf(mx, __shfl_xor(mx, 32, 64));
        float sum = 0.f;
#pragma unroll
        for (int t = 0; t < NT; ++t)
#pragma unroll
            for (int r = 0; r < 4; ++r) {
                float p = __expf(sa[t][r] - mx);
                sa[t][r] = p;
                sum += p;
            }
        sum += __shfl_xor(sum, 16, 64);
        sum += __shfl_xor(sum, 32, 64);
        float inv = 1.0f / sum;
        f4v oa[2] = {(f4v)0.f, (f4v)0.f};
#pragma unroll
        for (int c = 0; c < NCH; ++c) {
            s8v pb;
#pragma unroll
            for (int t = 0; t < 4; ++t) {
                pb[t]     = (short)f2bf(sa[c * 2][t]);
                pb[4 + t] = (short)f2bf(sa[c * 2 + 1][t]);
            }
#pragma unroll
            for (int dt = 0; dt < 2; ++dt) {
                s8v vf = *(const s8v*)&VT[(dt * 16 + ln) * MP + c * 32 + swz];
                oa[dt] = __builtin_amdgcn_mfma_f32_16x16x32_bf16(vf, pb, oa[dt], 0, 0, 0);
            }
        }
        ushort* op = cat + ((size_t)b * NN + n0) * CC + h * HD;
        s4v o0;
#pragma unroll
        for (int r = 0; r < 4; ++r) o0[r] = (short)f2bf(oa[0][r] * inv);
        *(s4v*)(op + g4 * 4) = o0;
        if (g4 < 2) {
            s4v o1;
#pragma unroll
            for (int r = 0; r < 4; ++r) o1[r] = (short)f2bf(oa[1][r] * inv);
            *(s4v*)(op + 16 + g4 * 4) = o1;
        }
    }
}

// ---------------- depthwise 3x3 hid=1024: x-walk, 4 outputs x 8ch per thread ----------------
__global__ __launch_bounds__(256) void dwconv_kernel(const ushort* __restrict__ z1,
        const float* __restrict__ wt, const float* __restrict__ bias,
        ushort* __restrict__ z2) {
    int bid = xcd_swz(blockIdx.x, HH * 7);
    int h = bid / 7, bx = bid - h * 7;
    int b = blockIdx.y;
    int c = (threadIdx.x & 127) * 8;
    int x0 = bx * 8 + (threadIdx.x >> 7) * 4;
    const ushort* zrow = z1 + ((size_t)b * NN + h * WW) * HID + c;
    float wreg[9][8];
#pragma unroll
    for (int t = 0; t < 9; ++t) {
        float4 w0 = *(const float4*)(wt + t * HID + c);
        float4 w1 = *(const float4*)(wt + t * HID + c + 4);
        wreg[t][0] = w0.x; wreg[t][1] = w0.y; wreg[t][2] = w0.z; wreg[t][3] = w0.w;
        wreg[t][4] = w1.x; wreg[t][5] = w1.y; wreg[t][6] = w1.z; wreg[t][7] = w1.w;
    }
    float acc[4][8];
    {
        float4 b0 = *(const float4*)(bias + c);
        float4 b1 = *(const float4*)(bias + c + 4);
#pragma unroll
        for (int xo = 0; xo < 4; ++xo) {
            acc[xo][0] = b0.x; acc[xo][1] = b0.y; acc[xo][2] = b0.z; acc[xo][3] = b0.w;
            acc[xo][4] = b1.x; acc[xo][5] = b1.y; acc[xo][6] = b1.z; acc[xo][7] = b1.w;
        }
    }
#pragma unroll
    for (int cx = 0; cx < 6; ++cx) {
        int wx = x0 + cx - 1;
        if ((unsigned)wx >= (unsigned)WW) continue;
#pragma unroll
        for (int ky = 0; ky < 3; ++ky) {
            int hy = h + ky - 1;
            if ((unsigned)hy >= (unsigned)HH) continue;
            s8v v = *(const s8v*)(zrow + ((size_t)(ky - 1) * WW + wx) * HID);
            float vf[8];
#pragma unroll
            for (int j = 0; j < 8; ++j) vf[j] = bf2f((ushort)v[j]);
#pragma unroll
            for (int xo = 0; xo < 4; ++xo) {
                int kx = cx - xo;
                if (kx < 0 || kx > 2) continue;
#pragma unroll
                for (int j = 0; j < 8; ++j)
                    acc[xo][j] = fmaf(vf[j], wreg[ky * 3 + kx][j], acc[xo][j]);
            }
        }
    }
    ushort* zo = z2 + ((size_t)b * NN + h * WW + x0) * HID + c;
#pragma unroll
    for (int xo = 0; xo < 4; ++xo) {
        s8v o;
#pragma unroll
        for (int j = 0; j < 8; ++j) o[j] = (short)f2bf(gelu_f(acc[xo][j]));
        *(s8v*)(zo + (size_t)xo * HID) = o;
    }
}

extern "C" void kernel_launch(void* const* d_in, const int* in_sizes, int n_in,
                              void* d_out, int out_size, void* d_ws, size_t ws_size,
                              hipStream_t stream) {
    const float* x      = (const float*)d_in[0];
    const float* lpu_w  = (const float*)d_in[3];
    const float* lpu_b  = (const float*)d_in[4];
    const float* n1_g   = (const float*)d_in[5];
    const float* n1_b   = (const float*)d_in[6];
    const float* c2_w   = (const float*)d_in[7];
    const float* c2_b   = (const float*)d_in[8];
    const float* cn_g   = (const float*)d_in[9];
    const float* cn_b   = (const float*)d_in[10];
    const float* q_w    = (const float*)d_in[11];
    const float* sr1_w  = (const float*)d_in[12];
    const float* sr1_b  = (const float*)d_in[13];
    const float* an1_g  = (const float*)d_in[14];
    const float* an1_b  = (const float*)d_in[15];
    const float* sr2_w  = (const float*)d_in[16];
    const float* sr2_b  = (const float*)d_in[17];
    const float* an2_g  = (const float*)d_in[18];
    const float* an2_b  = (const float*)d_in[19];
    const float* kv1_w  = (const float*)d_in[20];
    const float* kv2_w  = (const float*)d_in[21];
    const float* proj_w = (const float*)d_in[22];
    const float* proj_b = (const float*)d_in[23];
    const float* n2_g   = (const float*)d_in[24];
    const float* n2_b   = (const float*)d_in[25];
    const float* fc1_w  = (const float*)d_in[26];
    const float* fc1_b  = (const float*)d_in[27];
    const float* dw_w   = (const float*)d_in[28];
    const float* dw_b   = (const float*)d_in[29];
    const float* fc2_w  = (const float*)d_in[30];
    const float* fc2_b  = (const float*)d_in[31];
    float* out = (float*)d_out;

    char* ws = (char*)d_ws;
    size_t off = 0;
    auto allocB = [&](size_t bytes) {
        char* p = ws + off;
        off += ((bytes + 255) & ~(size_t)255);
        return p;
    };
    float*  xbuf = (float*)allocB((size_t)BNR * CC * 4);   // fp32 residual spine
    ushort* ybuf = (ushort*)allocB((size_t)BNR * CC * 2);  // LN out (bf16)
    ushort* wq   = (ushort*)allocB((size_t)AD * AD * 2);
    ushort* wkv1 = (ushort*)allocB((size_t)AD * AD * 2);
    ushort* wkv2 = (ushort*)allocB((size_t)AD * AD * 2);
    ushort* wpr  = (ushort*)allocB((size_t)CC * CC * 2);
    ushort* wf1  = (ushort*)allocB((size_t)HID * CC * 2);
    ushort* wf2  = (ushort*)allocB((size_t)CC * HID * 2);
    ushort* wcp  = (ushort*)allocB((size_t)64 * 576 * 2);
    float*  lpwt = (float*)allocB((size_t)9 * CC * 4);
    float*  dwwt = (float*)allocB((size_t)9 * HID * 4);
    size_t zmark = off;                                    // overlay region start
    ushort* cat  = (ushort*)allocB((size_t)BNR * CC * 2);  // [o1|o2|cp] bf16
    ushort* qbuf = (ushort*)allocB((size_t)BNR * AD * 2);
    ushort* x1g  = (ushort*)allocB((size_t)BB * M1 * AD * 2);
    ushort* x2g  = (ushort*)allocB((size_t)BB * M2 * AD * 2);
    ushort* kv1b = (ushort*)allocB((size_t)BB * M1 * AD * 2);  // bf16 kv
    ushort* kv2b = (ushort*)allocB((size_t)BB * M2 * AD * 2);

    int CB2 = 1;
    for (int cb = 16; cb >= 1; cb >>= 1) {
        if (zmark + 2 * (size_t)cb * NN * HID * 2 <= ws_size) { CB2 = cb; break; }
    }

    dim3 b256(256);
    // 0. fused weight prep (one launch)
    wprep_kernel<<<dim3(2925), b256, 0, stream>>>(
        q_w, kv1_w, kv2_w, proj_w, fc1_w, fc2_w, c2_w, lpu_w, dw_w,
        wq, wkv1, wkv2, wpr, wf1, wf2, wcp, lpwt, dwwt);
    // 1. LPU x-walk + residual + fused LN1
    lpu_kernel<<<dim3(NN / 16, BB), b256, 0, stream>>>(x, lpwt, lpu_b, n1_g, n1_b, xbuf, ybuf);
    // 3. cp branch: MFMA implicit conv + fused LN64+GELU -> cat cols [192,256)
    cpgemm_kernel<<<dim3(BNR / 128), b256, 0, stream>>>(ybuf, wcp, c2_b, cn_g, cn_b, cat);
    // 4. q = ap @ q_w.T  (bf16 out)
    gemm_mfma<4><<<dim3(2, BNR / 128), b256, 0, stream>>>(
        ybuf + CD, CC, wq, AD, AD, nullptr, nullptr, 0, qbuf, AD, BNR);
    // 5. SR convs + LN + GELU
    sr_kernel<8, 7><<<dim3(M1, BB), dim3(192), 0, stream>>>(ybuf + CD, sr1_w, sr1_b, an1_g, an1_b, x1g);
    sr_kernel<4, 14><<<dim3(M2, BB), dim3(192), 0, stream>>>(ybuf + CD, sr2_w, sr2_b, an2_g, an2_b, x2g);
    // 6. kv GEMMs (bf16 out)
    gemm_mfma<4><<<dim3(2, (BB * M1 + 127) / 128), b256, 0, stream>>>(
        x1g, AD, wkv1, AD, AD, nullptr, nullptr, 0, kv1b, AD, BB * M1);
    gemm_mfma<4><<<dim3(2, (BB * M2 + 127) / 128), b256, 0, stream>>>(
        x2g, AD, wkv2, AD, AD, nullptr, nullptr, 0, kv2b, AD, BB * M2);
    // 7. attention (MFMA, 256 q/block) -> cat cols [0,192)
    attn_mfma<M1, 64, 0><<<dim3((NN + 255) / 256, HG, BB), b256, 0, stream>>>(qbuf, kv1b, cat);
    attn_mfma<M2, 224, HG><<<dim3((NN + 255) / 256, HG, BB), b256, 0, stream>>>(qbuf, kv2b, cat);
    // 8. proj + bias + residual + fused LN2 (writes xbuf fp32 AND ybuf bf16)
    projln_kernel<<<dim3(BNR / 128), b256, 0, stream>>>(
        cat, wpr, proj_b, n2_g, n2_b, xbuf, ybuf);
    // 10. MLP in batch chunks
    ushort* z1 = (ushort*)(ws + zmark);
    ushort* z2 = z1 + (size_t)CB2 * NN * HID;
    for (int c0 = 0; c0 < BB; c0 += CB2) {
        size_t tokoff = (size_t)c0 * NN;
        int Rr = CB2 * NN;
        gemm_mfma<5><<<dim3(HID / 128, (Rr + 127) / 128), b256, 0, stream>>>(
            ybuf + tokoff * CC, CC, wf1, CC, HID, fc1_b, nullptr, 0, z1, HID, Rr);
        dwconv_kernel<<<dim3(HH * 7, CB2), b256, 0, stream>>>(z1, dwwt, dw_b, z2);
        gemm_mfma<3><<<dim3(CC / 128, (Rr + 127) / 128), b256, 0, stream>>>(
            z2, HID, wf2, HID, CC, fc2_b, xbuf + tokoff * CC, CC, out + tokoff * CC, CC, Rr);
    }
}